// Round 3
// baseline (691.079 us; speedup 1.0000x reference)
//
#include <hip/hip_runtime.h>
#include <hip/hip_fp16.h>
#include <stdint.h>

#define BB 16
#define NN 1620
#define DD 64
#define CC 128
#define KK 32
#define EPSV 1e-5f
#define PAIRS (BB*NN)            // 25920
#define ROWS  (PAIRS*KK)         // 829440
#define TILES (PAIRS/2)          // 12960 tiles of 64 rows
#define TPB_TILES 8
#define GRID_MM (TILES/TPB_TILES) // 1620
#define NCHUNK 26                // ceil(1620/64)
#define GRAM_BLOCKS 128
#define MSTRIDE 12416            // 3*4096 mats + 64 vcf + 64 vf

typedef _Float16 half8 __attribute__((ext_vector_type(8)));
typedef float f32x4 __attribute__((ext_vector_type(4)));

__device__ __forceinline__ float relu_(float v){ return v > 0.f ? v : 0.f; }

union H2U { __half2 h; unsigned u; };

// ---------------- x (B,D,N) fp32 -> feats (B,N,D) fp16 ----------------
__global__ void __launch_bounds__(256) k_prep_feats(const float* __restrict__ x,
                                                    __half* __restrict__ feats) {
    __shared__ float t[64*65];
    int b = blockIdx.y;
    int n0 = blockIdx.x * 64;
    int tid = threadIdx.x;
#pragma unroll
    for (int i = 0; i < 16; ++i) {
        int idx = i*256 + tid;
        int d = idx >> 6, nl = idx & 63;
        int n = n0 + nl;
        float v = 0.f;
        if (n < NN) v = x[((size_t)b*DD + d)*NN + n];
        t[d*65 + nl] = v;
    }
    __syncthreads();
#pragma unroll
    for (int i = 0; i < 8; ++i) {
        int idx = i*256 + tid;            // 64 nl x 32 d-pairs
        int nl = idx >> 5, dp = idx & 31;
        int n = n0 + nl;
        if (n < NN) {
            __half2 h = __floats2half2_rn(t[(dp*2)*65 + nl], t[(dp*2+1)*65 + nl]);
            *(__half2*)(feats + ((size_t)b*NN + n)*DD + dp*2) = h;
        }
    }
}

// ---------------- w fp32 -> fp16 (same [o][c] layout) ----------------
__global__ void k_convert_w(const float* __restrict__ w1, const float* __restrict__ w2,
                            __half* __restrict__ w1h, __half* __restrict__ w2h) {
    int i = blockIdx.x*256 + threadIdx.x;   // 64 blocks * 256 = 16384
    w1h[i] = __float2half(w1[i]);
    w2h[i] = __float2half(w2[i]);
}

// ---------------- KNN: radix-histogram rank selection + neighbor-count histogram ----------------
__global__ void __launch_bounds__(64) k_knn(const float* __restrict__ coords,
                                            int* __restrict__ idx_out,
                                            int* __restrict__ cnt) {
#pragma clang fp contract(off)
    __shared__ int hist[256];
    __shared__ unsigned bcast[2];   // [0]=bucket, [1]=count below bucket
    int p = blockIdx.x;
    int b = p / NN, n = p - b*NN;
    int lane = threadIdx.x;
    const float* cb = coords + (size_t)b*NN*3;
    float qx = cb[n*3+0], qy = cb[n*3+1], qz = cb[n*3+2];
    float sqn = (qx*qx + qy*qy) + qz*qz;

    unsigned key[NCHUNK];
#pragma unroll
    for (int i = 0; i < NCHUNK; ++i) {
        int m = lane + i*64;
        unsigned u = 0xFFFFFFFFu;
        if (m < NN) {
            float cx = cb[m*3+0], cy = cb[m*3+1], cz = cb[m*3+2];
            float sqm = (cx*cx + cy*cy) + cz*cz;
            float dot = (qx*cx + qy*cy) + qz*cz;
            float d = (sqn + sqm) - 2.0f*dot;
            unsigned t = __float_as_uint(d);
            u = (t & 0x80000000u) ? ~t : (t | 0x80000000u);
        }
        key[i] = u;
    }

    // ---- pass A: histogram on key[31:24] ----
#pragma unroll
    for (int i = 0; i < 4; ++i) hist[lane + i*64] = 0;
    __syncthreads();
#pragma unroll
    for (int i = 0; i < NCHUNK; ++i) {
        int m = lane + i*64;
        if (m < NN) atomicAdd(&hist[key[i] >> 24], 1);
    }
    __syncthreads();
    {
        int v0 = hist[lane*4+0], v1 = hist[lane*4+1], v2 = hist[lane*4+2], v3 = hist[lane*4+3];
        int c1 = v0+v1, c2 = c1+v2, c3 = c2+v3;
        int inc = c3;
#pragma unroll
        for (int off = 1; off < 64; off <<= 1) {
            int t = __shfl_up(inc, off);
            if (lane >= off) inc += t;
        }
        int base = inc - c3;
        if (base < KK) {
            int u0 = base+v0, u1 = base+c1, u2 = base+c2, u3 = base+c3;
            if      (u0 >= KK) { bcast[0] = lane*4+0; bcast[1] = base; }
            else if (u1 >= KK) { bcast[0] = lane*4+1; bcast[1] = u0; }
            else if (u2 >= KK) { bcast[0] = lane*4+2; bcast[1] = u1; }
            else if (u3 >= KK) { bcast[0] = lane*4+3; bcast[1] = u2; }
        }
    }
    __syncthreads();
    unsigned BA = bcast[0];
    int rA = KK - (int)bcast[1];
    __syncthreads();

    // ---- pass B: histogram on key[23:16] within bucket BA ----
#pragma unroll
    for (int i = 0; i < 4; ++i) hist[lane + i*64] = 0;
    __syncthreads();
#pragma unroll
    for (int i = 0; i < NCHUNK; ++i) {
        int m = lane + i*64;
        if (m < NN && (key[i] >> 24) == BA) atomicAdd(&hist[(key[i] >> 16) & 255], 1);
    }
    __syncthreads();
    {
        int v0 = hist[lane*4+0], v1 = hist[lane*4+1], v2 = hist[lane*4+2], v3 = hist[lane*4+3];
        int c1 = v0+v1, c2 = c1+v2, c3 = c2+v3;
        int inc = c3;
#pragma unroll
        for (int off = 1; off < 64; off <<= 1) {
            int t = __shfl_up(inc, off);
            if (lane >= off) inc += t;
        }
        int base = inc - c3;
        if (base < rA) {
            int u0 = base+v0, u1 = base+c1, u2 = base+c2, u3 = base+c3;
            if      (u0 >= rA) { bcast[0] = lane*4+0; bcast[1] = base; }
            else if (u1 >= rA) { bcast[0] = lane*4+1; bcast[1] = u0; }
            else if (u2 >= rA) { bcast[0] = lane*4+2; bcast[1] = u1; }
            else if (u3 >= rA) { bcast[0] = lane*4+3; bcast[1] = u2; }
        }
    }
    __syncthreads();
    unsigned prefix16 = (BA << 8) | bcast[0];
    int r = rA - (int)bcast[1];

    // ---- extract exact 32nd (key, m) pair ----
    unsigned long long fl = 0;
    for (int round = 0; round < r; ++round) {
        unsigned long long best = ~0ull;
#pragma unroll
        for (int i = 0; i < NCHUNK; ++i) {
            if ((key[i] >> 16) == prefix16) {
                unsigned long long v = ((unsigned long long)key[i] << 32) | (unsigned)(lane + i*64);
                if (v > fl && v < best) best = v;
            }
        }
#pragma unroll
        for (int off = 32; off; off >>= 1) {
            unsigned long long o = __shfl_xor(best, off, 64);
            if (o < best) best = o;
        }
        fl = best;
    }
    unsigned kstar = (unsigned)(fl >> 32);
    unsigned mstar = (unsigned)fl;

    int cnt_ = 0;
    unsigned long long mylow = (1ull << lane) - 1ull;
#pragma unroll
    for (int i = 0; i < NCHUNK; ++i) {
        unsigned m = lane + i*64;
        bool sel = (key[i] < kstar) || (key[i] == kstar && m <= mstar);
        unsigned long long bal = __ballot(sel);
        if (sel) {
            int pos = cnt_ + __popcll(bal & mylow);
            idx_out[p*KK + pos] = (int)m;
            atomicAdd(&cnt[b*NN + (int)m], 1);
        }
        cnt_ += __popcll(bal);
    }
}

// ---------------- gather-sum: s_p = sum_k f_nb(p,k), fp32 ----------------
__global__ void __launch_bounds__(256) k_gather_sum(const __half* __restrict__ feats,
                                                    const int* __restrict__ knn_idx,
                                                    float* __restrict__ s_arr) {
    int w = threadIdx.x >> 6, lane = threadIdx.x & 63;
    int p = blockIdx.x*4 + w;
    int b = p / NN;
    int bbase = b*NN;
    int idx = 0;
    if (lane < KK) idx = knn_idx[p*KK + lane];
    float s = 0.f;
#pragma unroll
    for (int k = 0; k < KK; ++k) {
        int nb = __shfl(idx, k);
        s += __half2float(feats[((size_t)(bbase + nb))*DD + lane]);
    }
    s_arr[(size_t)p*DD + lane] = s;
}

// ---------------- gram: per-block partial M1/M2/M3 + vectors ----------------
// M1 = sum cnt_m f f^T, M2 = sum s_p f_p^T, M3 = sum f f^T, vcf = sum cnt f, vf = sum f
__global__ void __launch_bounds__(256) k_gram(const __half* __restrict__ feats,
                                              const float* __restrict__ s_arr,
                                              const int* __restrict__ cnt,
                                              float* __restrict__ Mpart) {
    __shared__ float fs[4][64];
    __shared__ float ss[4][64];
    __shared__ float cs[4];
    int tid = threadIdx.x;
    int rt = tid >> 4, ct = tid & 15;
    int r0 = rt*4, c0 = ct*4;
    float m1a[4][4] = {{0}}, m2a[4][4] = {{0}}, m3a[4][4] = {{0}};
    float vcf4[4] = {0,0,0,0}, vf4[4] = {0,0,0,0};

    int per = (PAIRS + GRAM_BLOCKS - 1)/GRAM_BLOCKS;   // 203
    int p0 = blockIdx.x * per;
    int p1 = p0 + per; if (p1 > PAIRS) p1 = PAIRS;

    for (int pc = p0; pc < p1; pc += 4) {
        __syncthreads();
        int sub = tid >> 6, l = tid & 63;
        int pp = pc + sub;
        if (pp < p1) {
            fs[sub][l] = __half2float(feats[(size_t)pp*DD + l]);
            ss[sub][l] = s_arr[(size_t)pp*DD + l];
            if (l == 0) cs[sub] = (float)cnt[pp];
        }
        __syncthreads();
        int e = p1 - pc; if (e > 4) e = 4;
        for (int j = 0; j < e; ++j) {
            float cn = cs[j];
            float fr[4], sr[4], fc[4];
#pragma unroll
            for (int a = 0; a < 4; ++a) { fr[a] = fs[j][r0+a]; sr[a] = ss[j][r0+a]; fc[a] = fs[j][c0+a]; }
#pragma unroll
            for (int a = 0; a < 4; ++a) {
                float cfr = cn * fr[a];
#pragma unroll
                for (int bc = 0; bc < 4; ++bc) {
                    m1a[a][bc] = fmaf(cfr,   fc[bc], m1a[a][bc]);
                    m2a[a][bc] = fmaf(sr[a], fc[bc], m2a[a][bc]);
                    m3a[a][bc] = fmaf(fr[a], fc[bc], m3a[a][bc]);
                }
                if (ct == 0) { vcf4[a] += cfr; vf4[a] += fr[a]; }
            }
        }
    }
    float* out = Mpart + (size_t)blockIdx.x * MSTRIDE;
#pragma unroll
    for (int a = 0; a < 4; ++a)
#pragma unroll
        for (int bc = 0; bc < 4; ++bc) {
            int idx = (r0+a)*64 + c0+bc;
            out[idx]        = m1a[a][bc];
            out[4096 + idx] = m2a[a][bc];
            out[8192 + idx] = m3a[a][bc];
        }
    if (ct == 0)
#pragma unroll
        for (int a = 0; a < 4; ++a) {
            out[12288 + r0+a] = vcf4[a];
            out[12352 + r0+a] = vf4[a];
        }
}

__global__ void __launch_bounds__(256) k_gram_reduce(const float* __restrict__ Mpart,
                                                     float* __restrict__ Mfin) {
    int e = blockIdx.x*256 + threadIdx.x;
    if (e < MSTRIDE) {
        float s = 0.f;
        for (int p = 0; p < GRAM_BLOCKS; ++p) s += Mpart[(size_t)p*MSTRIDE + e];
        Mfin[e] = s;
    }
}

// ---------------- stats1 from Gram: one block per output channel o ----------------
__global__ void __launch_bounds__(256) k_stats1(const float* __restrict__ M,
                                                const __half* __restrict__ w1h,
                                                const float* __restrict__ g1,
                                                const float* __restrict__ b1,
                                                float* __restrict__ ab1) {
    __shared__ float wl[64], wr[64];
    __shared__ float redA[256], redB[256];
    int o = blockIdx.x, tid = threadIdx.x;
    if (tid < 64)       wl[tid]    = __half2float(w1h[o*CC + tid]);
    else if (tid < 128) wr[tid-64] = __half2float(w1h[o*CC + tid]);
    __syncthreads();
    const float* M1 = M;
    const float* M2 = M + 4096;
    const float* M3 = M + 8192;
    const float* vcf = M + 12288;
    const float* vf  = M + 12352;
    float part = 0.f;
    for (int e = tid; e < 4096; e += 256) {
        int i = e >> 6, j = e & 63;
        float m1 = M1[e], m2 = M2[e], m2t = M2[j*64 + i], m3 = M3[e];
        float A  = m1 - m2 - m2t + 32.f*m3;   // sum u u^T
        float Bc = m2 - 32.f*m3;              // sum u v^T
        part += wl[i]*(A*wl[j] + 2.f*Bc*wr[j]) + 32.f*wr[i]*m3*wr[j];
    }
    float psum = 0.f;
    if (tid < 64) psum = wl[tid]*(vcf[tid] - 32.f*vf[tid]) + 32.f*wr[tid]*vf[tid];
    redA[tid] = part; redB[tid] = psum;
    __syncthreads();
    for (int s = 128; s > 0; s >>= 1) {
        if (tid < s) { redA[tid] += redA[tid+s]; redB[tid] += redB[tid+s]; }
        __syncthreads();
    }
    if (tid == 0) {
        float sumsq = redA[0], sum = redB[0];
        float mean = sum / (float)ROWS;
        float var  = sumsq / (float)ROWS - mean*mean;
        float a = g1[o] * rsqrtf(var + EPSV);
        ab1[o] = a;
        ab1[CC + o] = b1[o] - mean*a;
    }
}

// ============ staging helpers: coalesced gather + XOR-swizzled LDS ============
// ctr base (p*DD) is pure arithmetic of (blk, tloc, row) -> no LDS array needed.
__device__ __forceinline__ void fill_bases(const int* __restrict__ knn_idx,
                                           int blk, int tid, int* rowb) {
#pragma unroll
    for (int e = tid; e < TPB_TILES*64; e += 256) {
        int tile = blk*TPB_TILES + (e >> 6);
        int rr = e & 63;
        int p = tile*2 + (rr >> 5);
        int nb = knn_idx[p*KK + (rr & 31)];
        int b = p / NN;
        rowb[e] = (b*NN + nb)*DD;
    }
}

__device__ __forceinline__ void stage_load(const __half* __restrict__ feats,
                                           const int* rowb, int blk,
                                           int tloc, int tid, uint4* A) {
    int kc = tid & 15;
#pragma unroll
    for (int it = 0; it < 4; ++it) {
        int row = it*16 + (tid >> 4);
        int e = tloc*64 + row;
        int p = (blk*TPB_TILES + tloc)*2 + (row >> 5);
        int ra = (kc < 8) ? (rowb[e] + kc*8) : (p*DD + (kc-8)*8);
        A[it] = *(const uint4*)(feats + ra);
    }
}

__device__ __forceinline__ void stage_write(const __half* __restrict__ feats,
                                            int blk, int tloc, int tid,
                                            const uint4* A, __half* nf) {
    int kc = tid & 15;
#pragma unroll
    for (int it = 0; it < 4; ++it) {
        int row = it*16 + (tid >> 4);
        int p = (blk*TPB_TILES + tloc)*2 + (row >> 5);
        union { uint4 u; __half2 h[4]; } a, b, rr;
        a.u = A[it];
        if (kc < 8) {
            b.u = *(const uint4*)(feats + p*DD + kc*8);
#pragma unroll
            for (int j = 0; j < 4; ++j) rr.h[j] = __hsub2(a.h[j], b.h[j]);
        } else {
            rr.u = a.u;
        }
        int C = (row >> 4)*256 + kc*16 + ((row & 15) ^ kc);   // XOR swizzle
        *(uint4*)(nf + C*8) = rr.u;
    }
}

// ---------------- finalize bn params (layer 2) ----------------
__global__ void k_finalize(const float* __restrict__ gsum, const float* __restrict__ gsumsq,
                           const float* __restrict__ g, const float* __restrict__ bb,
                           float* __restrict__ ab) {
    int o = threadIdx.x;
    float cnt = (float)ROWS;
    float mean = gsum[o] / cnt;
    float var = gsumsq[o] / cnt - mean*mean;
    float a = g[o] * rsqrtf(var + EPSV);
    ab[o] = a;
    ab[CC + o] = bb[o] - mean*a;
}

// ---------------- fused: mm1 + bn1relu + mm2 + stats2 + per-pair max/min ----------------
// LDS = nf 16K + y1s 16K + rowb 2K = 34 KB.
// waves_per_eu(3,3): rounds 1-2 showed that a 4-waves/EU target imposes a
// 512/4=128-reg cap; this kernel's unified demand is ~150 regs, so the
// backend demoted w1f/w2f (64 regs) to scratch -> +740 MB/dispatch HBM
// traffic (VGPR_Count 120->64, FETCH 14.5->535 MB). Round 0 only avoided
// this because its 45.5 KB LDS made 4 blocks/CU unachievable, relaxing the
// budget to 512/3=170. Pin 3 waves/EU explicitly: budget 170 >= demand.
__global__ void __launch_bounds__(256)
__attribute__((amdgpu_waves_per_eu(3, 3)))
k_fused_mfma(const __half* __restrict__ feats,
             const int* __restrict__ knn_idx,
             const __half* __restrict__ w1h,
             const __half* __restrict__ w2h,
             const float* __restrict__ ab1,
             float* __restrict__ gsum2,
             float* __restrict__ gsumsq2,
             float* __restrict__ wsmax,
             float* __restrict__ wsmin) {
    __shared__ __align__(16) __half nf[8192];     // 16 KB, swizzled chunks
    __shared__ __align__(16) __half y1s[8192];    // 16 KB, same swizzled layout
    __shared__ int rowb[TPB_TILES*64];
    int tid = threadIdx.x;
    int lane = tid & 63, wid = tid >> 6;
    int m = lane & 15, q = lane >> 4;

    fill_bases(knn_idx, blockIdx.x, tid, rowb);

    half8 w1f[2][4], w2f[2][4];
#pragma unroll
    for (int ob = 0; ob < 2; ++ob)
#pragma unroll
        for (int t = 0; t < 4; ++t) {
            int o = wid*32 + ob*16 + m;
            w1f[ob][t] = *(const half8*)(w1h + o*CC + t*32 + q*8);
            w2f[ob][t] = *(const half8*)(w2h + o*CC + t*32 + q*8);
        }
    f32x4 a1v[2], c1v[2];
#pragma unroll
    for (int ob = 0; ob < 2; ++ob) {
        a1v[ob] = *(const f32x4*)(ab1 + wid*32 + ob*16 + q*4);
        c1v[ob] = *(const f32x4*)(ab1 + CC + wid*32 + ob*16 + q*4);
    }
    f32x4 zero4 = {0.f, 0.f, 0.f, 0.f};
    f32x4 ssum[2] = {zero4, zero4}, ssq[2] = {zero4, zero4};

    __syncthreads();
    uint4 pf[4];
    stage_load(feats, rowb, blockIdx.x, 0, tid, pf);

    for (int it = 0; it < TPB_TILES; ++it) {
        int tile = blockIdx.x * TPB_TILES + it;
        stage_write(feats, blockIdx.x, it, tid, pf, nf);
        __syncthreads();                               // B1
        if (it + 1 < TPB_TILES) stage_load(feats, rowb, blockIdx.x, it + 1, tid, pf);

        f32x4 acc[2][4];
#pragma unroll
        for (int ob = 0; ob < 2; ++ob)
#pragma unroll
            for (int rbk = 0; rbk < 4; ++rbk) acc[ob][rbk] = zero4;

        // mm1: z1^T = w1 . nf^T
#pragma unroll
        for (int t = 0; t < 4; ++t) {
            int kct = t*4 + q;
            int sw = m ^ kct;
#pragma unroll
            for (int rbk = 0; rbk < 4; ++rbk) {
                half8 bfr = *(const half8*)(nf + (rbk*256 + kct*16 + sw)*8);
                acc[0][rbk] = __builtin_amdgcn_mfma_f32_16x16x32_f16(w1f[0][t], bfr, acc[0][rbk], 0, 0, 0);
                acc[1][rbk] = __builtin_amdgcn_mfma_f32_16x16x32_f16(w1f[1][t], bfr, acc[1][rbk], 0, 0, 0);
            }
        }
        // bn1 + relu, write y1 in swizzled chunk layout
#pragma unroll
        for (int ob = 0; ob < 2; ++ob)
#pragma unroll
            for (int rbk = 0; rbk < 4; ++rbk) {
                f32x4 z = acc[ob][rbk];
                float y0 = relu_(fmaf(a1v[ob][0], z[0], c1v[ob][0]));
                float y1 = relu_(fmaf(a1v[ob][1], z[1], c1v[ob][1]));
                float y2 = relu_(fmaf(a1v[ob][2], z[2], c1v[ob][2]));
                float y3 = relu_(fmaf(a1v[ob][3], z[3], c1v[ob][3]));
                H2U p0, p1;
                p0.h = __floats2half2_rn(y0, y1);
                p1.h = __floats2half2_rn(y2, y3);
                int kcy = wid*4 + ob*2 + (q >> 1);
                int C = rbk*256 + kcy*16 + (m ^ kcy);
                uint2 v; v.x = p0.u; v.y = p1.u;
                *(uint2*)(y1s + C*8 + (q & 1)*4) = v;
            }
        __syncthreads();                               // B2

        // mm2: z2^T = w2 . y1^T
#pragma unroll
        for (int ob = 0; ob < 2; ++ob)
#pragma unroll
            for (int rbk = 0; rbk < 4; ++rbk) acc[ob][rbk] = zero4;
#pragma unroll
        for (int t = 0; t < 4; ++t) {
            int kct = t*4 + q;
            int sw = m ^ kct;
#pragma unroll
            for (int rbk = 0; rbk < 4; ++rbk) {
                half8 bfr = *(const half8*)(y1s + (rbk*256 + kct*16 + sw)*8);
                acc[0][rbk] = __builtin_amdgcn_mfma_f32_16x16x32_f16(w2f[0][t], bfr, acc[0][rbk], 0, 0, 0);
                acc[1][rbk] = __builtin_amdgcn_mfma_f32_16x16x32_f16(w2f[1][t], bfr, acc[1][rbk], 0, 0, 0);
            }
        }
        // stats2
#pragma unroll
        for (int ob = 0; ob < 2; ++ob)
#pragma unroll
            for (int rbk = 0; rbk < 4; ++rbk) {
                ssum[ob] += acc[ob][rbk];
                ssq[ob]  += acc[ob][rbk]*acc[ob][rbk];
            }
        // per-pair max/min: full in-register reduce over the 16 m-lanes;
        // lane m==0 of each q-group owns channels o = wid*32+ob*16+q*4..+3
#pragma unroll
        for (int ob = 0; ob < 2; ++ob)
#pragma unroll
            for (int pr = 0; pr < 2; ++pr) {
                f32x4 a0 = acc[ob][pr*2], a1 = acc[ob][pr*2 + 1];
                f32x4 vmx, vmn;
#pragma unroll
                for (int c = 0; c < 4; ++c) {
                    vmx[c] = fmaxf(a0[c], a1[c]);
                    vmn[c] = fminf(a0[c], a1[c]);
                }
#pragma unroll
                for (int off = 1; off < 16; off <<= 1)
#pragma unroll
                    for (int c = 0; c < 4; ++c) {
                        vmx[c] = fmaxf(vmx[c], __shfl_xor(vmx[c], off));
                        vmn[c] = fminf(vmn[c], __shfl_xor(vmn[c], off));
                    }
                if (m == 0) {
                    int p = tile*2 + pr;
                    int o0 = wid*32 + ob*16 + q*4;
                    *(f32x4*)(wsmax + (size_t)p*CC + o0) = vmx;
                    *(f32x4*)(wsmin + (size_t)p*CC + o0) = vmn;
                }
            }
    }
#pragma unroll
    for (int ob = 0; ob < 2; ++ob)
#pragma unroll
        for (int c = 0; c < 4; ++c) {
            float v = ssum[ob][c], v2 = ssq[ob][c];
#pragma unroll
            for (int off = 1; off < 16; off <<= 1) {
                v  += __shfl_xor(v,  off);
                v2 += __shfl_xor(v2, off);
            }
            if (m == 0) {
                int o = wid*32 + ob*16 + q*4 + c;
                atomicAdd(&gsum2[o], v);
                atomicAdd(&gsumsq2[o], v2);
            }
        }
}

// ---------------- epilogue: bn2+relu on max/min, transpose to (B,C,N) ----------------
__global__ void __launch_bounds__(256) k_epilogue(const float* __restrict__ wsmax,
                                                  const float* __restrict__ wsmin,
                                                  const float* __restrict__ ab2,
                                                  float* __restrict__ out) {
    __shared__ float t[128*65];
    int b = blockIdx.y;
    int n0 = blockIdx.x * 64;
    int tid = threadIdx.x;
#pragma unroll
    for (int i = 0; i < 32; ++i) {
        int idx = i*256 + tid;
        int nl = idx >> 7, o = idx & 127;
        int n = n0 + nl;
        float v = 0.f;
        if (n < NN) {
            float a = ab2[o], cc = ab2[CC + o];
            size_t p = (size_t)b*NN + n;
            float z = (a >= 0.f) ? wsmax[p*CC + o] : wsmin[p*CC + o];
            v = fmaf(a, z, cc);
            v = v > 0.f ? v : 0.f;
        }
        t[o*65 + nl] = v;
    }
    __syncthreads();
#pragma unroll
    for (int i = 0; i < 32; ++i) {
        int idx = i*256 + tid;
        int o = idx >> 6, nl = idx & 63;
        int n = n0 + nl;
        if (n < NN) out[((size_t)b*CC + o)*NN + n] = t[o*65 + nl];
    }
}

extern "C" void kernel_launch(void* const* d_in, const int* in_sizes, int n_in,
                              void* d_out, int out_size, void* d_ws, size_t ws_size,
                              hipStream_t stream) {
    const float* x      = (const float*)d_in[0];
    const float* coords = (const float*)d_in[1];
    const float* w1     = (const float*)d_in[2];
    const float* g1     = (const float*)d_in[3];
    const float* b1     = (const float*)d_in[4];
    const float* w2     = (const float*)d_in[5];
    const float* g2     = (const float*)d_in[6];
    const float* b2     = (const float*)d_in[7];
    float* out = (float*)d_out;

    char* ws = (char*)d_ws;
    size_t off = 0;
    int* knn_idx = (int*)(ws + off);   off += (size_t)ROWS * sizeof(int);        // 3.32 MB
    float* stats = (float*)(ws + off); off += 1024 * sizeof(float);
    float* gsum2 = stats + 256, *gsq2 = stats + 384;
    float* ab1   = stats + 512;
    float* ab2   = stats + 768;
    __half* feats = (__half*)(ws + off); off += (size_t)BB*NN*DD * sizeof(__half); // 3.32 MB
    __half* w1h   = (__half*)(ws + off); off += CC*CC * sizeof(__half);
    __half* w2h   = (__half*)(ws + off); off += CC*CC * sizeof(__half);
    float* wsmax = (float*)(ws + off);  off += (size_t)PAIRS*CC * sizeof(float);  // 13.3 MB
    float* wsmin = (float*)(ws + off);  off += (size_t)PAIRS*CC * sizeof(float);  // 13.3 MB
    int*   cnt   = (int*)(ws + off);    off += (size_t)PAIRS * sizeof(int);       // 104 KB
    float* Mfin  = (float*)(ws + off);  off += (size_t)MSTRIDE * sizeof(float);   // 50 KB
    // aliases (dead before k_fused writes wsmax/wsmin):
    float* s_arr = wsmax;                    // PAIRS*64 fp32 = 6.64 MB  (<13.3)
    float* Mpart = wsmin;                    // 128*12416 fp32 = 6.36 MB (<13.3)
    (void)ws_size; (void)in_sizes; (void)n_in; (void)out_size;

    hipMemsetAsync(stats, 0, 512 * sizeof(float), stream);
    hipMemsetAsync(cnt, 0, (size_t)PAIRS * sizeof(int), stream);

    dim3 gT((NN + 63)/64, BB);
    k_prep_feats<<<gT, 256, 0, stream>>>(x, feats);
    k_convert_w<<<64, 256, 0, stream>>>(w1, w2, w1h, w2h);
    k_knn<<<PAIRS, 64, 0, stream>>>(coords, knn_idx, cnt);
    k_gather_sum<<<PAIRS/4, 256, 0, stream>>>(feats, knn_idx, s_arr);
    k_gram<<<GRAM_BLOCKS, 256, 0, stream>>>(feats, s_arr, cnt, Mpart);
    k_gram_reduce<<<(MSTRIDE + 255)/256, 256, 0, stream>>>(Mpart, Mfin);
    k_stats1<<<CC, 256, 0, stream>>>(Mfin, w1h, g1, b1, ab1);
    k_fused_mfma<<<GRID_MM, 256, 0, stream>>>(feats, knn_idx, w1h, w2h, ab1,
                                              gsum2, gsq2, wsmax, wsmin);
    k_finalize<<<1, CC, 0, stream>>>(gsum2, gsq2, g2, b2, ab2);
    dim3 gE((NN + 63)/64, BB);
    k_epilogue<<<gE, 256, 0, stream>>>(wsmax, wsmin, ab2, out);
}

// Round 4
// 605.864 us; speedup vs baseline: 1.1407x; 1.1407x over previous
//
#include <hip/hip_runtime.h>
#include <hip/hip_fp16.h>
#include <stdint.h>

#define BB 16
#define NN 1620
#define DD 64
#define CC 128
#define KK 32
#define EPSV 1e-5f
#define PAIRS (BB*NN)            // 25920
#define ROWS  (PAIRS*KK)         // 829440
#define TILES (PAIRS/2)          // 12960 tiles of 64 rows
#define TPB_TILES 8
#define GRID_MM (TILES/TPB_TILES) // 1620
#define NCHUNK 26                // ceil(1620/64)
#define GRAM_BLOCKS 128
#define MSTRIDE 12416            // 3*4096 mats + 64 vcf + 64 vf

typedef _Float16 half8 __attribute__((ext_vector_type(8)));
typedef float f32x4 __attribute__((ext_vector_type(4)));

__device__ __forceinline__ float relu_(float v){ return v > 0.f ? v : 0.f; }

union H2U { __half2 h; unsigned u; };

// ---------------- x (B,D,N) fp32 -> feats (B,N,D) fp16 ----------------
__global__ void __launch_bounds__(256) k_prep_feats(const float* __restrict__ x,
                                                    __half* __restrict__ feats) {
    __shared__ float t[64*65];
    int b = blockIdx.y;
    int n0 = blockIdx.x * 64;
    int tid = threadIdx.x;
#pragma unroll
    for (int i = 0; i < 16; ++i) {
        int idx = i*256 + tid;
        int d = idx >> 6, nl = idx & 63;
        int n = n0 + nl;
        float v = 0.f;
        if (n < NN) v = x[((size_t)b*DD + d)*NN + n];
        t[d*65 + nl] = v;
    }
    __syncthreads();
#pragma unroll
    for (int i = 0; i < 8; ++i) {
        int idx = i*256 + tid;            // 64 nl x 32 d-pairs
        int nl = idx >> 5, dp = idx & 31;
        int n = n0 + nl;
        if (n < NN) {
            __half2 h = __floats2half2_rn(t[(dp*2)*65 + nl], t[(dp*2+1)*65 + nl]);
            *(__half2*)(feats + ((size_t)b*NN + n)*DD + dp*2) = h;
        }
    }
}

// ---------------- w fp32 -> fp16 (same [o][c] layout) ----------------
__global__ void k_convert_w(const float* __restrict__ w1, const float* __restrict__ w2,
                            __half* __restrict__ w1h, __half* __restrict__ w2h) {
    int i = blockIdx.x*256 + threadIdx.x;   // 64 blocks * 256 = 16384
    w1h[i] = __float2half(w1[i]);
    w2h[i] = __float2half(w2[i]);
}

// ---------------- KNN: radix-histogram rank selection + neighbor-count histogram ----------------
__global__ void __launch_bounds__(64) k_knn(const float* __restrict__ coords,
                                            int* __restrict__ idx_out,
                                            int* __restrict__ cnt) {
#pragma clang fp contract(off)
    __shared__ int hist[256];
    __shared__ unsigned bcast[2];   // [0]=bucket, [1]=count below bucket
    int p = blockIdx.x;
    int b = p / NN, n = p - b*NN;
    int lane = threadIdx.x;
    const float* cb = coords + (size_t)b*NN*3;
    float qx = cb[n*3+0], qy = cb[n*3+1], qz = cb[n*3+2];
    float sqn = (qx*qx + qy*qy) + qz*qz;

    unsigned key[NCHUNK];
#pragma unroll
    for (int i = 0; i < NCHUNK; ++i) {
        int m = lane + i*64;
        unsigned u = 0xFFFFFFFFu;
        if (m < NN) {
            float cx = cb[m*3+0], cy = cb[m*3+1], cz = cb[m*3+2];
            float sqm = (cx*cx + cy*cy) + cz*cz;
            float dot = (qx*cx + qy*cy) + qz*cz;
            float d = (sqn + sqm) - 2.0f*dot;
            unsigned t = __float_as_uint(d);
            u = (t & 0x80000000u) ? ~t : (t | 0x80000000u);
        }
        key[i] = u;
    }

    // ---- pass A: histogram on key[31:24] ----
#pragma unroll
    for (int i = 0; i < 4; ++i) hist[lane + i*64] = 0;
    __syncthreads();
#pragma unroll
    for (int i = 0; i < NCHUNK; ++i) {
        int m = lane + i*64;
        if (m < NN) atomicAdd(&hist[key[i] >> 24], 1);
    }
    __syncthreads();
    {
        int v0 = hist[lane*4+0], v1 = hist[lane*4+1], v2 = hist[lane*4+2], v3 = hist[lane*4+3];
        int c1 = v0+v1, c2 = c1+v2, c3 = c2+v3;
        int inc = c3;
#pragma unroll
        for (int off = 1; off < 64; off <<= 1) {
            int t = __shfl_up(inc, off);
            if (lane >= off) inc += t;
        }
        int base = inc - c3;
        if (base < KK) {
            int u0 = base+v0, u1 = base+c1, u2 = base+c2, u3 = base+c3;
            if      (u0 >= KK) { bcast[0] = lane*4+0; bcast[1] = base; }
            else if (u1 >= KK) { bcast[0] = lane*4+1; bcast[1] = u0; }
            else if (u2 >= KK) { bcast[0] = lane*4+2; bcast[1] = u1; }
            else if (u3 >= KK) { bcast[0] = lane*4+3; bcast[1] = u2; }
        }
    }
    __syncthreads();
    unsigned BA = bcast[0];
    int rA = KK - (int)bcast[1];
    __syncthreads();

    // ---- pass B: histogram on key[23:16] within bucket BA ----
#pragma unroll
    for (int i = 0; i < 4; ++i) hist[lane + i*64] = 0;
    __syncthreads();
#pragma unroll
    for (int i = 0; i < NCHUNK; ++i) {
        int m = lane + i*64;
        if (m < NN && (key[i] >> 24) == BA) atomicAdd(&hist[(key[i] >> 16) & 255], 1);
    }
    __syncthreads();
    {
        int v0 = hist[lane*4+0], v1 = hist[lane*4+1], v2 = hist[lane*4+2], v3 = hist[lane*4+3];
        int c1 = v0+v1, c2 = c1+v2, c3 = c2+v3;
        int inc = c3;
#pragma unroll
        for (int off = 1; off < 64; off <<= 1) {
            int t = __shfl_up(inc, off);
            if (lane >= off) inc += t;
        }
        int base = inc - c3;
        if (base < rA) {
            int u0 = base+v0, u1 = base+c1, u2 = base+c2, u3 = base+c3;
            if      (u0 >= rA) { bcast[0] = lane*4+0; bcast[1] = base; }
            else if (u1 >= rA) { bcast[0] = lane*4+1; bcast[1] = u0; }
            else if (u2 >= rA) { bcast[0] = lane*4+2; bcast[1] = u1; }
            else if (u3 >= rA) { bcast[0] = lane*4+3; bcast[1] = u2; }
        }
    }
    __syncthreads();
    unsigned prefix16 = (BA << 8) | bcast[0];
    int r = rA - (int)bcast[1];

    // ---- extract exact 32nd (key, m) pair ----
    unsigned long long fl = 0;
    for (int round = 0; round < r; ++round) {
        unsigned long long best = ~0ull;
#pragma unroll
        for (int i = 0; i < NCHUNK; ++i) {
            if ((key[i] >> 16) == prefix16) {
                unsigned long long v = ((unsigned long long)key[i] << 32) | (unsigned)(lane + i*64);
                if (v > fl && v < best) best = v;
            }
        }
#pragma unroll
        for (int off = 32; off; off >>= 1) {
            unsigned long long o = __shfl_xor(best, off, 64);
            if (o < best) best = o;
        }
        fl = best;
    }
    unsigned kstar = (unsigned)(fl >> 32);
    unsigned mstar = (unsigned)fl;

    int cnt_ = 0;
    unsigned long long mylow = (1ull << lane) - 1ull;
#pragma unroll
    for (int i = 0; i < NCHUNK; ++i) {
        unsigned m = lane + i*64;
        bool sel = (key[i] < kstar) || (key[i] == kstar && m <= mstar);
        unsigned long long bal = __ballot(sel);
        if (sel) {
            int pos = cnt_ + __popcll(bal & mylow);
            idx_out[p*KK + pos] = (int)m;
            atomicAdd(&cnt[b*NN + (int)m], 1);
        }
        cnt_ += __popcll(bal);
    }
}

// ---------------- gather-sum: s_p = sum_k f_nb(p,k), fp32 ----------------
__global__ void __launch_bounds__(256) k_gather_sum(const __half* __restrict__ feats,
                                                    const int* __restrict__ knn_idx,
                                                    float* __restrict__ s_arr) {
    int w = threadIdx.x >> 6, lane = threadIdx.x & 63;
    int p = blockIdx.x*4 + w;
    int b = p / NN;
    int bbase = b*NN;
    int idx = 0;
    if (lane < KK) idx = knn_idx[p*KK + lane];
    float s = 0.f;
#pragma unroll
    for (int k = 0; k < KK; ++k) {
        int nb = __shfl(idx, k);
        s += __half2float(feats[((size_t)(bbase + nb))*DD + lane]);
    }
    s_arr[(size_t)p*DD + lane] = s;
}

// ---------------- gram: per-block partial M1/M2/M3 + vectors ----------------
// M1 = sum cnt_m f f^T, M2 = sum s_p f_p^T, M3 = sum f f^T, vcf = sum cnt f, vf = sum f
__global__ void __launch_bounds__(256) k_gram(const __half* __restrict__ feats,
                                              const float* __restrict__ s_arr,
                                              const int* __restrict__ cnt,
                                              float* __restrict__ Mpart) {
    __shared__ float fs[4][64];
    __shared__ float ss[4][64];
    __shared__ float cs[4];
    int tid = threadIdx.x;
    int rt = tid >> 4, ct = tid & 15;
    int r0 = rt*4, c0 = ct*4;
    float m1a[4][4] = {{0}}, m2a[4][4] = {{0}}, m3a[4][4] = {{0}};
    float vcf4[4] = {0,0,0,0}, vf4[4] = {0,0,0,0};

    int per = (PAIRS + GRAM_BLOCKS - 1)/GRAM_BLOCKS;   // 203
    int p0 = blockIdx.x * per;
    int p1 = p0 + per; if (p1 > PAIRS) p1 = PAIRS;

    for (int pc = p0; pc < p1; pc += 4) {
        __syncthreads();
        int sub = tid >> 6, l = tid & 63;
        int pp = pc + sub;
        if (pp < p1) {
            fs[sub][l] = __half2float(feats[(size_t)pp*DD + l]);
            ss[sub][l] = s_arr[(size_t)pp*DD + l];
            if (l == 0) cs[sub] = (float)cnt[pp];
        }
        __syncthreads();
        int e = p1 - pc; if (e > 4) e = 4;
        for (int j = 0; j < e; ++j) {
            float cn = cs[j];
            float fr[4], sr[4], fc[4];
#pragma unroll
            for (int a = 0; a < 4; ++a) { fr[a] = fs[j][r0+a]; sr[a] = ss[j][r0+a]; fc[a] = fs[j][c0+a]; }
#pragma unroll
            for (int a = 0; a < 4; ++a) {
                float cfr = cn * fr[a];
#pragma unroll
                for (int bc = 0; bc < 4; ++bc) {
                    m1a[a][bc] = fmaf(cfr,   fc[bc], m1a[a][bc]);
                    m2a[a][bc] = fmaf(sr[a], fc[bc], m2a[a][bc]);
                    m3a[a][bc] = fmaf(fr[a], fc[bc], m3a[a][bc]);
                }
                if (ct == 0) { vcf4[a] += cfr; vf4[a] += fr[a]; }
            }
        }
    }
    float* out = Mpart + (size_t)blockIdx.x * MSTRIDE;
#pragma unroll
    for (int a = 0; a < 4; ++a)
#pragma unroll
        for (int bc = 0; bc < 4; ++bc) {
            int idx = (r0+a)*64 + c0+bc;
            out[idx]        = m1a[a][bc];
            out[4096 + idx] = m2a[a][bc];
            out[8192 + idx] = m3a[a][bc];
        }
    if (ct == 0)
#pragma unroll
        for (int a = 0; a < 4; ++a) {
            out[12288 + r0+a] = vcf4[a];
            out[12352 + r0+a] = vf4[a];
        }
}

__global__ void __launch_bounds__(256) k_gram_reduce(const float* __restrict__ Mpart,
                                                     float* __restrict__ Mfin) {
    int e = blockIdx.x*256 + threadIdx.x;
    if (e < MSTRIDE) {
        float s = 0.f;
        for (int p = 0; p < GRAM_BLOCKS; ++p) s += Mpart[(size_t)p*MSTRIDE + e];
        Mfin[e] = s;
    }
}

// ---------------- stats1 from Gram: one block per output channel o ----------------
__global__ void __launch_bounds__(256) k_stats1(const float* __restrict__ M,
                                                const __half* __restrict__ w1h,
                                                const float* __restrict__ g1,
                                                const float* __restrict__ b1,
                                                float* __restrict__ ab1) {
    __shared__ float wl[64], wr[64];
    __shared__ float redA[256], redB[256];
    int o = blockIdx.x, tid = threadIdx.x;
    if (tid < 64)       wl[tid]    = __half2float(w1h[o*CC + tid]);
    else if (tid < 128) wr[tid-64] = __half2float(w1h[o*CC + tid]);
    __syncthreads();
    const float* M1 = M;
    const float* M2 = M + 4096;
    const float* M3 = M + 8192;
    const float* vcf = M + 12288;
    const float* vf  = M + 12352;
    float part = 0.f;
    for (int e = tid; e < 4096; e += 256) {
        int i = e >> 6, j = e & 63;
        float m1 = M1[e], m2 = M2[e], m2t = M2[j*64 + i], m3 = M3[e];
        float A  = m1 - m2 - m2t + 32.f*m3;   // sum u u^T
        float Bc = m2 - 32.f*m3;              // sum u v^T
        part += wl[i]*(A*wl[j] + 2.f*Bc*wr[j]) + 32.f*wr[i]*m3*wr[j];
    }
    float psum = 0.f;
    if (tid < 64) psum = wl[tid]*(vcf[tid] - 32.f*vf[tid]) + 32.f*wr[tid]*vf[tid];
    redA[tid] = part; redB[tid] = psum;
    __syncthreads();
    for (int s = 128; s > 0; s >>= 1) {
        if (tid < s) { redA[tid] += redA[tid+s]; redB[tid] += redB[tid+s]; }
        __syncthreads();
    }
    if (tid == 0) {
        float sumsq = redA[0], sum = redB[0];
        float mean = sum / (float)ROWS;
        float var  = sumsq / (float)ROWS - mean*mean;
        float a = g1[o] * rsqrtf(var + EPSV);
        ab1[o] = a;
        ab1[CC + o] = b1[o] - mean*a;
    }
}

// ============ staging helpers: coalesced gather + XOR-swizzled LDS ============
// ctr base (p*DD) is pure arithmetic of (blk, tloc, row) -> no LDS array needed.
__device__ __forceinline__ void fill_bases(const int* __restrict__ knn_idx,
                                           int blk, int tid, int* rowb) {
#pragma unroll
    for (int e = tid; e < TPB_TILES*64; e += 256) {
        int tile = blk*TPB_TILES + (e >> 6);
        int rr = e & 63;
        int p = tile*2 + (rr >> 5);
        int nb = knn_idx[p*KK + (rr & 31)];
        int b = p / NN;
        rowb[e] = (b*NN + nb)*DD;
    }
}

__device__ __forceinline__ void stage_load(const __half* __restrict__ feats,
                                           const int* rowb, int blk,
                                           int tloc, int tid, uint4* A) {
    int kc = tid & 15;
#pragma unroll
    for (int it = 0; it < 4; ++it) {
        int row = it*16 + (tid >> 4);
        int e = tloc*64 + row;
        int p = (blk*TPB_TILES + tloc)*2 + (row >> 5);
        int ra = (kc < 8) ? (rowb[e] + kc*8) : (p*DD + (kc-8)*8);
        A[it] = *(const uint4*)(feats + ra);
    }
}

__device__ __forceinline__ void stage_write(const __half* __restrict__ feats,
                                            int blk, int tloc, int tid,
                                            const uint4* A, __half* nf) {
    int kc = tid & 15;
#pragma unroll
    for (int it = 0; it < 4; ++it) {
        int row = it*16 + (tid >> 4);
        int p = (blk*TPB_TILES + tloc)*2 + (row >> 5);
        union { uint4 u; __half2 h[4]; } a, b, rr;
        a.u = A[it];
        if (kc < 8) {
            b.u = *(const uint4*)(feats + p*DD + kc*8);
#pragma unroll
            for (int j = 0; j < 4; ++j) rr.h[j] = __hsub2(a.h[j], b.h[j]);
        } else {
            rr.u = a.u;
        }
        int C = (row >> 4)*256 + kc*16 + ((row & 15) ^ kc);   // XOR swizzle
        *(uint4*)(nf + C*8) = rr.u;
    }
}

// ---------------- finalize bn params (layer 2) ----------------
__global__ void k_finalize(const float* __restrict__ gsum, const float* __restrict__ gsumsq,
                           const float* __restrict__ g, const float* __restrict__ bb,
                           float* __restrict__ ab) {
    int o = threadIdx.x;
    float cnt = (float)ROWS;
    float mean = gsum[o] / cnt;
    float var = gsumsq[o] / cnt - mean*mean;
    float a = g[o] * rsqrtf(var + EPSV);
    ab[o] = a;
    ab[CC + o] = bb[o] - mean*a;
}

// ---------------- fused: mm1 + bn1relu + mm2 + stats2 + per-pair max/min ----------------
// LDS = nf 16K + y1s 16K + rowb 2K = 34 KB -> 4 blocks/CU at <=128 VGPR.
// Register-demand fix (rounds 1-3 post-mortem): resident w1f+w2f = 64 regs
// pushed peak demand to ~150 > the 128-reg budget of 4 waves/EU, and the
// allocator demoted them to scratch (FETCH 535/224 MB of spill traffic).
// Now the weight fragments are re-loaded PER TILE from L2-hot w1h/w2h:
//   - w1f issued before stage_write -> B1's vmcnt drain hides latency,
//     dies at end of mm1;
//   - w2f issued after mm1 (reuses w1f's registers) -> hidden by B2,
//     dies at end of mm2.
// asm-opaque pointer per iteration stops LICM from hoisting the loads back
// out (which would silently restore the 64-reg residency).
__global__ void __launch_bounds__(256, 4)
k_fused_mfma(const __half* __restrict__ feats,
             const int* __restrict__ knn_idx,
             const __half* __restrict__ w1h,
             const __half* __restrict__ w2h,
             const float* __restrict__ ab1,
             float* __restrict__ gsum2,
             float* __restrict__ gsumsq2,
             float* __restrict__ wsmax,
             float* __restrict__ wsmin) {
    __shared__ __align__(16) __half nf[8192];     // 16 KB, swizzled chunks
    __shared__ __align__(16) __half y1s[8192];    // 16 KB, same swizzled layout
    __shared__ int rowb[TPB_TILES*64];
    int tid = threadIdx.x;
    int lane = tid & 63, wid = tid >> 6;
    int m = lane & 15, q = lane >> 4;

    fill_bases(knn_idx, blockIdx.x, tid, rowb);

    // per-thread weight base: row (wid*32 + m), col q*8; frag (ob,t) at
    // byte offset ob*16*CC*2 + t*64
    const __half* w1base = w1h + (wid*32 + m)*CC + q*8;
    const __half* w2base = w2h + (wid*32 + m)*CC + q*8;

    f32x4 a1v[2], c1v[2];
#pragma unroll
    for (int ob = 0; ob < 2; ++ob) {
        a1v[ob] = *(const f32x4*)(ab1 + wid*32 + ob*16 + q*4);
        c1v[ob] = *(const f32x4*)(ab1 + CC + wid*32 + ob*16 + q*4);
    }
    f32x4 zero4 = {0.f, 0.f, 0.f, 0.f};
    f32x4 ssum[2] = {zero4, zero4}, ssq[2] = {zero4, zero4};

    __syncthreads();
    uint4 pf[4];
    stage_load(feats, rowb, blockIdx.x, 0, tid, pf);

    for (int it = 0; it < TPB_TILES; ++it) {
        int tile = blockIdx.x * TPB_TILES + it;

        // issue w1 fragment loads (L2-hot); latency hidden by B1's drain
        const __half* w1p = w1base;
        asm volatile("" : "+v"(w1p));          // opaque: no LICM hoist
        half8 w1f[2][4];
#pragma unroll
        for (int ob = 0; ob < 2; ++ob)
#pragma unroll
            for (int t = 0; t < 4; ++t)
                w1f[ob][t] = *(const half8*)(w1p + ob*16*CC + t*32);

        stage_write(feats, blockIdx.x, it, tid, pf, nf);
        __syncthreads();                               // B1
        if (it + 1 < TPB_TILES) stage_load(feats, rowb, blockIdx.x, it + 1, tid, pf);

        f32x4 acc[2][4];
#pragma unroll
        for (int ob = 0; ob < 2; ++ob)
#pragma unroll
            for (int rbk = 0; rbk < 4; ++rbk) acc[ob][rbk] = zero4;

        // mm1: z1^T = w1 . nf^T
#pragma unroll
        for (int t = 0; t < 4; ++t) {
            int kct = t*4 + q;
            int sw = m ^ kct;
#pragma unroll
            for (int rbk = 0; rbk < 4; ++rbk) {
                half8 bfr = *(const half8*)(nf + (rbk*256 + kct*16 + sw)*8);
                acc[0][rbk] = __builtin_amdgcn_mfma_f32_16x16x32_f16(w1f[0][t], bfr, acc[0][rbk], 0, 0, 0);
                acc[1][rbk] = __builtin_amdgcn_mfma_f32_16x16x32_f16(w1f[1][t], bfr, acc[1][rbk], 0, 0, 0);
            }
        }

        // issue w2 fragment loads (reuse w1f's registers); hidden by B2
        const __half* w2p = w2base;
        asm volatile("" : "+v"(w2p));          // opaque: no LICM hoist
        half8 w2f[2][4];
#pragma unroll
        for (int ob = 0; ob < 2; ++ob)
#pragma unroll
            for (int t = 0; t < 4; ++t)
                w2f[ob][t] = *(const half8*)(w2p + ob*16*CC + t*32);

        // bn1 + relu, write y1 in swizzled chunk layout
#pragma unroll
        for (int ob = 0; ob < 2; ++ob)
#pragma unroll
            for (int rbk = 0; rbk < 4; ++rbk) {
                f32x4 z = acc[ob][rbk];
                float y0 = relu_(fmaf(a1v[ob][0], z[0], c1v[ob][0]));
                float y1 = relu_(fmaf(a1v[ob][1], z[1], c1v[ob][1]));
                float y2 = relu_(fmaf(a1v[ob][2], z[2], c1v[ob][2]));
                float y3 = relu_(fmaf(a1v[ob][3], z[3], c1v[ob][3]));
                H2U p0, p1;
                p0.h = __floats2half2_rn(y0, y1);
                p1.h = __floats2half2_rn(y2, y3);
                int kcy = wid*4 + ob*2 + (q >> 1);
                int C = rbk*256 + kcy*16 + (m ^ kcy);
                uint2 v; v.x = p0.u; v.y = p1.u;
                *(uint2*)(y1s + C*8 + (q & 1)*4) = v;
            }
        __syncthreads();                               // B2

        // mm2: z2^T = w2 . y1^T
#pragma unroll
        for (int ob = 0; ob < 2; ++ob)
#pragma unroll
            for (int rbk = 0; rbk < 4; ++rbk) acc[ob][rbk] = zero4;
#pragma unroll
        for (int t = 0; t < 4; ++t) {
            int kct = t*4 + q;
            int sw = m ^ kct;
#pragma unroll
            for (int rbk = 0; rbk < 4; ++rbk) {
                half8 bfr = *(const half8*)(y1s + (rbk*256 + kct*16 + sw)*8);
                acc[0][rbk] = __builtin_amdgcn_mfma_f32_16x16x32_f16(w2f[0][t], bfr, acc[0][rbk], 0, 0, 0);
                acc[1][rbk] = __builtin_amdgcn_mfma_f32_16x16x32_f16(w2f[1][t], bfr, acc[1][rbk], 0, 0, 0);
            }
        }
        // stats2
#pragma unroll
        for (int ob = 0; ob < 2; ++ob)
#pragma unroll
            for (int rbk = 0; rbk < 4; ++rbk) {
                ssum[ob] += acc[ob][rbk];
                ssq[ob]  += acc[ob][rbk]*acc[ob][rbk];
            }
        // per-pair max/min: full in-register reduce over the 16 m-lanes;
        // lane m==0 of each q-group owns channels o = wid*32+ob*16+q*4..+3
#pragma unroll
        for (int ob = 0; ob < 2; ++ob)
#pragma unroll
            for (int pr = 0; pr < 2; ++pr) {
                f32x4 a0 = acc[ob][pr*2], a1 = acc[ob][pr*2 + 1];
                f32x4 vmx, vmn;
#pragma unroll
                for (int c = 0; c < 4; ++c) {
                    vmx[c] = fmaxf(a0[c], a1[c]);
                    vmn[c] = fminf(a0[c], a1[c]);
                }
#pragma unroll
                for (int off = 1; off < 16; off <<= 1)
#pragma unroll
                    for (int c = 0; c < 4; ++c) {
                        vmx[c] = fmaxf(vmx[c], __shfl_xor(vmx[c], off));
                        vmn[c] = fminf(vmn[c], __shfl_xor(vmn[c], off));
                    }
                if (m == 0) {
                    int p = tile*2 + pr;
                    int o0 = wid*32 + ob*16 + q*4;
                    *(f32x4*)(wsmax + (size_t)p*CC + o0) = vmx;
                    *(f32x4*)(wsmin + (size_t)p*CC + o0) = vmn;
                }
            }
    }
#pragma unroll
    for (int ob = 0; ob < 2; ++ob)
#pragma unroll
        for (int c = 0; c < 4; ++c) {
            float v = ssum[ob][c], v2 = ssq[ob][c];
#pragma unroll
            for (int off = 1; off < 16; off <<= 1) {
                v  += __shfl_xor(v,  off);
                v2 += __shfl_xor(v2, off);
            }
            if (m == 0) {
                int o = wid*32 + ob*16 + q*4 + c;
                atomicAdd(&gsum2[o], v);
                atomicAdd(&gsumsq2[o], v2);
            }
        }
}

// ---------------- epilogue: bn2+relu on max/min, transpose to (B,C,N) ----------------
__global__ void __launch_bounds__(256) k_epilogue(const float* __restrict__ wsmax,
                                                  const float* __restrict__ wsmin,
                                                  const float* __restrict__ ab2,
                                                  float* __restrict__ out) {
    __shared__ float t[128*65];
    int b = blockIdx.y;
    int n0 = blockIdx.x * 64;
    int tid = threadIdx.x;
#pragma unroll
    for (int i = 0; i < 32; ++i) {
        int idx = i*256 + tid;
        int nl = idx >> 7, o = idx & 127;
        int n = n0 + nl;
        float v = 0.f;
        if (n < NN) {
            float a = ab2[o], cc = ab2[CC + o];
            size_t p = (size_t)b*NN + n;
            float z = (a >= 0.f) ? wsmax[p*CC + o] : wsmin[p*CC + o];
            v = fmaf(a, z, cc);
            v = v > 0.f ? v : 0.f;
        }
        t[o*65 + nl] = v;
    }
    __syncthreads();
#pragma unroll
    for (int i = 0; i < 32; ++i) {
        int idx = i*256 + tid;
        int o = idx >> 6, nl = idx & 63;
        int n = n0 + nl;
        if (n < NN) out[((size_t)b*CC + o)*NN + n] = t[o*65 + nl];
    }
}

extern "C" void kernel_launch(void* const* d_in, const int* in_sizes, int n_in,
                              void* d_out, int out_size, void* d_ws, size_t ws_size,
                              hipStream_t stream) {
    const float* x      = (const float*)d_in[0];
    const float* coords = (const float*)d_in[1];
    const float* w1     = (const float*)d_in[2];
    const float* g1     = (const float*)d_in[3];
    const float* b1     = (const float*)d_in[4];
    const float* w2     = (const float*)d_in[5];
    const float* g2     = (const float*)d_in[6];
    const float* b2     = (const float*)d_in[7];
    float* out = (float*)d_out;

    char* ws = (char*)d_ws;
    size_t off = 0;
    int* knn_idx = (int*)(ws + off);   off += (size_t)ROWS * sizeof(int);        // 3.32 MB
    float* stats = (float*)(ws + off); off += 1024 * sizeof(float);
    float* gsum2 = stats + 256, *gsq2 = stats + 384;
    float* ab1   = stats + 512;
    float* ab2   = stats + 768;
    __half* feats = (__half*)(ws + off); off += (size_t)BB*NN*DD * sizeof(__half); // 3.32 MB
    __half* w1h   = (__half*)(ws + off); off += CC*CC * sizeof(__half);
    __half* w2h   = (__half*)(ws + off); off += CC*CC * sizeof(__half);
    float* wsmax = (float*)(ws + off);  off += (size_t)PAIRS*CC * sizeof(float);  // 13.3 MB
    float* wsmin = (float*)(ws + off);  off += (size_t)PAIRS*CC * sizeof(float);  // 13.3 MB
    int*   cnt   = (int*)(ws + off);    off += (size_t)PAIRS * sizeof(int);       // 104 KB
    float* Mfin  = (float*)(ws + off);  off += (size_t)MSTRIDE * sizeof(float);   // 50 KB
    // aliases (dead before k_fused writes wsmax/wsmin):
    float* s_arr = wsmax;                    // PAIRS*64 fp32 = 6.64 MB  (<13.3)
    float* Mpart = wsmin;                    // 128*12416 fp32 = 6.36 MB (<13.3)
    (void)ws_size; (void)in_sizes; (void)n_in; (void)out_size;

    hipMemsetAsync(stats, 0, 512 * sizeof(float), stream);
    hipMemsetAsync(cnt, 0, (size_t)PAIRS * sizeof(int), stream);

    dim3 gT((NN + 63)/64, BB);
    k_prep_feats<<<gT, 256, 0, stream>>>(x, feats);
    k_convert_w<<<64, 256, 0, stream>>>(w1, w2, w1h, w2h);
    k_knn<<<PAIRS, 64, 0, stream>>>(coords, knn_idx, cnt);
    k_gather_sum<<<PAIRS/4, 256, 0, stream>>>(feats, knn_idx, s_arr);
    k_gram<<<GRAM_BLOCKS, 256, 0, stream>>>(feats, s_arr, cnt, Mpart);
    k_gram_reduce<<<(MSTRIDE + 255)/256, 256, 0, stream>>>(Mpart, Mfin);
    k_stats1<<<CC, 256, 0, stream>>>(Mfin, w1h, g1, b1, ab1);
    k_fused_mfma<<<GRID_MM, 256, 0, stream>>>(feats, knn_idx, w1h, w2h, ab1,
                                              gsum2, gsq2, wsmax, wsmin);
    k_finalize<<<1, CC, 0, stream>>>(gsum2, gsq2, g2, b2, ab2);
    dim3 gE((NN + 63)/64, BB);
    k_epilogue<<<gE, 256, 0, stream>>>(wsmax, wsmin, ab2, out);
}

// Round 5
// 578.148 us; speedup vs baseline: 1.1953x; 1.0479x over previous
//
#include <hip/hip_runtime.h>
#include <hip/hip_fp16.h>
#include <stdint.h>

#define BB 16
#define NN 1620
#define DD 64
#define CC 128
#define KK 32
#define EPSV 1e-5f
#define PAIRS (BB*NN)            // 25920
#define ROWS  (PAIRS*KK)         // 829440
#define TILES (PAIRS/2)          // 12960 tiles of 64 rows
#define TPB_TILES 8
#define GRID_MM (TILES/TPB_TILES) // 1620
#define NCHUNK 26                // ceil(1620/64)
#define GRAM_BLOCKS 128
#define MSTRIDE 12416            // 3*4096 mats + 64 vcf + 64 vf

typedef _Float16 half8 __attribute__((ext_vector_type(8)));
typedef float f32x4 __attribute__((ext_vector_type(4)));

__device__ __forceinline__ float relu_(float v){ return v > 0.f ? v : 0.f; }

union H2U { __half2 h; unsigned u; };

// ---------------- x (B,D,N) fp32 -> feats (B,N,D) fp16 ----------------
__global__ void __launch_bounds__(256) k_prep_feats(const float* __restrict__ x,
                                                    __half* __restrict__ feats) {
    __shared__ float t[64*65];
    int b = blockIdx.y;
    int n0 = blockIdx.x * 64;
    int tid = threadIdx.x;
#pragma unroll
    for (int i = 0; i < 16; ++i) {
        int idx = i*256 + tid;
        int d = idx >> 6, nl = idx & 63;
        int n = n0 + nl;
        float v = 0.f;
        if (n < NN) v = x[((size_t)b*DD + d)*NN + n];
        t[d*65 + nl] = v;
    }
    __syncthreads();
#pragma unroll
    for (int i = 0; i < 8; ++i) {
        int idx = i*256 + tid;            // 64 nl x 32 d-pairs
        int nl = idx >> 5, dp = idx & 31;
        int n = n0 + nl;
        if (n < NN) {
            __half2 h = __floats2half2_rn(t[(dp*2)*65 + nl], t[(dp*2+1)*65 + nl]);
            *(__half2*)(feats + ((size_t)b*NN + n)*DD + dp*2) = h;
        }
    }
}

// ---------------- w fp32 -> fp16 (same [o][c] layout) ----------------
__global__ void k_convert_w(const float* __restrict__ w1, const float* __restrict__ w2,
                            __half* __restrict__ w1h, __half* __restrict__ w2h) {
    int i = blockIdx.x*256 + threadIdx.x;   // 64 blocks * 256 = 16384
    w1h[i] = __float2half(w1[i]);
    w2h[i] = __float2half(w2[i]);
}

// ---------------- KNN: radix-histogram rank selection + neighbor-count histogram ----------------
__global__ void __launch_bounds__(64) k_knn(const float* __restrict__ coords,
                                            int* __restrict__ idx_out,
                                            int* __restrict__ cnt) {
#pragma clang fp contract(off)
    __shared__ int hist[256];
    __shared__ unsigned bcast[2];   // [0]=bucket, [1]=count below bucket
    int p = blockIdx.x;
    int b = p / NN, n = p - b*NN;
    int lane = threadIdx.x;
    const float* cb = coords + (size_t)b*NN*3;
    float qx = cb[n*3+0], qy = cb[n*3+1], qz = cb[n*3+2];
    float sqn = (qx*qx + qy*qy) + qz*qz;

    unsigned key[NCHUNK];
#pragma unroll
    for (int i = 0; i < NCHUNK; ++i) {
        int m = lane + i*64;
        unsigned u = 0xFFFFFFFFu;
        if (m < NN) {
            float cx = cb[m*3+0], cy = cb[m*3+1], cz = cb[m*3+2];
            float sqm = (cx*cx + cy*cy) + cz*cz;
            float dot = (qx*cx + qy*cy) + qz*cz;
            float d = (sqn + sqm) - 2.0f*dot;
            unsigned t = __float_as_uint(d);
            u = (t & 0x80000000u) ? ~t : (t | 0x80000000u);
        }
        key[i] = u;
    }

    // ---- pass A: histogram on key[31:24] ----
#pragma unroll
    for (int i = 0; i < 4; ++i) hist[lane + i*64] = 0;
    __syncthreads();
#pragma unroll
    for (int i = 0; i < NCHUNK; ++i) {
        int m = lane + i*64;
        if (m < NN) atomicAdd(&hist[key[i] >> 24], 1);
    }
    __syncthreads();
    {
        int v0 = hist[lane*4+0], v1 = hist[lane*4+1], v2 = hist[lane*4+2], v3 = hist[lane*4+3];
        int c1 = v0+v1, c2 = c1+v2, c3 = c2+v3;
        int inc = c3;
#pragma unroll
        for (int off = 1; off < 64; off <<= 1) {
            int t = __shfl_up(inc, off);
            if (lane >= off) inc += t;
        }
        int base = inc - c3;
        if (base < KK) {
            int u0 = base+v0, u1 = base+c1, u2 = base+c2, u3 = base+c3;
            if      (u0 >= KK) { bcast[0] = lane*4+0; bcast[1] = base; }
            else if (u1 >= KK) { bcast[0] = lane*4+1; bcast[1] = u0; }
            else if (u2 >= KK) { bcast[0] = lane*4+2; bcast[1] = u1; }
            else if (u3 >= KK) { bcast[0] = lane*4+3; bcast[1] = u2; }
        }
    }
    __syncthreads();
    unsigned BA = bcast[0];
    int rA = KK - (int)bcast[1];
    __syncthreads();

    // ---- pass B: histogram on key[23:16] within bucket BA ----
#pragma unroll
    for (int i = 0; i < 4; ++i) hist[lane + i*64] = 0;
    __syncthreads();
#pragma unroll
    for (int i = 0; i < NCHUNK; ++i) {
        int m = lane + i*64;
        if (m < NN && (key[i] >> 24) == BA) atomicAdd(&hist[(key[i] >> 16) & 255], 1);
    }
    __syncthreads();
    {
        int v0 = hist[lane*4+0], v1 = hist[lane*4+1], v2 = hist[lane*4+2], v3 = hist[lane*4+3];
        int c1 = v0+v1, c2 = c1+v2, c3 = c2+v3;
        int inc = c3;
#pragma unroll
        for (int off = 1; off < 64; off <<= 1) {
            int t = __shfl_up(inc, off);
            if (lane >= off) inc += t;
        }
        int base = inc - c3;
        if (base < rA) {
            int u0 = base+v0, u1 = base+c1, u2 = base+c2, u3 = base+c3;
            if      (u0 >= rA) { bcast[0] = lane*4+0; bcast[1] = base; }
            else if (u1 >= rA) { bcast[0] = lane*4+1; bcast[1] = u0; }
            else if (u2 >= rA) { bcast[0] = lane*4+2; bcast[1] = u1; }
            else if (u3 >= rA) { bcast[0] = lane*4+3; bcast[1] = u2; }
        }
    }
    __syncthreads();
    unsigned prefix16 = (BA << 8) | bcast[0];
    int r = rA - (int)bcast[1];

    // ---- extract exact 32nd (key, m) pair ----
    unsigned long long fl = 0;
    for (int round = 0; round < r; ++round) {
        unsigned long long best = ~0ull;
#pragma unroll
        for (int i = 0; i < NCHUNK; ++i) {
            if ((key[i] >> 16) == prefix16) {
                unsigned long long v = ((unsigned long long)key[i] << 32) | (unsigned)(lane + i*64);
                if (v > fl && v < best) best = v;
            }
        }
#pragma unroll
        for (int off = 32; off; off >>= 1) {
            unsigned long long o = __shfl_xor(best, off, 64);
            if (o < best) best = o;
        }
        fl = best;
    }
    unsigned kstar = (unsigned)(fl >> 32);
    unsigned mstar = (unsigned)fl;

    int cnt_ = 0;
    unsigned long long mylow = (1ull << lane) - 1ull;
#pragma unroll
    for (int i = 0; i < NCHUNK; ++i) {
        unsigned m = lane + i*64;
        bool sel = (key[i] < kstar) || (key[i] == kstar && m <= mstar);
        unsigned long long bal = __ballot(sel);
        if (sel) {
            int pos = cnt_ + __popcll(bal & mylow);
            idx_out[p*KK + pos] = (int)m;
            atomicAdd(&cnt[b*NN + (int)m], 1);
        }
        cnt_ += __popcll(bal);
    }
}

// ---------------- gather-sum: s_p = sum_k f_nb(p,k), fp32 ----------------
__global__ void __launch_bounds__(256) k_gather_sum(const __half* __restrict__ feats,
                                                    const int* __restrict__ knn_idx,
                                                    float* __restrict__ s_arr) {
    int w = threadIdx.x >> 6, lane = threadIdx.x & 63;
    int p = blockIdx.x*4 + w;
    int b = p / NN;
    int bbase = b*NN;
    int idx = 0;
    if (lane < KK) idx = knn_idx[p*KK + lane];
    float s = 0.f;
#pragma unroll
    for (int k = 0; k < KK; ++k) {
        int nb = __shfl(idx, k);
        s += __half2float(feats[((size_t)(bbase + nb))*DD + lane]);
    }
    s_arr[(size_t)p*DD + lane] = s;
}

// ---------------- gram: per-block partial M1/M2/M3 + vectors ----------------
// M1 = sum cnt_m f f^T, M2 = sum s_p f_p^T, M3 = sum f f^T, vcf = sum cnt f, vf = sum f
__global__ void __launch_bounds__(256) k_gram(const __half* __restrict__ feats,
                                              const float* __restrict__ s_arr,
                                              const int* __restrict__ cnt,
                                              float* __restrict__ Mpart) {
    __shared__ float fs[4][64];
    __shared__ float ss[4][64];
    __shared__ float cs[4];
    int tid = threadIdx.x;
    int rt = tid >> 4, ct = tid & 15;
    int r0 = rt*4, c0 = ct*4;
    float m1a[4][4] = {{0}}, m2a[4][4] = {{0}}, m3a[4][4] = {{0}};
    float vcf4[4] = {0,0,0,0}, vf4[4] = {0,0,0,0};

    int per = (PAIRS + GRAM_BLOCKS - 1)/GRAM_BLOCKS;   // 203
    int p0 = blockIdx.x * per;
    int p1 = p0 + per; if (p1 > PAIRS) p1 = PAIRS;

    for (int pc = p0; pc < p1; pc += 4) {
        __syncthreads();
        int sub = tid >> 6, l = tid & 63;
        int pp = pc + sub;
        if (pp < p1) {
            fs[sub][l] = __half2float(feats[(size_t)pp*DD + l]);
            ss[sub][l] = s_arr[(size_t)pp*DD + l];
            if (l == 0) cs[sub] = (float)cnt[pp];
        }
        __syncthreads();
        int e = p1 - pc; if (e > 4) e = 4;
        for (int j = 0; j < e; ++j) {
            float cn = cs[j];
            float fr[4], sr[4], fc[4];
#pragma unroll
            for (int a = 0; a < 4; ++a) { fr[a] = fs[j][r0+a]; sr[a] = ss[j][r0+a]; fc[a] = fs[j][c0+a]; }
#pragma unroll
            for (int a = 0; a < 4; ++a) {
                float cfr = cn * fr[a];
#pragma unroll
                for (int bc = 0; bc < 4; ++bc) {
                    m1a[a][bc] = fmaf(cfr,   fc[bc], m1a[a][bc]);
                    m2a[a][bc] = fmaf(sr[a], fc[bc], m2a[a][bc]);
                    m3a[a][bc] = fmaf(fr[a], fc[bc], m3a[a][bc]);
                }
                if (ct == 0) { vcf4[a] += cfr; vf4[a] += fr[a]; }
            }
        }
    }
    float* out = Mpart + (size_t)blockIdx.x * MSTRIDE;
#pragma unroll
    for (int a = 0; a < 4; ++a)
#pragma unroll
        for (int bc = 0; bc < 4; ++bc) {
            int idx = (r0+a)*64 + c0+bc;
            out[idx]        = m1a[a][bc];
            out[4096 + idx] = m2a[a][bc];
            out[8192 + idx] = m3a[a][bc];
        }
    if (ct == 0)
#pragma unroll
        for (int a = 0; a < 4; ++a) {
            out[12288 + r0+a] = vcf4[a];
            out[12352 + r0+a] = vf4[a];
        }
}

__global__ void __launch_bounds__(256) k_gram_reduce(const float* __restrict__ Mpart,
                                                     float* __restrict__ Mfin) {
    int e = blockIdx.x*256 + threadIdx.x;
    if (e < MSTRIDE) {
        float s = 0.f;
        for (int p = 0; p < GRAM_BLOCKS; ++p) s += Mpart[(size_t)p*MSTRIDE + e];
        Mfin[e] = s;
    }
}

// ---------------- stats1 from Gram: one block per output channel o ----------------
__global__ void __launch_bounds__(256) k_stats1(const float* __restrict__ M,
                                                const __half* __restrict__ w1h,
                                                const float* __restrict__ g1,
                                                const float* __restrict__ b1,
                                                float* __restrict__ ab1) {
    __shared__ float wl[64], wr[64];
    __shared__ float redA[256], redB[256];
    int o = blockIdx.x, tid = threadIdx.x;
    if (tid < 64)       wl[tid]    = __half2float(w1h[o*CC + tid]);
    else if (tid < 128) wr[tid-64] = __half2float(w1h[o*CC + tid]);
    __syncthreads();
    const float* M1 = M;
    const float* M2 = M + 4096;
    const float* M3 = M + 8192;
    const float* vcf = M + 12288;
    const float* vf  = M + 12352;
    float part = 0.f;
    for (int e = tid; e < 4096; e += 256) {
        int i = e >> 6, j = e & 63;
        float m1 = M1[e], m2 = M2[e], m2t = M2[j*64 + i], m3 = M3[e];
        float A  = m1 - m2 - m2t + 32.f*m3;   // sum u u^T
        float Bc = m2 - 32.f*m3;              // sum u v^T
        part += wl[i]*(A*wl[j] + 2.f*Bc*wr[j]) + 32.f*wr[i]*m3*wr[j];
    }
    float psum = 0.f;
    if (tid < 64) psum = wl[tid]*(vcf[tid] - 32.f*vf[tid]) + 32.f*wr[tid]*vf[tid];
    redA[tid] = part; redB[tid] = psum;
    __syncthreads();
    for (int s = 128; s > 0; s >>= 1) {
        if (tid < s) { redA[tid] += redA[tid+s]; redB[tid] += redB[tid+s]; }
        __syncthreads();
    }
    if (tid == 0) {
        float sumsq = redA[0], sum = redB[0];
        float mean = sum / (float)ROWS;
        float var  = sumsq / (float)ROWS - mean*mean;
        float a = g1[o] * rsqrtf(var + EPSV);
        ab1[o] = a;
        ab1[CC + o] = b1[o] - mean*a;
    }
}

// ============ staging helpers: coalesced gather + XOR-swizzled LDS ============
// ctr base (p*DD) is pure arithmetic of (blk, tloc, row) -> no LDS array needed.
__device__ __forceinline__ void fill_bases(const int* __restrict__ knn_idx,
                                           int blk, int tid, int* rowb) {
#pragma unroll
    for (int e = tid; e < TPB_TILES*64; e += 256) {
        int tile = blk*TPB_TILES + (e >> 6);
        int rr = e & 63;
        int p = tile*2 + (rr >> 5);
        int nb = knn_idx[p*KK + (rr & 31)];
        int b = p / NN;
        rowb[e] = (b*NN + nb)*DD;
    }
}

__device__ __forceinline__ void stage_load(const __half* __restrict__ feats,
                                           const int* rowb, int blk,
                                           int tloc, int tid, uint4* A) {
    int kc = tid & 15;
#pragma unroll
    for (int it = 0; it < 4; ++it) {
        int row = it*16 + (tid >> 4);
        int e = tloc*64 + row;
        int p = (blk*TPB_TILES + tloc)*2 + (row >> 5);
        int ra = (kc < 8) ? (rowb[e] + kc*8) : (p*DD + (kc-8)*8);
        A[it] = *(const uint4*)(feats + ra);
    }
}

// stage_write: no global re-load of the center row. Lane kc>=8's prefetched
// A[it] IS the center at cols (kc-8)*8; lane kc<8 needs cols kc*8 -> exactly
// lane (kc^8)'s A[it]. A 4-word shfl_xor replaces an L2-latency gather on the
// B1 critical path.
__device__ __forceinline__ void stage_write(int tid, const uint4* A, __half* nf) {
    int kc = tid & 15;
#pragma unroll
    for (int it = 0; it < 4; ++it) {
        int row = it*16 + (tid >> 4);
        union { uint4 u; __half2 h[4]; } a, b, rr;
        a.u = A[it];
        b.u.x = (unsigned)__shfl_xor((int)a.u.x, 8);
        b.u.y = (unsigned)__shfl_xor((int)a.u.y, 8);
        b.u.z = (unsigned)__shfl_xor((int)a.u.z, 8);
        b.u.w = (unsigned)__shfl_xor((int)a.u.w, 8);
        if (kc < 8) {
#pragma unroll
            for (int j = 0; j < 4; ++j) rr.h[j] = __hsub2(a.h[j], b.h[j]);
        } else {
            rr.u = a.u;
        }
        int C = (row >> 4)*256 + kc*16 + ((row & 15) ^ kc);   // XOR swizzle
        *(uint4*)(nf + C*8) = rr.u;
    }
}

// ---------------- finalize bn params (layer 2) ----------------
__global__ void k_finalize(const float* __restrict__ gsum, const float* __restrict__ gsumsq,
                           const float* __restrict__ g, const float* __restrict__ bb,
                           float* __restrict__ ab) {
    int o = threadIdx.x;
    float cnt = (float)ROWS;
    float mean = gsum[o] / cnt;
    float var = gsumsq[o] / cnt - mean*mean;
    float a = g[o] * rsqrtf(var + EPSV);
    ab[o] = a;
    ab[CC + o] = bb[o] - mean*a;
}

// ---------------- fused: mm1 + bn1relu + mm2 + stats2 + per-pair max/min ----------------
// LDS = nf 16K + y1s 16K + rowb 2K + abs 1K = 35 KB -> 4 blocks/CU.
// Register budget model (rounds 0-4): counter VGPR_Count = ARCH regs only;
// real constraint is arch+acc <= 512/waves_per_EU. launch_bounds(256,4)
// pins total=128. Demand is trimmed under that:
//   - w1f/w2f reloaded per tile from L2-hot w1h/w2h (not resident): -64
//   - bn1 scale/bias a1v/c1v moved to LDS (broadcast reads):         -16
//   - center row recovered from pf via shfl_xor(8) in stage_write (no
//     per-tile global re-load, shorter B1 critical path)
// Peak live ~110 (acc 32 + wf 32 + pf 16 + ssum/ssq 16 + addr ~14) < 128.
__global__ void __launch_bounds__(256, 4)
k_fused_mfma(const __half* __restrict__ feats,
             const int* __restrict__ knn_idx,
             const __half* __restrict__ w1h,
             const __half* __restrict__ w2h,
             const float* __restrict__ ab1,
             float* __restrict__ gsum2,
             float* __restrict__ gsumsq2,
             float* __restrict__ wsmax,
             float* __restrict__ wsmin) {
    __shared__ __align__(16) __half nf[8192];     // 16 KB, swizzled chunks
    __shared__ __align__(16) __half y1s[8192];    // 16 KB, same swizzled layout
    __shared__ __align__(16) float abs_lds[256];  // bn1 a (0..127), c (128..255)
    __shared__ int rowb[TPB_TILES*64];
    int tid = threadIdx.x;
    int lane = tid & 63, wid = tid >> 6;
    int m = lane & 15, q = lane >> 4;

    fill_bases(knn_idx, blockIdx.x, tid, rowb);
    abs_lds[tid] = ab1[tid];

    // per-thread weight base: row (wid*32 + m), col q*8; frag (ob,t) at
    // offset ob*16*CC + t*32 halves
    const __half* w1base = w1h + (wid*32 + m)*CC + q*8;
    const __half* w2base = w2h + (wid*32 + m)*CC + q*8;

    f32x4 zero4 = {0.f, 0.f, 0.f, 0.f};
    f32x4 ssum[2] = {zero4, zero4}, ssq[2] = {zero4, zero4};

    __syncthreads();
    uint4 pf[4];
    stage_load(feats, rowb, blockIdx.x, 0, tid, pf);

    for (int it = 0; it < TPB_TILES; ++it) {
        int tile = blockIdx.x * TPB_TILES + it;

        // issue w1 fragment loads (L2-hot); latency hidden by B1's drain
        const __half* w1p = w1base;
        asm volatile("" : "+v"(w1p));          // opaque: no LICM hoist
        half8 w1f[2][4];
#pragma unroll
        for (int ob = 0; ob < 2; ++ob)
#pragma unroll
            for (int t = 0; t < 4; ++t)
                w1f[ob][t] = *(const half8*)(w1p + ob*16*CC + t*32);

        stage_write(tid, pf, nf);
        __syncthreads();                               // B1
        if (it + 1 < TPB_TILES) stage_load(feats, rowb, blockIdx.x, it + 1, tid, pf);

        f32x4 acc[2][4];
#pragma unroll
        for (int ob = 0; ob < 2; ++ob)
#pragma unroll
            for (int rbk = 0; rbk < 4; ++rbk) acc[ob][rbk] = zero4;

        // mm1: z1^T = w1 . nf^T
#pragma unroll
        for (int t = 0; t < 4; ++t) {
            int kct = t*4 + q;
            int sw = m ^ kct;
#pragma unroll
            for (int rbk = 0; rbk < 4; ++rbk) {
                half8 bfr = *(const half8*)(nf + (rbk*256 + kct*16 + sw)*8);
                acc[0][rbk] = __builtin_amdgcn_mfma_f32_16x16x32_f16(w1f[0][t], bfr, acc[0][rbk], 0, 0, 0);
                acc[1][rbk] = __builtin_amdgcn_mfma_f32_16x16x32_f16(w1f[1][t], bfr, acc[1][rbk], 0, 0, 0);
            }
        }

        // issue w2 fragment loads (reuse w1f's registers); hidden by B2
        const __half* w2p = w2base;
        asm volatile("" : "+v"(w2p));          // opaque: no LICM hoist
        half8 w2f[2][4];
#pragma unroll
        for (int ob = 0; ob < 2; ++ob)
#pragma unroll
            for (int t = 0; t < 4; ++t)
                w2f[ob][t] = *(const half8*)(w2p + ob*16*CC + t*32);

        // bn1 + relu, write y1 in swizzled chunk layout (a/c from LDS,
        // 16 m-lanes read the same address -> broadcast, conflict-free)
#pragma unroll
        for (int ob = 0; ob < 2; ++ob) {
            f32x4 av = *(const f32x4*)(abs_lds + wid*32 + ob*16 + q*4);
            f32x4 cv = *(const f32x4*)(abs_lds + 128 + wid*32 + ob*16 + q*4);
#pragma unroll
            for (int rbk = 0; rbk < 4; ++rbk) {
                f32x4 z = acc[ob][rbk];
                float y0 = relu_(fmaf(av[0], z[0], cv[0]));
                float y1 = relu_(fmaf(av[1], z[1], cv[1]));
                float y2 = relu_(fmaf(av[2], z[2], cv[2]));
                float y3 = relu_(fmaf(av[3], z[3], cv[3]));
                H2U p0, p1;
                p0.h = __floats2half2_rn(y0, y1);
                p1.h = __floats2half2_rn(y2, y3);
                int kcy = wid*4 + ob*2 + (q >> 1);
                int C = rbk*256 + kcy*16 + (m ^ kcy);
                uint2 v; v.x = p0.u; v.y = p1.u;
                *(uint2*)(y1s + C*8 + (q & 1)*4) = v;
            }
        }
        __syncthreads();                               // B2

        // mm2: z2^T = w2 . y1^T
#pragma unroll
        for (int ob = 0; ob < 2; ++ob)
#pragma unroll
            for (int rbk = 0; rbk < 4; ++rbk) acc[ob][rbk] = zero4;
#pragma unroll
        for (int t = 0; t < 4; ++t) {
            int kct = t*4 + q;
            int sw = m ^ kct;
#pragma unroll
            for (int rbk = 0; rbk < 4; ++rbk) {
                half8 bfr = *(const half8*)(y1s + (rbk*256 + kct*16 + sw)*8);
                acc[0][rbk] = __builtin_amdgcn_mfma_f32_16x16x32_f16(w2f[0][t], bfr, acc[0][rbk], 0, 0, 0);
                acc[1][rbk] = __builtin_amdgcn_mfma_f32_16x16x32_f16(w2f[1][t], bfr, acc[1][rbk], 0, 0, 0);
            }
        }
        // stats2
#pragma unroll
        for (int ob = 0; ob < 2; ++ob)
#pragma unroll
            for (int rbk = 0; rbk < 4; ++rbk) {
                ssum[ob] += acc[ob][rbk];
                ssq[ob]  += acc[ob][rbk]*acc[ob][rbk];
            }
        // per-pair max/min: full in-register reduce over the 16 m-lanes;
        // lane m==0 of each q-group owns channels o = wid*32+ob*16+q*4..+3
#pragma unroll
        for (int ob = 0; ob < 2; ++ob)
#pragma unroll
            for (int pr = 0; pr < 2; ++pr) {
                f32x4 a0 = acc[ob][pr*2], a1 = acc[ob][pr*2 + 1];
                f32x4 vmx, vmn;
#pragma unroll
                for (int c = 0; c < 4; ++c) {
                    vmx[c] = fmaxf(a0[c], a1[c]);
                    vmn[c] = fminf(a0[c], a1[c]);
                }
#pragma unroll
                for (int off = 1; off < 16; off <<= 1)
#pragma unroll
                    for (int c = 0; c < 4; ++c) {
                        vmx[c] = fmaxf(vmx[c], __shfl_xor(vmx[c], off));
                        vmn[c] = fminf(vmn[c], __shfl_xor(vmn[c], off));
                    }
                if (m == 0) {
                    int p = tile*2 + pr;
                    int o0 = wid*32 + ob*16 + q*4;
                    *(f32x4*)(wsmax + (size_t)p*CC + o0) = vmx;
                    *(f32x4*)(wsmin + (size_t)p*CC + o0) = vmn;
                }
            }
    }
#pragma unroll
    for (int ob = 0; ob < 2; ++ob)
#pragma unroll
        for (int c = 0; c < 4; ++c) {
            float v = ssum[ob][c], v2 = ssq[ob][c];
#pragma unroll
            for (int off = 1; off < 16; off <<= 1) {
                v  += __shfl_xor(v,  off);
                v2 += __shfl_xor(v2, off);
            }
            if (m == 0) {
                int o = wid*32 + ob*16 + q*4 + c;
                atomicAdd(&gsum2[o], v);
                atomicAdd(&gsumsq2[o], v2);
            }
        }
}

// ---------------- epilogue: bn2+relu on max/min, transpose to (B,C,N) ----------------
__global__ void __launch_bounds__(256) k_epilogue(const float* __restrict__ wsmax,
                                                  const float* __restrict__ wsmin,
                                                  const float* __restrict__ ab2,
                                                  float* __restrict__ out) {
    __shared__ float t[128*65];
    int b = blockIdx.y;
    int n0 = blockIdx.x * 64;
    int tid = threadIdx.x;
#pragma unroll
    for (int i = 0; i < 32; ++i) {
        int idx = i*256 + tid;
        int nl = idx >> 7, o = idx & 127;
        int n = n0 + nl;
        float v = 0.f;
        if (n < NN) {
            float a = ab2[o], cc = ab2[CC + o];
            size_t p = (size_t)b*NN + n;
            float z = (a >= 0.f) ? wsmax[p*CC + o] : wsmin[p*CC + o];
            v = fmaf(a, z, cc);
            v = v > 0.f ? v : 0.f;
        }
        t[o*65 + nl] = v;
    }
    __syncthreads();
#pragma unroll
    for (int i = 0; i < 32; ++i) {
        int idx = i*256 + tid;
        int o = idx >> 6, nl = idx & 63;
        int n = n0 + nl;
        if (n < NN) out[((size_t)b*CC + o)*NN + n] = t[o*65 + nl];
    }
}

extern "C" void kernel_launch(void* const* d_in, const int* in_sizes, int n_in,
                              void* d_out, int out_size, void* d_ws, size_t ws_size,
                              hipStream_t stream) {
    const float* x      = (const float*)d_in[0];
    const float* coords = (const float*)d_in[1];
    const float* w1     = (const float*)d_in[2];
    const float* g1     = (const float*)d_in[3];
    const float* b1     = (const float*)d_in[4];
    const float* w2     = (const float*)d_in[5];
    const float* g2     = (const float*)d_in[6];
    const float* b2     = (const float*)d_in[7];
    float* out = (float*)d_out;

    char* ws = (char*)d_ws;
    size_t off = 0;
    int* knn_idx = (int*)(ws + off);   off += (size_t)ROWS * sizeof(int);        // 3.32 MB
    float* stats = (float*)(ws + off); off += 1024 * sizeof(float);
    float* gsum2 = stats + 256, *gsq2 = stats + 384;
    float* ab1   = stats + 512;
    float* ab2   = stats + 768;
    __half* feats = (__half*)(ws + off); off += (size_t)BB*NN*DD * sizeof(__half); // 3.32 MB
    __half* w1h   = (__half*)(ws + off); off += CC*CC * sizeof(__half);
    __half* w2h   = (__half*)(ws + off); off += CC*CC * sizeof(__half);
    float* wsmax = (float*)(ws + off);  off += (size_t)PAIRS*CC * sizeof(float);  // 13.3 MB
    float* wsmin = (float*)(ws + off);  off += (size_t)PAIRS*CC * sizeof(float);  // 13.3 MB
    int*   cnt   = (int*)(ws + off);    off += (size_t)PAIRS * sizeof(int);       // 104 KB
    float* Mfin  = (float*)(ws + off);  off += (size_t)MSTRIDE * sizeof(float);   // 50 KB
    // aliases (dead before k_fused writes wsmax/wsmin):
    float* s_arr = wsmax;                    // PAIRS*64 fp32 = 6.64 MB  (<13.3)
    float* Mpart = wsmin;                    // 128*12416 fp32 = 6.36 MB (<13.3)
    (void)ws_size; (void)in_sizes; (void)n_in; (void)out_size;

    hipMemsetAsync(stats, 0, 512 * sizeof(float), stream);
    hipMemsetAsync(cnt, 0, (size_t)PAIRS * sizeof(int), stream);

    dim3 gT((NN + 63)/64, BB);
    k_prep_feats<<<gT, 256, 0, stream>>>(x, feats);
    k_convert_w<<<64, 256, 0, stream>>>(w1, w2, w1h, w2h);
    k_knn<<<PAIRS, 64, 0, stream>>>(coords, knn_idx, cnt);
    k_gather_sum<<<PAIRS/4, 256, 0, stream>>>(feats, knn_idx, s_arr);
    k_gram<<<GRAM_BLOCKS, 256, 0, stream>>>(feats, s_arr, cnt, Mpart);
    k_gram_reduce<<<(MSTRIDE + 255)/256, 256, 0, stream>>>(Mpart, Mfin);
    k_stats1<<<CC, 256, 0, stream>>>(Mfin, w1h, g1, b1, ab1);
    k_fused_mfma<<<GRID_MM, 256, 0, stream>>>(feats, knn_idx, w1h, w2h, ab1,
                                              gsum2, gsq2, wsmax, wsmin);
    k_finalize<<<1, CC, 0, stream>>>(gsum2, gsq2, g2, b2, ab2);
    dim3 gE((NN + 63)/64, BB);
    k_epilogue<<<gE, 256, 0, stream>>>(wsmax, wsmin, ab2, out);
}

// Round 6
// 416.527 us; speedup vs baseline: 1.6591x; 1.3880x over previous
//
#include <hip/hip_runtime.h>
#include <hip/hip_fp16.h>
#include <stdint.h>

#define BB 16
#define NN 1620
#define DD 64
#define CC 128
#define KK 32
#define EPSV 1e-5f
#define PAIRS (BB*NN)            // 25920
#define ROWS  (PAIRS*KK)         // 829440
#define TILES (PAIRS/2)          // 12960 tiles of 64 rows
#define TPB_TILES 8
#define GRID_MM (TILES/TPB_TILES) // 1620
#define NCHUNK 26                // ceil(1620/64)
#define GRAM_BLOCKS 128
#define MSTRIDE 12416            // 3*4096 mats + 64 vcf + 64 vf

typedef _Float16 half8 __attribute__((ext_vector_type(8)));
typedef float f32x4 __attribute__((ext_vector_type(4)));

__device__ __forceinline__ float relu_(float v){ return v > 0.f ? v : 0.f; }

union H2U { __half2 h; unsigned u; };

// ---------------- x (B,D,N) fp32 -> feats (B,N,D) fp16 ----------------
__global__ void __launch_bounds__(256) k_prep_feats(const float* __restrict__ x,
                                                    __half* __restrict__ feats) {
    __shared__ float t[64*65];
    int b = blockIdx.y;
    int n0 = blockIdx.x * 64;
    int tid = threadIdx.x;
#pragma unroll
    for (int i = 0; i < 16; ++i) {
        int idx = i*256 + tid;
        int d = idx >> 6, nl = idx & 63;
        int n = n0 + nl;
        float v = 0.f;
        if (n < NN) v = x[((size_t)b*DD + d)*NN + n];
        t[d*65 + nl] = v;
    }
    __syncthreads();
#pragma unroll
    for (int i = 0; i < 8; ++i) {
        int idx = i*256 + tid;            // 64 nl x 32 d-pairs
        int nl = idx >> 5, dp = idx & 31;
        int n = n0 + nl;
        if (n < NN) {
            __half2 h = __floats2half2_rn(t[(dp*2)*65 + nl], t[(dp*2+1)*65 + nl]);
            *(__half2*)(feats + ((size_t)b*NN + n)*DD + dp*2) = h;
        }
    }
}

// ---------------- w fp32 -> fp16 (same [o][c] layout) ----------------
__global__ void k_convert_w(const float* __restrict__ w1, const float* __restrict__ w2,
                            __half* __restrict__ w1h, __half* __restrict__ w2h) {
    int i = blockIdx.x*256 + threadIdx.x;   // 64 blocks * 256 = 16384
    w1h[i] = __float2half(w1[i]);
    w2h[i] = __float2half(w2[i]);
}

// ---------------- KNN: radix-histogram rank selection + neighbor-count histogram ----------------
__global__ void __launch_bounds__(64) k_knn(const float* __restrict__ coords,
                                            int* __restrict__ idx_out,
                                            int* __restrict__ cnt) {
#pragma clang fp contract(off)
    __shared__ int hist[256];
    __shared__ unsigned bcast[2];   // [0]=bucket, [1]=count below bucket
    int p = blockIdx.x;
    int b = p / NN, n = p - b*NN;
    int lane = threadIdx.x;
    const float* cb = coords + (size_t)b*NN*3;
    float qx = cb[n*3+0], qy = cb[n*3+1], qz = cb[n*3+2];
    float sqn = (qx*qx + qy*qy) + qz*qz;

    unsigned key[NCHUNK];
#pragma unroll
    for (int i = 0; i < NCHUNK; ++i) {
        int m = lane + i*64;
        unsigned u = 0xFFFFFFFFu;
        if (m < NN) {
            float cx = cb[m*3+0], cy = cb[m*3+1], cz = cb[m*3+2];
            float sqm = (cx*cx + cy*cy) + cz*cz;
            float dot = (qx*cx + qy*cy) + qz*cz;
            float d = (sqn + sqm) - 2.0f*dot;
            unsigned t = __float_as_uint(d);
            u = (t & 0x80000000u) ? ~t : (t | 0x80000000u);
        }
        key[i] = u;
    }

    // ---- pass A: histogram on key[31:24] ----
#pragma unroll
    for (int i = 0; i < 4; ++i) hist[lane + i*64] = 0;
    __syncthreads();
#pragma unroll
    for (int i = 0; i < NCHUNK; ++i) {
        int m = lane + i*64;
        if (m < NN) atomicAdd(&hist[key[i] >> 24], 1);
    }
    __syncthreads();
    {
        int v0 = hist[lane*4+0], v1 = hist[lane*4+1], v2 = hist[lane*4+2], v3 = hist[lane*4+3];
        int c1 = v0+v1, c2 = c1+v2, c3 = c2+v3;
        int inc = c3;
#pragma unroll
        for (int off = 1; off < 64; off <<= 1) {
            int t = __shfl_up(inc, off);
            if (lane >= off) inc += t;
        }
        int base = inc - c3;
        if (base < KK) {
            int u0 = base+v0, u1 = base+c1, u2 = base+c2, u3 = base+c3;
            if      (u0 >= KK) { bcast[0] = lane*4+0; bcast[1] = base; }
            else if (u1 >= KK) { bcast[0] = lane*4+1; bcast[1] = u0; }
            else if (u2 >= KK) { bcast[0] = lane*4+2; bcast[1] = u1; }
            else if (u3 >= KK) { bcast[0] = lane*4+3; bcast[1] = u2; }
        }
    }
    __syncthreads();
    unsigned BA = bcast[0];
    int rA = KK - (int)bcast[1];
    __syncthreads();

    // ---- pass B: histogram on key[23:16] within bucket BA ----
#pragma unroll
    for (int i = 0; i < 4; ++i) hist[lane + i*64] = 0;
    __syncthreads();
#pragma unroll
    for (int i = 0; i < NCHUNK; ++i) {
        int m = lane + i*64;
        if (m < NN && (key[i] >> 24) == BA) atomicAdd(&hist[(key[i] >> 16) & 255], 1);
    }
    __syncthreads();
    {
        int v0 = hist[lane*4+0], v1 = hist[lane*4+1], v2 = hist[lane*4+2], v3 = hist[lane*4+3];
        int c1 = v0+v1, c2 = c1+v2, c3 = c2+v3;
        int inc = c3;
#pragma unroll
        for (int off = 1; off < 64; off <<= 1) {
            int t = __shfl_up(inc, off);
            if (lane >= off) inc += t;
        }
        int base = inc - c3;
        if (base < rA) {
            int u0 = base+v0, u1 = base+c1, u2 = base+c2, u3 = base+c3;
            if      (u0 >= rA) { bcast[0] = lane*4+0; bcast[1] = base; }
            else if (u1 >= rA) { bcast[0] = lane*4+1; bcast[1] = u0; }
            else if (u2 >= rA) { bcast[0] = lane*4+2; bcast[1] = u1; }
            else if (u3 >= rA) { bcast[0] = lane*4+3; bcast[1] = u2; }
        }
    }
    __syncthreads();
    unsigned prefix16 = (BA << 8) | bcast[0];
    int r = rA - (int)bcast[1];

    // ---- extract exact 32nd (key, m) pair ----
    unsigned long long fl = 0;
    for (int round = 0; round < r; ++round) {
        unsigned long long best = ~0ull;
#pragma unroll
        for (int i = 0; i < NCHUNK; ++i) {
            if ((key[i] >> 16) == prefix16) {
                unsigned long long v = ((unsigned long long)key[i] << 32) | (unsigned)(lane + i*64);
                if (v > fl && v < best) best = v;
            }
        }
#pragma unroll
        for (int off = 32; off; off >>= 1) {
            unsigned long long o = __shfl_xor(best, off, 64);
            if (o < best) best = o;
        }
        fl = best;
    }
    unsigned kstar = (unsigned)(fl >> 32);
    unsigned mstar = (unsigned)fl;

    int cnt_ = 0;
    unsigned long long mylow = (1ull << lane) - 1ull;
#pragma unroll
    for (int i = 0; i < NCHUNK; ++i) {
        unsigned m = lane + i*64;
        bool sel = (key[i] < kstar) || (key[i] == kstar && m <= mstar);
        unsigned long long bal = __ballot(sel);
        if (sel) {
            int pos = cnt_ + __popcll(bal & mylow);
            idx_out[p*KK + pos] = (int)m;
            atomicAdd(&cnt[b*NN + (int)m], 1);
        }
        cnt_ += __popcll(bal);
    }
}

// ---------------- gather-sum: s_p = sum_k f_nb(p,k), fp32 ----------------
__global__ void __launch_bounds__(256) k_gather_sum(const __half* __restrict__ feats,
                                                    const int* __restrict__ knn_idx,
                                                    float* __restrict__ s_arr) {
    int w = threadIdx.x >> 6, lane = threadIdx.x & 63;
    int p = blockIdx.x*4 + w;
    int b = p / NN;
    int bbase = b*NN;
    int idx = 0;
    if (lane < KK) idx = knn_idx[p*KK + lane];
    float s = 0.f;
#pragma unroll
    for (int k = 0; k < KK; ++k) {
        int nb = __shfl(idx, k);
        s += __half2float(feats[((size_t)(bbase + nb))*DD + lane]);
    }
    s_arr[(size_t)p*DD + lane] = s;
}

// ---------------- gram: per-block partial M1/M2/M3 + vectors ----------------
// M1 = sum cnt_m f f^T, M2 = sum s_p f_p^T, M3 = sum f f^T, vcf = sum cnt f, vf = sum f
__global__ void __launch_bounds__(256) k_gram(const __half* __restrict__ feats,
                                              const float* __restrict__ s_arr,
                                              const int* __restrict__ cnt,
                                              float* __restrict__ Mpart) {
    __shared__ float fs[4][64];
    __shared__ float ss[4][64];
    __shared__ float cs[4];
    int tid = threadIdx.x;
    int rt = tid >> 4, ct = tid & 15;
    int r0 = rt*4, c0 = ct*4;
    float m1a[4][4] = {{0}}, m2a[4][4] = {{0}}, m3a[4][4] = {{0}};
    float vcf4[4] = {0,0,0,0}, vf4[4] = {0,0,0,0};

    int per = (PAIRS + GRAM_BLOCKS - 1)/GRAM_BLOCKS;   // 203
    int p0 = blockIdx.x * per;
    int p1 = p0 + per; if (p1 > PAIRS) p1 = PAIRS;

    for (int pc = p0; pc < p1; pc += 4) {
        __syncthreads();
        int sub = tid >> 6, l = tid & 63;
        int pp = pc + sub;
        if (pp < p1) {
            fs[sub][l] = __half2float(feats[(size_t)pp*DD + l]);
            ss[sub][l] = s_arr[(size_t)pp*DD + l];
            if (l == 0) cs[sub] = (float)cnt[pp];
        }
        __syncthreads();
        int e = p1 - pc; if (e > 4) e = 4;
        for (int j = 0; j < e; ++j) {
            float cn = cs[j];
            float fr[4], sr[4], fc[4];
#pragma unroll
            for (int a = 0; a < 4; ++a) { fr[a] = fs[j][r0+a]; sr[a] = ss[j][r0+a]; fc[a] = fs[j][c0+a]; }
#pragma unroll
            for (int a = 0; a < 4; ++a) {
                float cfr = cn * fr[a];
#pragma unroll
                for (int bc = 0; bc < 4; ++bc) {
                    m1a[a][bc] = fmaf(cfr,   fc[bc], m1a[a][bc]);
                    m2a[a][bc] = fmaf(sr[a], fc[bc], m2a[a][bc]);
                    m3a[a][bc] = fmaf(fr[a], fc[bc], m3a[a][bc]);
                }
                if (ct == 0) { vcf4[a] += cfr; vf4[a] += fr[a]; }
            }
        }
    }
    float* out = Mpart + (size_t)blockIdx.x * MSTRIDE;
#pragma unroll
    for (int a = 0; a < 4; ++a)
#pragma unroll
        for (int bc = 0; bc < 4; ++bc) {
            int idx = (r0+a)*64 + c0+bc;
            out[idx]        = m1a[a][bc];
            out[4096 + idx] = m2a[a][bc];
            out[8192 + idx] = m3a[a][bc];
        }
    if (ct == 0)
#pragma unroll
        for (int a = 0; a < 4; ++a) {
            out[12288 + r0+a] = vcf4[a];
            out[12352 + r0+a] = vf4[a];
        }
}

__global__ void __launch_bounds__(256) k_gram_reduce(const float* __restrict__ Mpart,
                                                     float* __restrict__ Mfin) {
    int e = blockIdx.x*256 + threadIdx.x;
    if (e < MSTRIDE) {
        float s = 0.f;
        for (int p = 0; p < GRAM_BLOCKS; ++p) s += Mpart[(size_t)p*MSTRIDE + e];
        Mfin[e] = s;
    }
}

// ---------------- stats1 from Gram: one block per output channel o ----------------
__global__ void __launch_bounds__(256) k_stats1(const float* __restrict__ M,
                                                const __half* __restrict__ w1h,
                                                const float* __restrict__ g1,
                                                const float* __restrict__ b1,
                                                float* __restrict__ ab1) {
    __shared__ float wl[64], wr[64];
    __shared__ float redA[256], redB[256];
    int o = blockIdx.x, tid = threadIdx.x;
    if (tid < 64)       wl[tid]    = __half2float(w1h[o*CC + tid]);
    else if (tid < 128) wr[tid-64] = __half2float(w1h[o*CC + tid]);
    __syncthreads();
    const float* M1 = M;
    const float* M2 = M + 4096;
    const float* M3 = M + 8192;
    const float* vcf = M + 12288;
    const float* vf  = M + 12352;
    float part = 0.f;
    for (int e = tid; e < 4096; e += 256) {
        int i = e >> 6, j = e & 63;
        float m1 = M1[e], m2 = M2[e], m2t = M2[j*64 + i], m3 = M3[e];
        float A  = m1 - m2 - m2t + 32.f*m3;   // sum u u^T
        float Bc = m2 - 32.f*m3;              // sum u v^T
        part += wl[i]*(A*wl[j] + 2.f*Bc*wr[j]) + 32.f*wr[i]*m3*wr[j];
    }
    float psum = 0.f;
    if (tid < 64) psum = wl[tid]*(vcf[tid] - 32.f*vf[tid]) + 32.f*wr[tid]*vf[tid];
    redA[tid] = part; redB[tid] = psum;
    __syncthreads();
    for (int s = 128; s > 0; s >>= 1) {
        if (tid < s) { redA[tid] += redA[tid+s]; redB[tid] += redB[tid+s]; }
        __syncthreads();
    }
    if (tid == 0) {
        float sumsq = redA[0], sum = redB[0];
        float mean = sum / (float)ROWS;
        float var  = sumsq / (float)ROWS - mean*mean;
        float a = g1[o] * rsqrtf(var + EPSV);
        ab1[o] = a;
        ab1[CC + o] = b1[o] - mean*a;
    }
}

// ============ staging helpers: coalesced gather + XOR-swizzled LDS ============
// ctr base (p*DD) is pure arithmetic of (blk, tloc, row) -> no LDS array needed.
__device__ __forceinline__ void fill_bases(const int* __restrict__ knn_idx,
                                           int blk, int tid, int* rowb) {
#pragma unroll
    for (int e = tid; e < TPB_TILES*64; e += 256) {
        int tile = blk*TPB_TILES + (e >> 6);
        int rr = e & 63;
        int p = tile*2 + (rr >> 5);
        int nb = knn_idx[p*KK + (rr & 31)];
        int b = p / NN;
        rowb[e] = (b*NN + nb)*DD;
    }
}

__device__ __forceinline__ void stage_load(const __half* __restrict__ feats,
                                           const int* rowb, int blk,
                                           int tloc, int tid, uint4* A) {
    int kc = tid & 15;
#pragma unroll
    for (int it = 0; it < 4; ++it) {
        int row = it*16 + (tid >> 4);
        int e = tloc*64 + row;
        int p = (blk*TPB_TILES + tloc)*2 + (row >> 5);
        int ra = (kc < 8) ? (rowb[e] + kc*8) : (p*DD + (kc-8)*8);
        A[it] = *(const uint4*)(feats + ra);
    }
}

// stage_write: no global re-load of the center row. Lane kc>=8's prefetched
// A[it] IS the center at cols (kc-8)*8; lane kc<8 needs cols kc*8 -> exactly
// lane (kc^8)'s A[it]. A 4-word shfl_xor replaces an L2-latency gather on the
// B1 critical path.
__device__ __forceinline__ void stage_write(int tid, const uint4* A, __half* nf) {
    int kc = tid & 15;
#pragma unroll
    for (int it = 0; it < 4; ++it) {
        int row = it*16 + (tid >> 4);
        union { uint4 u; __half2 h[4]; } a, b, rr;
        a.u = A[it];
        b.u.x = (unsigned)__shfl_xor((int)a.u.x, 8);
        b.u.y = (unsigned)__shfl_xor((int)a.u.y, 8);
        b.u.z = (unsigned)__shfl_xor((int)a.u.z, 8);
        b.u.w = (unsigned)__shfl_xor((int)a.u.w, 8);
        if (kc < 8) {
#pragma unroll
            for (int j = 0; j < 4; ++j) rr.h[j] = __hsub2(a.h[j], b.h[j]);
        } else {
            rr.u = a.u;
        }
        int C = (row >> 4)*256 + kc*16 + ((row & 15) ^ kc);   // XOR swizzle
        *(uint4*)(nf + C*8) = rr.u;
    }
}

// ---------------- finalize bn params (layer 2) ----------------
__global__ void k_finalize(const float* __restrict__ gsum, const float* __restrict__ gsumsq,
                           const float* __restrict__ g, const float* __restrict__ bb,
                           float* __restrict__ ab) {
    int o = threadIdx.x;
    float cnt = (float)ROWS;
    float mean = gsum[o] / cnt;
    float var = gsumsq[o] / cnt - mean*mean;
    float a = g[o] * rsqrtf(var + EPSV);
    ab[o] = a;
    ab[CC + o] = bb[o] - mean*a;
}

// ---------------- fused: mm1 + bn1relu + mm2 + stats2 + per-pair max/min ----------------
// Operating point (5-round ledger): the ONLY zero-spill config was round 0's
// launch_bounds(256,4) + LDS > 40 KB: the LDS limit forces a 3-block/CU
// occupancy target, relaxing the reg budget to 512/3 = 170 (120 arch + 48
// acc observed). Explicit reg-budget attributes (r2/r3) and demand-trimming
// at the 128 cap (r4/r5) all left residual spill. So: weights RESIDENT
// again, and a volatile-kept 5.25 KB LDS pad pushes LDS to 41,088 B.
//
// mm2 OPERAND SWAP: mfma(bfr, w2f) instead of mfma(w2f, bfr). Fragments and
// LDS reads are byte-identical; output is transposed: channel = lane&15,
// row = rbk*16 + q*4 + c. The per-pair row-max/min becomes 7 in-thread fmax
// + 2 shfl_xor (off 16,32) instead of a 4-step 16-lane butterfly: 16 shfls
// per tile per thread vs 128 (shfl = ds_bpermute, ~6cyc on the LDS pipe -
// this was ~768 cyc/tile vs ~320 cyc of MFMA, the dominant epilogue cost).
__global__ void __launch_bounds__(256, 4)
k_fused_mfma(const __half* __restrict__ feats,
             const int* __restrict__ knn_idx,
             const __half* __restrict__ w1h,
             const __half* __restrict__ w2h,
             const float* __restrict__ ab1,
             float* __restrict__ gsum2,
             float* __restrict__ gsumsq2,
             float* __restrict__ wsmax,
             float* __restrict__ wsmin) {
    __shared__ __align__(16) __half nf[8192];     // 16 KB, swizzled chunks
    __shared__ __align__(16) __half y1s[8192];    // 16 KB, same swizzled layout
    __shared__ __align__(16) float abs_lds[256];  // bn1 a (0..127), c (128..255)
    __shared__ int rowb[TPB_TILES*64];            // 2 KB
    __shared__ float lds_pad[1312];               // 5.25 KB occupancy shaping
    int tid = threadIdx.x;
    int lane = tid & 63, wid = tid >> 6;
    int m = lane & 15, q = lane >> 4;

    fill_bases(knn_idx, blockIdx.x, tid, rowb);
    abs_lds[tid] = ab1[tid];
    // keep the pad allocated (forces 3 blocks/CU -> 170-reg budget)
    ((volatile float*)lds_pad)[tid] = 0.f;

    // resident weight fragments (round-0 proven at the 170-reg budget)
    half8 w1f[2][4], w2f[2][4];
#pragma unroll
    for (int ob = 0; ob < 2; ++ob)
#pragma unroll
        for (int t = 0; t < 4; ++t) {
            int o = wid*32 + ob*16 + m;
            w1f[ob][t] = *(const half8*)(w1h + o*CC + t*32 + q*8);
            w2f[ob][t] = *(const half8*)(w2h + o*CC + t*32 + q*8);
        }

    f32x4 zero4 = {0.f, 0.f, 0.f, 0.f};
    f32x4 ssum[2] = {zero4, zero4}, ssq[2] = {zero4, zero4};

    __syncthreads();
    uint4 pf[4];
    stage_load(feats, rowb, blockIdx.x, 0, tid, pf);

    for (int it = 0; it < TPB_TILES; ++it) {
        int tile = blockIdx.x * TPB_TILES + it;

        stage_write(tid, pf, nf);
        __syncthreads();                               // B1
        if (it + 1 < TPB_TILES) stage_load(feats, rowb, blockIdx.x, it + 1, tid, pf);

        f32x4 acc[2][4];
#pragma unroll
        for (int ob = 0; ob < 2; ++ob)
#pragma unroll
            for (int rbk = 0; rbk < 4; ++rbk) acc[ob][rbk] = zero4;

        // mm1: z1^T = w1 . nf^T  (channel in row dim: lane holds ch q*4+c, row m)
#pragma unroll
        for (int t = 0; t < 4; ++t) {
            int kct = t*4 + q;
            int sw = m ^ kct;
#pragma unroll
            for (int rbk = 0; rbk < 4; ++rbk) {
                half8 bfr = *(const half8*)(nf + (rbk*256 + kct*16 + sw)*8);
                acc[0][rbk] = __builtin_amdgcn_mfma_f32_16x16x32_f16(w1f[0][t], bfr, acc[0][rbk], 0, 0, 0);
                acc[1][rbk] = __builtin_amdgcn_mfma_f32_16x16x32_f16(w1f[1][t], bfr, acc[1][rbk], 0, 0, 0);
            }
        }

        // bn1 + relu, write y1 in swizzled chunk layout (a/c broadcast from LDS)
#pragma unroll
        for (int ob = 0; ob < 2; ++ob) {
            f32x4 av = *(const f32x4*)(abs_lds + wid*32 + ob*16 + q*4);
            f32x4 cv = *(const f32x4*)(abs_lds + 128 + wid*32 + ob*16 + q*4);
#pragma unroll
            for (int rbk = 0; rbk < 4; ++rbk) {
                f32x4 z = acc[ob][rbk];
                float y0 = relu_(fmaf(av[0], z[0], cv[0]));
                float y1 = relu_(fmaf(av[1], z[1], cv[1]));
                float y2 = relu_(fmaf(av[2], z[2], cv[2]));
                float y3 = relu_(fmaf(av[3], z[3], cv[3]));
                H2U p0, p1;
                p0.h = __floats2half2_rn(y0, y1);
                p1.h = __floats2half2_rn(y2, y3);
                int kcy = wid*4 + ob*2 + (q >> 1);
                int C = rbk*256 + kcy*16 + (m ^ kcy);
                uint2 v; v.x = p0.u; v.y = p1.u;
                *(uint2*)(y1s + C*8 + (q & 1)*4) = v;
            }
        }
        __syncthreads();                               // B2

        // mm2 SWAPPED: acc = mfma(y1-rows, w2^T) -> channel = lane&15 = m,
        // row = rbk*16 + q*4 + c. Same y1s reads, same w2f fragments.
#pragma unroll
        for (int ob = 0; ob < 2; ++ob)
#pragma unroll
            for (int rbk = 0; rbk < 4; ++rbk) acc[ob][rbk] = zero4;
#pragma unroll
        for (int t = 0; t < 4; ++t) {
            int kct = t*4 + q;
            int sw = m ^ kct;
#pragma unroll
            for (int rbk = 0; rbk < 4; ++rbk) {
                half8 bfr = *(const half8*)(y1s + (rbk*256 + kct*16 + sw)*8);
                acc[0][rbk] = __builtin_amdgcn_mfma_f32_16x16x32_f16(bfr, w2f[0][t], acc[0][rbk], 0, 0, 0);
                acc[1][rbk] = __builtin_amdgcn_mfma_f32_16x16x32_f16(bfr, w2f[1][t], acc[1][rbk], 0, 0, 0);
            }
        }
        // stats2: lane's channel = wid*32+ob*16+m; c-components are rows
#pragma unroll
        for (int ob = 0; ob < 2; ++ob)
#pragma unroll
            for (int rbk = 0; rbk < 4; ++rbk) {
                ssum[ob] += acc[ob][rbk];
                ssq[ob]  += acc[ob][rbk]*acc[ob][rbk];
            }
        // per-pair max/min: pair pr = rows {2pr,2pr+1}x16; in-thread over
        // 8 values (2 rbk x 4 c), then 2-step shfl over the q groups.
#pragma unroll
        for (int ob = 0; ob < 2; ++ob)
#pragma unroll
            for (int pr = 0; pr < 2; ++pr) {
                f32x4 x0 = acc[ob][pr*2], x1 = acc[ob][pr*2 + 1];
                float mx = fmaxf(fmaxf(fmaxf(x0[0], x0[1]), fmaxf(x0[2], x0[3])),
                                 fmaxf(fmaxf(x1[0], x1[1]), fmaxf(x1[2], x1[3])));
                float mn = fminf(fminf(fminf(x0[0], x0[1]), fminf(x0[2], x0[3])),
                                 fminf(fminf(x1[0], x1[1]), fminf(x1[2], x1[3])));
                mx = fmaxf(mx, __shfl_xor(mx, 16));
                mx = fmaxf(mx, __shfl_xor(mx, 32));
                mn = fminf(mn, __shfl_xor(mn, 16));
                mn = fminf(mn, __shfl_xor(mn, 32));
                if (lane < 16) {               // q == 0 lanes: 16 contiguous ch
                    int p = tile*2 + pr;
                    int o = wid*32 + ob*16 + m;
                    wsmax[(size_t)p*CC + o] = mx;
                    wsmin[(size_t)p*CC + o] = mn;
                }
            }
    }
    // final stats2 reduce: sum c-components (rows), then over q groups
#pragma unroll
    for (int ob = 0; ob < 2; ++ob) {
        float v  = ssum[ob][0] + ssum[ob][1] + ssum[ob][2] + ssum[ob][3];
        float v2 = ssq[ob][0]  + ssq[ob][1]  + ssq[ob][2]  + ssq[ob][3];
        v  += __shfl_xor(v, 16);  v  += __shfl_xor(v, 32);
        v2 += __shfl_xor(v2, 16); v2 += __shfl_xor(v2, 32);
        if (lane < 16) {
            int o = wid*32 + ob*16 + m;
            atomicAdd(&gsum2[o], v);
            atomicAdd(&gsumsq2[o], v2);
        }
    }
}

// ---------------- epilogue: bn2+relu on max/min, transpose to (B,C,N) ----------------
__global__ void __launch_bounds__(256) k_epilogue(const float* __restrict__ wsmax,
                                                  const float* __restrict__ wsmin,
                                                  const float* __restrict__ ab2,
                                                  float* __restrict__ out) {
    __shared__ float t[128*65];
    int b = blockIdx.y;
    int n0 = blockIdx.x * 64;
    int tid = threadIdx.x;
#pragma unroll
    for (int i = 0; i < 32; ++i) {
        int idx = i*256 + tid;
        int nl = idx >> 7, o = idx & 127;
        int n = n0 + nl;
        float v = 0.f;
        if (n < NN) {
            float a = ab2[o], cc = ab2[CC + o];
            size_t p = (size_t)b*NN + n;
            float z = (a >= 0.f) ? wsmax[p*CC + o] : wsmin[p*CC + o];
            v = fmaf(a, z, cc);
            v = v > 0.f ? v : 0.f;
        }
        t[o*65 + nl] = v;
    }
    __syncthreads();
#pragma unroll
    for (int i = 0; i < 32; ++i) {
        int idx = i*256 + tid;
        int o = idx >> 6, nl = idx & 63;
        int n = n0 + nl;
        if (n < NN) out[((size_t)b*CC + o)*NN + n] = t[o*65 + nl];
    }
}

extern "C" void kernel_launch(void* const* d_in, const int* in_sizes, int n_in,
                              void* d_out, int out_size, void* d_ws, size_t ws_size,
                              hipStream_t stream) {
    const float* x      = (const float*)d_in[0];
    const float* coords = (const float*)d_in[1];
    const float* w1     = (const float*)d_in[2];
    const float* g1     = (const float*)d_in[3];
    const float* b1     = (const float*)d_in[4];
    const float* w2     = (const float*)d_in[5];
    const float* g2     = (const float*)d_in[6];
    const float* b2     = (const float*)d_in[7];
    float* out = (float*)d_out;

    char* ws = (char*)d_ws;
    size_t off = 0;
    int* knn_idx = (int*)(ws + off);   off += (size_t)ROWS * sizeof(int);        // 3.32 MB
    float* stats = (float*)(ws + off); off += 1024 * sizeof(float);
    float* gsum2 = stats + 256, *gsq2 = stats + 384;
    float* ab1   = stats + 512;
    float* ab2   = stats + 768;
    __half* feats = (__half*)(ws + off); off += (size_t)BB*NN*DD * sizeof(__half); // 3.32 MB
    __half* w1h   = (__half*)(ws + off); off += CC*CC * sizeof(__half);
    __half* w2h   = (__half*)(ws + off); off += CC*CC * sizeof(__half);
    float* wsmax = (float*)(ws + off);  off += (size_t)PAIRS*CC * sizeof(float);  // 13.3 MB
    float* wsmin = (float*)(ws + off);  off += (size_t)PAIRS*CC * sizeof(float);  // 13.3 MB
    int*   cnt   = (int*)(ws + off);    off += (size_t)PAIRS * sizeof(int);       // 104 KB
    float* Mfin  = (float*)(ws + off);  off += (size_t)MSTRIDE * sizeof(float);   // 50 KB
    // aliases (dead before k_fused writes wsmax/wsmin):
    float* s_arr = wsmax;                    // PAIRS*64 fp32 = 6.64 MB  (<13.3)
    float* Mpart = wsmin;                    // 128*12416 fp32 = 6.36 MB (<13.3)
    (void)ws_size; (void)in_sizes; (void)n_in; (void)out_size;

    hipMemsetAsync(stats, 0, 512 * sizeof(float), stream);
    hipMemsetAsync(cnt, 0, (size_t)PAIRS * sizeof(int), stream);

    dim3 gT((NN + 63)/64, BB);
    k_prep_feats<<<gT, 256, 0, stream>>>(x, feats);
    k_convert_w<<<64, 256, 0, stream>>>(w1, w2, w1h, w2h);
    k_knn<<<PAIRS, 64, 0, stream>>>(coords, knn_idx, cnt);
    k_gather_sum<<<PAIRS/4, 256, 0, stream>>>(feats, knn_idx, s_arr);
    k_gram<<<GRAM_BLOCKS, 256, 0, stream>>>(feats, s_arr, cnt, Mpart);
    k_gram_reduce<<<(MSTRIDE + 255)/256, 256, 0, stream>>>(Mpart, Mfin);
    k_stats1<<<CC, 256, 0, stream>>>(Mfin, w1h, g1, b1, ab1);
    k_fused_mfma<<<GRID_MM, 256, 0, stream>>>(feats, knn_idx, w1h, w2h, ab1,
                                              gsum2, gsq2, wsmax, wsmin);
    k_finalize<<<1, CC, 0, stream>>>(gsum2, gsq2, g2, b2, ab2);
    dim3 gE((NN + 63)/64, BB);
    k_epilogue<<<gE, 256, 0, stream>>>(wsmax, wsmin, ab2, out);
}

// Round 7
// 402.404 us; speedup vs baseline: 1.7174x; 1.0351x over previous
//
#include <hip/hip_runtime.h>
#include <hip/hip_fp16.h>
#include <stdint.h>

#define BB 16
#define NN 1620
#define DD 64
#define CC 128
#define KK 32
#define EPSV 1e-5f
#define PAIRS (BB*NN)            // 25920
#define ROWS  (PAIRS*KK)         // 829440
#define TILES (PAIRS/2)          // 12960 tiles of 64 rows
#define TPB_TILES 8
#define GRID_MM (TILES/TPB_TILES) // 1620
#define NCHUNK 26                // ceil(1620/64)
#define GRAM_BLOCKS 128
#define MSTRIDE 12416            // 3*4096 mats + 64 vcf + 64 vf
#define QPB 4                    // knn queries per 256-thread block

typedef _Float16 half8 __attribute__((ext_vector_type(8)));
typedef float f32x4 __attribute__((ext_vector_type(4)));

__device__ __forceinline__ float relu_(float v){ return v > 0.f ? v : 0.f; }

union H2U { __half2 h; unsigned u; };

// ---------------- x (B,D,N) fp32 -> feats (B,N,D) fp16 ----------------
__global__ void __launch_bounds__(256) k_prep_feats(const float* __restrict__ x,
                                                    __half* __restrict__ feats) {
    __shared__ float t[64*65];
    int b = blockIdx.y;
    int n0 = blockIdx.x * 64;
    int tid = threadIdx.x;
#pragma unroll
    for (int i = 0; i < 16; ++i) {
        int idx = i*256 + tid;
        int d = idx >> 6, nl = idx & 63;
        int n = n0 + nl;
        float v = 0.f;
        if (n < NN) v = x[((size_t)b*DD + d)*NN + n];
        t[d*65 + nl] = v;
    }
    __syncthreads();
#pragma unroll
    for (int i = 0; i < 8; ++i) {
        int idx = i*256 + tid;            // 64 nl x 32 d-pairs
        int nl = idx >> 5, dp = idx & 31;
        int n = n0 + nl;
        if (n < NN) {
            __half2 h = __floats2half2_rn(t[(dp*2)*65 + nl], t[(dp*2+1)*65 + nl]);
            *(__half2*)(feats + ((size_t)b*NN + n)*DD + dp*2) = h;
        }
    }
}

// ---------------- w fp32 -> fp16 (same [o][c] layout) ----------------
__global__ void k_convert_w(const float* __restrict__ w1, const float* __restrict__ w2,
                            __half* __restrict__ w1h, __half* __restrict__ w2h) {
    int i = blockIdx.x*256 + threadIdx.x;   // 64 blocks * 256 = 16384
    w1h[i] = __float2half(w1[i]);
    w2h[i] = __float2half(w2[i]);
}

// ---------------- KNN: radix-histogram rank selection ----------------
// Round-6 PMC: SQ_LDS_BANK_CONFLICT 2.3e7 (~28% of kernel time) -- keys are
// sign-flipped float bits of non-negative distances, so key[31:24] lands in
// ~6 buckets and 64 lanes' atomicAdds serialize on the same LDS address.
// Fix: (a) 4-way replicated histogram hist[w][lane&3][bin] -> <=16 lanes per
// address; (b) 4 queries per 256-thread block (one per wave, private hist
// set) -> lifts the 16-workgroup-slot occupancy cap (59% observed) so L2
// coord-load latency is hidden. All __syncthreads remain wave-uniform (the
// rank-dependent r-loop has no barriers).
__global__ void __launch_bounds__(256) k_knn(const float* __restrict__ coords,
                                             int* __restrict__ idx_out,
                                             int* __restrict__ cnt) {
#pragma clang fp contract(off)
    __shared__ int hist[QPB][4][256];     // 16 KB: per-wave, 4-way replicated
    __shared__ unsigned bcast[QPB][2];    // [0]=bucket, [1]=count below bucket
    int w = threadIdx.x >> 6, lane = threadIdx.x & 63;
    int p = blockIdx.x*QPB + w;
    int b = p / NN, n = p - b*NN;
    const float* cb = coords + (size_t)b*NN*3;
    float qx = cb[n*3+0], qy = cb[n*3+1], qz = cb[n*3+2];
    float sqn = (qx*qx + qy*qy) + qz*qz;

    unsigned key[NCHUNK];
#pragma unroll
    for (int i = 0; i < NCHUNK; ++i) {
        int m = lane + i*64;
        unsigned u = 0xFFFFFFFFu;
        if (m < NN) {
            float cx = cb[m*3+0], cy = cb[m*3+1], cz = cb[m*3+2];
            float sqm = (cx*cx + cy*cy) + cz*cz;
            float dot = (qx*cx + qy*cy) + qz*cz;
            float d = (sqn + sqm) - 2.0f*dot;
            unsigned t = __float_as_uint(d);
            u = (t & 0x80000000u) ? ~t : (t | 0x80000000u);
        }
        key[i] = u;
    }
    int rep = lane & 3;

    // ---- pass A: histogram on key[31:24] ----
#pragma unroll
    for (int c = 0; c < 4; ++c)
#pragma unroll
        for (int i = 0; i < 4; ++i) hist[w][c][i*64 + lane] = 0;
    __syncthreads();
#pragma unroll
    for (int i = 0; i < NCHUNK; ++i) {
        int m = lane + i*64;
        if (m < NN) atomicAdd(&hist[w][rep][key[i] >> 24], 1);
    }
    __syncthreads();
    {
        int v0 = 0, v1 = 0, v2 = 0, v3 = 0;
#pragma unroll
        for (int c = 0; c < 4; ++c) {
            v0 += hist[w][c][lane*4+0]; v1 += hist[w][c][lane*4+1];
            v2 += hist[w][c][lane*4+2]; v3 += hist[w][c][lane*4+3];
        }
        int c1 = v0+v1, c2 = c1+v2, c3 = c2+v3;
        int inc = c3;
#pragma unroll
        for (int off = 1; off < 64; off <<= 1) {
            int t = __shfl_up(inc, off);
            if (lane >= off) inc += t;
        }
        int base = inc - c3;
        if (base < KK) {
            int u0 = base+v0, u1 = base+c1, u2 = base+c2, u3 = base+c3;
            if      (u0 >= KK) { bcast[w][0] = lane*4+0; bcast[w][1] = base; }
            else if (u1 >= KK) { bcast[w][0] = lane*4+1; bcast[w][1] = u0; }
            else if (u2 >= KK) { bcast[w][0] = lane*4+2; bcast[w][1] = u1; }
            else if (u3 >= KK) { bcast[w][0] = lane*4+3; bcast[w][1] = u2; }
        }
    }
    __syncthreads();
    unsigned BA = bcast[w][0];
    int rA = KK - (int)bcast[w][1];
    __syncthreads();

    // ---- pass B: histogram on key[23:16] within bucket BA ----
#pragma unroll
    for (int c = 0; c < 4; ++c)
#pragma unroll
        for (int i = 0; i < 4; ++i) hist[w][c][i*64 + lane] = 0;
    __syncthreads();
#pragma unroll
    for (int i = 0; i < NCHUNK; ++i) {
        int m = lane + i*64;
        if (m < NN && (key[i] >> 24) == BA) atomicAdd(&hist[w][rep][(key[i] >> 16) & 255], 1);
    }
    __syncthreads();
    {
        int v0 = 0, v1 = 0, v2 = 0, v3 = 0;
#pragma unroll
        for (int c = 0; c < 4; ++c) {
            v0 += hist[w][c][lane*4+0]; v1 += hist[w][c][lane*4+1];
            v2 += hist[w][c][lane*4+2]; v3 += hist[w][c][lane*4+3];
        }
        int c1 = v0+v1, c2 = c1+v2, c3 = c2+v3;
        int inc = c3;
#pragma unroll
        for (int off = 1; off < 64; off <<= 1) {
            int t = __shfl_up(inc, off);
            if (lane >= off) inc += t;
        }
        int base = inc - c3;
        if (base < rA) {
            int u0 = base+v0, u1 = base+c1, u2 = base+c2, u3 = base+c3;
            if      (u0 >= rA) { bcast[w][0] = lane*4+0; bcast[w][1] = base; }
            else if (u1 >= rA) { bcast[w][0] = lane*4+1; bcast[w][1] = u0; }
            else if (u2 >= rA) { bcast[w][0] = lane*4+2; bcast[w][1] = u1; }
            else if (u3 >= rA) { bcast[w][0] = lane*4+3; bcast[w][1] = u2; }
        }
    }
    __syncthreads();
    unsigned prefix16 = (BA << 8) | bcast[w][0];
    int r = rA - (int)bcast[w][1];

    // ---- extract exact 32nd (key, m) pair (wave-local, no barriers) ----
    unsigned long long fl = 0;
    for (int round = 0; round < r; ++round) {
        unsigned long long best = ~0ull;
#pragma unroll
        for (int i = 0; i < NCHUNK; ++i) {
            if ((key[i] >> 16) == prefix16) {
                unsigned long long v = ((unsigned long long)key[i] << 32) | (unsigned)(lane + i*64);
                if (v > fl && v < best) best = v;
            }
        }
#pragma unroll
        for (int off = 32; off; off >>= 1) {
            unsigned long long o = __shfl_xor(best, off, 64);
            if (o < best) best = o;
        }
        fl = best;
    }
    unsigned kstar = (unsigned)(fl >> 32);
    unsigned mstar = (unsigned)fl;

    int cnt_ = 0;
    unsigned long long mylow = (1ull << lane) - 1ull;
#pragma unroll
    for (int i = 0; i < NCHUNK; ++i) {
        unsigned m = lane + i*64;
        bool sel = (key[i] < kstar) || (key[i] == kstar && m <= mstar);
        unsigned long long bal = __ballot(sel);
        if (sel) {
            int pos = cnt_ + __popcll(bal & mylow);
            idx_out[p*KK + pos] = (int)m;
            atomicAdd(&cnt[b*NN + (int)m], 1);
        }
        cnt_ += __popcll(bal);
    }
}

// ---------------- gather-sum: s_p = sum_k f_nb(p,k), fp32 ----------------
__global__ void __launch_bounds__(256) k_gather_sum(const __half* __restrict__ feats,
                                                    const int* __restrict__ knn_idx,
                                                    float* __restrict__ s_arr) {
    int w = threadIdx.x >> 6, lane = threadIdx.x & 63;
    int p = blockIdx.x*4 + w;
    int b = p / NN;
    int bbase = b*NN;
    int idx = 0;
    if (lane < KK) idx = knn_idx[p*KK + lane];
    float s = 0.f;
#pragma unroll
    for (int k = 0; k < KK; ++k) {
        int nb = __shfl(idx, k);
        s += __half2float(feats[((size_t)(bbase + nb))*DD + lane]);
    }
    s_arr[(size_t)p*DD + lane] = s;
}

// ---------------- gram: per-block partial M1/M2/M3 + vectors ----------------
// M1 = sum cnt_m f f^T, M2 = sum s_p f_p^T, M3 = sum f f^T, vcf = sum cnt f, vf = sum f
__global__ void __launch_bounds__(256) k_gram(const __half* __restrict__ feats,
                                              const float* __restrict__ s_arr,
                                              const int* __restrict__ cnt,
                                              float* __restrict__ Mpart) {
    __shared__ float fs[4][64];
    __shared__ float ss[4][64];
    __shared__ float cs[4];
    int tid = threadIdx.x;
    int rt = tid >> 4, ct = tid & 15;
    int r0 = rt*4, c0 = ct*4;
    float m1a[4][4] = {{0}}, m2a[4][4] = {{0}}, m3a[4][4] = {{0}};
    float vcf4[4] = {0,0,0,0}, vf4[4] = {0,0,0,0};

    int per = (PAIRS + GRAM_BLOCKS - 1)/GRAM_BLOCKS;   // 203
    int p0 = blockIdx.x * per;
    int p1 = p0 + per; if (p1 > PAIRS) p1 = PAIRS;

    for (int pc = p0; pc < p1; pc += 4) {
        __syncthreads();
        int sub = tid >> 6, l = tid & 63;
        int pp = pc + sub;
        if (pp < p1) {
            fs[sub][l] = __half2float(feats[(size_t)pp*DD + l]);
            ss[sub][l] = s_arr[(size_t)pp*DD + l];
            if (l == 0) cs[sub] = (float)cnt[pp];
        }
        __syncthreads();
        int e = p1 - pc; if (e > 4) e = 4;
        for (int j = 0; j < e; ++j) {
            float cn = cs[j];
            float fr[4], sr[4], fc[4];
#pragma unroll
            for (int a = 0; a < 4; ++a) { fr[a] = fs[j][r0+a]; sr[a] = ss[j][r0+a]; fc[a] = fs[j][c0+a]; }
#pragma unroll
            for (int a = 0; a < 4; ++a) {
                float cfr = cn * fr[a];
#pragma unroll
                for (int bc = 0; bc < 4; ++bc) {
                    m1a[a][bc] = fmaf(cfr,   fc[bc], m1a[a][bc]);
                    m2a[a][bc] = fmaf(sr[a], fc[bc], m2a[a][bc]);
                    m3a[a][bc] = fmaf(fr[a], fc[bc], m3a[a][bc]);
                }
                if (ct == 0) { vcf4[a] += cfr; vf4[a] += fr[a]; }
            }
        }
    }
    float* out = Mpart + (size_t)blockIdx.x * MSTRIDE;
#pragma unroll
    for (int a = 0; a < 4; ++a)
#pragma unroll
        for (int bc = 0; bc < 4; ++bc) {
            int idx = (r0+a)*64 + c0+bc;
            out[idx]        = m1a[a][bc];
            out[4096 + idx] = m2a[a][bc];
            out[8192 + idx] = m3a[a][bc];
        }
    if (ct == 0)
#pragma unroll
        for (int a = 0; a < 4; ++a) {
            out[12288 + r0+a] = vcf4[a];
            out[12352 + r0+a] = vf4[a];
        }
}

__global__ void __launch_bounds__(256) k_gram_reduce(const float* __restrict__ Mpart,
                                                     float* __restrict__ Mfin) {
    int e = blockIdx.x*256 + threadIdx.x;
    if (e < MSTRIDE) {
        float s = 0.f;
        for (int p = 0; p < GRAM_BLOCKS; ++p) s += Mpart[(size_t)p*MSTRIDE + e];
        Mfin[e] = s;
    }
}

// ---------------- stats1 from Gram: one block per output channel o ----------------
__global__ void __launch_bounds__(256) k_stats1(const float* __restrict__ M,
                                                const __half* __restrict__ w1h,
                                                const float* __restrict__ g1,
                                                const float* __restrict__ b1,
                                                float* __restrict__ ab1) {
    __shared__ float wl[64], wr[64];
    __shared__ float redA[256], redB[256];
    int o = blockIdx.x, tid = threadIdx.x;
    if (tid < 64)       wl[tid]    = __half2float(w1h[o*CC + tid]);
    else if (tid < 128) wr[tid-64] = __half2float(w1h[o*CC + tid]);
    __syncthreads();
    const float* M1 = M;
    const float* M2 = M + 4096;
    const float* M3 = M + 8192;
    const float* vcf = M + 12288;
    const float* vf  = M + 12352;
    float part = 0.f;
    for (int e = tid; e < 4096; e += 256) {
        int i = e >> 6, j = e & 63;
        float m1 = M1[e], m2 = M2[e], m2t = M2[j*64 + i], m3 = M3[e];
        float A  = m1 - m2 - m2t + 32.f*m3;   // sum u u^T
        float Bc = m2 - 32.f*m3;              // sum u v^T
        part += wl[i]*(A*wl[j] + 2.f*Bc*wr[j]) + 32.f*wr[i]*m3*wr[j];
    }
    float psum = 0.f;
    if (tid < 64) psum = wl[tid]*(vcf[tid] - 32.f*vf[tid]) + 32.f*wr[tid]*vf[tid];
    redA[tid] = part; redB[tid] = psum;
    __syncthreads();
    for (int s = 128; s > 0; s >>= 1) {
        if (tid < s) { redA[tid] += redA[tid+s]; redB[tid] += redB[tid+s]; }
        __syncthreads();
    }
    if (tid == 0) {
        float sumsq = redA[0], sum = redB[0];
        float mean = sum / (float)ROWS;
        float var  = sumsq / (float)ROWS - mean*mean;
        float a = g1[o] * rsqrtf(var + EPSV);
        ab1[o] = a;
        ab1[CC + o] = b1[o] - mean*a;
    }
}

// ============ staging helpers: coalesced gather + XOR-swizzled LDS ============
__device__ __forceinline__ void fill_bases(const int* __restrict__ knn_idx,
                                           int blk, int tid, int* rowb) {
#pragma unroll
    for (int e = tid; e < TPB_TILES*64; e += 256) {
        int tile = blk*TPB_TILES + (e >> 6);
        int rr = e & 63;
        int p = tile*2 + (rr >> 5);
        int nb = knn_idx[p*KK + (rr & 31)];
        int b = p / NN;
        rowb[e] = (b*NN + nb)*DD;
    }
}

__device__ __forceinline__ void stage_load(const __half* __restrict__ feats,
                                           const int* rowb, int blk,
                                           int tloc, int tid, uint4* A) {
    int kc = tid & 15;
#pragma unroll
    for (int it = 0; it < 4; ++it) {
        int row = it*16 + (tid >> 4);
        int e = tloc*64 + row;
        int p = (blk*TPB_TILES + tloc)*2 + (row >> 5);
        int ra = (kc < 8) ? (rowb[e] + kc*8) : (p*DD + (kc-8)*8);
        A[it] = *(const uint4*)(feats + ra);
    }
}

// stage_write: center row recovered from lane (kc^8)'s prefetch via shfl_xor.
__device__ __forceinline__ void stage_write(int tid, const uint4* A, __half* nf) {
    int kc = tid & 15;
#pragma unroll
    for (int it = 0; it < 4; ++it) {
        int row = it*16 + (tid >> 4);
        union { uint4 u; __half2 h[4]; } a, b, rr;
        a.u = A[it];
        b.u.x = (unsigned)__shfl_xor((int)a.u.x, 8);
        b.u.y = (unsigned)__shfl_xor((int)a.u.y, 8);
        b.u.z = (unsigned)__shfl_xor((int)a.u.z, 8);
        b.u.w = (unsigned)__shfl_xor((int)a.u.w, 8);
        if (kc < 8) {
#pragma unroll
            for (int j = 0; j < 4; ++j) rr.h[j] = __hsub2(a.h[j], b.h[j]);
        } else {
            rr.u = a.u;
        }
        int C = (row >> 4)*256 + kc*16 + ((row & 15) ^ kc);   // XOR swizzle
        *(uint4*)(nf + C*8) = rr.u;
    }
}

// ---------------- finalize bn params (layer 2) ----------------
__global__ void k_finalize(const float* __restrict__ gsum, const float* __restrict__ gsumsq,
                           const float* __restrict__ g, const float* __restrict__ bb,
                           float* __restrict__ ab) {
    int o = threadIdx.x;
    float cnt = (float)ROWS;
    float mean = gsum[o] / cnt;
    float var = gsumsq[o] / cnt - mean*mean;
    float a = g[o] * rsqrtf(var + EPSV);
    ab[o] = a;
    ab[CC + o] = bb[o] - mean*a;
}

// ---------------- fused: mm1 + bn1relu + mm2 + stats2 + per-pair max/min ----------------
// Round-6 proven operating point: launch_bounds(256,4) + LDS>40KB (pad)
// -> 3 blocks/CU -> 170-reg budget -> resident weights, zero spill.
// mm2 operand-swapped so per-pair max/min needs 2 shfls instead of a
// 4-step butterfly. DO NOT change LDS below 40 KB (rounds 1-5 ledger).
__global__ void __launch_bounds__(256, 4)
k_fused_mfma(const __half* __restrict__ feats,
             const int* __restrict__ knn_idx,
             const __half* __restrict__ w1h,
             const __half* __restrict__ w2h,
             const float* __restrict__ ab1,
             float* __restrict__ gsum2,
             float* __restrict__ gsumsq2,
             float* __restrict__ wsmax,
             float* __restrict__ wsmin) {
    __shared__ __align__(16) __half nf[8192];     // 16 KB, swizzled chunks
    __shared__ __align__(16) __half y1s[8192];    // 16 KB, same swizzled layout
    __shared__ __align__(16) float abs_lds[256];  // bn1 a (0..127), c (128..255)
    __shared__ int rowb[TPB_TILES*64];            // 2 KB
    __shared__ float lds_pad[1312];               // 5.25 KB occupancy shaping
    int tid = threadIdx.x;
    int lane = tid & 63, wid = tid >> 6;
    int m = lane & 15, q = lane >> 4;

    fill_bases(knn_idx, blockIdx.x, tid, rowb);
    abs_lds[tid] = ab1[tid];
    ((volatile float*)lds_pad)[tid] = 0.f;

    half8 w1f[2][4], w2f[2][4];
#pragma unroll
    for (int ob = 0; ob < 2; ++ob)
#pragma unroll
        for (int t = 0; t < 4; ++t) {
            int o = wid*32 + ob*16 + m;
            w1f[ob][t] = *(const half8*)(w1h + o*CC + t*32 + q*8);
            w2f[ob][t] = *(const half8*)(w2h + o*CC + t*32 + q*8);
        }

    f32x4 zero4 = {0.f, 0.f, 0.f, 0.f};
    f32x4 ssum[2] = {zero4, zero4}, ssq[2] = {zero4, zero4};

    __syncthreads();
    uint4 pf[4];
    stage_load(feats, rowb, blockIdx.x, 0, tid, pf);

    for (int it = 0; it < TPB_TILES; ++it) {
        int tile = blockIdx.x * TPB_TILES + it;

        stage_write(tid, pf, nf);
        __syncthreads();                               // B1
        if (it + 1 < TPB_TILES) stage_load(feats, rowb, blockIdx.x, it + 1, tid, pf);

        f32x4 acc[2][4];
#pragma unroll
        for (int ob = 0; ob < 2; ++ob)
#pragma unroll
            for (int rbk = 0; rbk < 4; ++rbk) acc[ob][rbk] = zero4;

        // mm1: z1^T = w1 . nf^T
#pragma unroll
        for (int t = 0; t < 4; ++t) {
            int kct = t*4 + q;
            int sw = m ^ kct;
#pragma unroll
            for (int rbk = 0; rbk < 4; ++rbk) {
                half8 bfr = *(const half8*)(nf + (rbk*256 + kct*16 + sw)*8);
                acc[0][rbk] = __builtin_amdgcn_mfma_f32_16x16x32_f16(w1f[0][t], bfr, acc[0][rbk], 0, 0, 0);
                acc[1][rbk] = __builtin_amdgcn_mfma_f32_16x16x32_f16(w1f[1][t], bfr, acc[1][rbk], 0, 0, 0);
            }
        }

        // bn1 + relu, write y1 in swizzled chunk layout (a/c broadcast from LDS)
#pragma unroll
        for (int ob = 0; ob < 2; ++ob) {
            f32x4 av = *(const f32x4*)(abs_lds + wid*32 + ob*16 + q*4);
            f32x4 cv = *(const f32x4*)(abs_lds + 128 + wid*32 + ob*16 + q*4);
#pragma unroll
            for (int rbk = 0; rbk < 4; ++rbk) {
                f32x4 z = acc[ob][rbk];
                float y0 = relu_(fmaf(av[0], z[0], cv[0]));
                float y1 = relu_(fmaf(av[1], z[1], cv[1]));
                float y2 = relu_(fmaf(av[2], z[2], cv[2]));
                float y3 = relu_(fmaf(av[3], z[3], cv[3]));
                H2U p0, p1;
                p0.h = __floats2half2_rn(y0, y1);
                p1.h = __floats2half2_rn(y2, y3);
                int kcy = wid*4 + ob*2 + (q >> 1);
                int C = rbk*256 + kcy*16 + (m ^ kcy);
                uint2 v; v.x = p0.u; v.y = p1.u;
                *(uint2*)(y1s + C*8 + (q & 1)*4) = v;
            }
        }
        __syncthreads();                               // B2

        // mm2 SWAPPED: channel = lane&15, row = rbk*16 + q*4 + c
#pragma unroll
        for (int ob = 0; ob < 2; ++ob)
#pragma unroll
            for (int rbk = 0; rbk < 4; ++rbk) acc[ob][rbk] = zero4;
#pragma unroll
        for (int t = 0; t < 4; ++t) {
            int kct = t*4 + q;
            int sw = m ^ kct;
#pragma unroll
            for (int rbk = 0; rbk < 4; ++rbk) {
                half8 bfr = *(const half8*)(y1s + (rbk*256 + kct*16 + sw)*8);
                acc[0][rbk] = __builtin_amdgcn_mfma_f32_16x16x32_f16(bfr, w2f[0][t], acc[0][rbk], 0, 0, 0);
                acc[1][rbk] = __builtin_amdgcn_mfma_f32_16x16x32_f16(bfr, w2f[1][t], acc[1][rbk], 0, 0, 0);
            }
        }
        // stats2
#pragma unroll
        for (int ob = 0; ob < 2; ++ob)
#pragma unroll
            for (int rbk = 0; rbk < 4; ++rbk) {
                ssum[ob] += acc[ob][rbk];
                ssq[ob]  += acc[ob][rbk]*acc[ob][rbk];
            }
        // per-pair max/min: 7 in-thread fmax + 2 shfls
#pragma unroll
        for (int ob = 0; ob < 2; ++ob)
#pragma unroll
            for (int pr = 0; pr < 2; ++pr) {
                f32x4 x0 = acc[ob][pr*2], x1 = acc[ob][pr*2 + 1];
                float mx = fmaxf(fmaxf(fmaxf(x0[0], x0[1]), fmaxf(x0[2], x0[3])),
                                 fmaxf(fmaxf(x1[0], x1[1]), fmaxf(x1[2], x1[3])));
                float mn = fminf(fminf(fminf(x0[0], x0[1]), fminf(x0[2], x0[3])),
                                 fminf(fminf(x1[0], x1[1]), fminf(x1[2], x1[3])));
                mx = fmaxf(mx, __shfl_xor(mx, 16));
                mx = fmaxf(mx, __shfl_xor(mx, 32));
                mn = fminf(mn, __shfl_xor(mn, 16));
                mn = fminf(mn, __shfl_xor(mn, 32));
                if (lane < 16) {
                    int p = tile*2 + pr;
                    int o = wid*32 + ob*16 + m;
                    wsmax[(size_t)p*CC + o] = mx;
                    wsmin[(size_t)p*CC + o] = mn;
                }
            }
    }
#pragma unroll
    for (int ob = 0; ob < 2; ++ob) {
        float v  = ssum[ob][0] + ssum[ob][1] + ssum[ob][2] + ssum[ob][3];
        float v2 = ssq[ob][0]  + ssq[ob][1]  + ssq[ob][2]  + ssq[ob][3];
        v  += __shfl_xor(v, 16);  v  += __shfl_xor(v, 32);
        v2 += __shfl_xor(v2, 16); v2 += __shfl_xor(v2, 32);
        if (lane < 16) {
            int o = wid*32 + ob*16 + m;
            atomicAdd(&gsum2[o], v);
            atomicAdd(&gsumsq2[o], v2);
        }
    }
}

// ---------------- epilogue: bn2+relu on max/min, transpose to (B,C,N) ----------------
__global__ void __launch_bounds__(256) k_epilogue(const float* __restrict__ wsmax,
                                                  const float* __restrict__ wsmin,
                                                  const float* __restrict__ ab2,
                                                  float* __restrict__ out) {
    __shared__ float t[128*65];
    int b = blockIdx.y;
    int n0 = blockIdx.x * 64;
    int tid = threadIdx.x;
#pragma unroll
    for (int i = 0; i < 32; ++i) {
        int idx = i*256 + tid;
        int nl = idx >> 7, o = idx & 127;
        int n = n0 + nl;
        float v = 0.f;
        if (n < NN) {
            float a = ab2[o], cc = ab2[CC + o];
            size_t p = (size_t)b*NN + n;
            float z = (a >= 0.f) ? wsmax[p*CC + o] : wsmin[p*CC + o];
            v = fmaf(a, z, cc);
            v = v > 0.f ? v : 0.f;
        }
        t[o*65 + nl] = v;
    }
    __syncthreads();
#pragma unroll
    for (int i = 0; i < 32; ++i) {
        int idx = i*256 + tid;
        int o = idx >> 6, nl = idx & 63;
        int n = n0 + nl;
        if (n < NN) out[((size_t)b*CC + o)*NN + n] = t[o*65 + nl];
    }
}

extern "C" void kernel_launch(void* const* d_in, const int* in_sizes, int n_in,
                              void* d_out, int out_size, void* d_ws, size_t ws_size,
                              hipStream_t stream) {
    const float* x      = (const float*)d_in[0];
    const float* coords = (const float*)d_in[1];
    const float* w1     = (const float*)d_in[2];
    const float* g1     = (const float*)d_in[3];
    const float* b1     = (const float*)d_in[4];
    const float* w2     = (const float*)d_in[5];
    const float* g2     = (const float*)d_in[6];
    const float* b2     = (const float*)d_in[7];
    float* out = (float*)d_out;

    char* ws = (char*)d_ws;
    size_t off = 0;
    int* knn_idx = (int*)(ws + off);   off += (size_t)ROWS * sizeof(int);        // 3.32 MB
    float* stats = (float*)(ws + off); off += 1024 * sizeof(float);
    float* gsum2 = stats + 256, *gsq2 = stats + 384;
    float* ab1   = stats + 512;
    float* ab2   = stats + 768;
    __half* feats = (__half*)(ws + off); off += (size_t)BB*NN*DD * sizeof(__half); // 3.32 MB
    __half* w1h   = (__half*)(ws + off); off += CC*CC * sizeof(__half);
    __half* w2h   = (__half*)(ws + off); off += CC*CC * sizeof(__half);
    float* wsmax = (float*)(ws + off);  off += (size_t)PAIRS*CC * sizeof(float);  // 13.3 MB
    float* wsmin = (float*)(ws + off);  off += (size_t)PAIRS*CC * sizeof(float);  // 13.3 MB
    int*   cnt   = (int*)(ws + off);    off += (size_t)PAIRS * sizeof(int);       // 104 KB
    float* Mfin  = (float*)(ws + off);  off += (size_t)MSTRIDE * sizeof(float);   // 50 KB
    // aliases (dead before k_fused writes wsmax/wsmin):
    float* s_arr = wsmax;                    // PAIRS*64 fp32 = 6.64 MB  (<13.3)
    float* Mpart = wsmin;                    // 128*12416 fp32 = 6.36 MB (<13.3)
    (void)ws_size; (void)in_sizes; (void)n_in; (void)out_size;

    hipMemsetAsync(stats, 0, 512 * sizeof(float), stream);
    hipMemsetAsync(cnt, 0, (size_t)PAIRS * sizeof(int), stream);

    dim3 gT((NN + 63)/64, BB);
    k_prep_feats<<<gT, 256, 0, stream>>>(x, feats);
    k_convert_w<<<64, 256, 0, stream>>>(w1, w2, w1h, w2h);
    k_knn<<<PAIRS/QPB, 256, 0, stream>>>(coords, knn_idx, cnt);
    k_gather_sum<<<PAIRS/4, 256, 0, stream>>>(feats, knn_idx, s_arr);
    k_gram<<<GRAM_BLOCKS, 256, 0, stream>>>(feats, s_arr, cnt, Mpart);
    k_gram_reduce<<<(MSTRIDE + 255)/256, 256, 0, stream>>>(Mpart, Mfin);
    k_stats1<<<CC, 256, 0, stream>>>(Mfin, w1h, g1, b1, ab1);
    k_fused_mfma<<<GRID_MM, 256, 0, stream>>>(feats, knn_idx, w1h, w2h, ab1,
                                              gsum2, gsq2, wsmax, wsmin);
    k_finalize<<<1, CC, 0, stream>>>(gsum2, gsq2, g2, b2, ab2);
    dim3 gE((NN + 63)/64, BB);
    k_epilogue<<<gE, 256, 0, stream>>>(wsmax, wsmin, ab2, out);
}

// Round 8
// 387.443 us; speedup vs baseline: 1.7837x; 1.0386x over previous
//
#include <hip/hip_runtime.h>
#include <hip/hip_fp16.h>
#include <stdint.h>

#define BB 16
#define NN 1620
#define DD 64
#define CC 128
#define KK 32
#define EPSV 1e-5f
#define PAIRS (BB*NN)            // 25920
#define ROWS  (PAIRS*KK)         // 829440
#define TILES (PAIRS/2)          // 12960 tiles of 64 rows
#define TPB_TILES 8
#define GRID_MM (TILES/TPB_TILES) // 1620
#define NCHUNK 26                // ceil(1620/64)
#define GRAM_BLOCKS 128
#define MSTRIDE 12416            // 3*4096 mats + 64 vcf + 64 vf
#define QPB 4                    // knn queries per 256-thread block
#define HSTRIDE 264              // replica stride (ints): 264 % 32 == 8 ->
                                 // replicas of a bin land in 4 DISTINCT banks

typedef _Float16 half8 __attribute__((ext_vector_type(8)));
typedef float f32x4 __attribute__((ext_vector_type(4)));

__device__ __forceinline__ float relu_(float v){ return v > 0.f ? v : 0.f; }

union H2U { __half2 h; unsigned u; };

// ---------------- x (B,D,N) fp32 -> feats (B,N,D) fp16 ----------------
__global__ void __launch_bounds__(256) k_prep_feats(const float* __restrict__ x,
                                                    __half* __restrict__ feats) {
    __shared__ float t[64*65];
    int b = blockIdx.y;
    int n0 = blockIdx.x * 64;
    int tid = threadIdx.x;
#pragma unroll
    for (int i = 0; i < 16; ++i) {
        int idx = i*256 + tid;
        int d = idx >> 6, nl = idx & 63;
        int n = n0 + nl;
        float v = 0.f;
        if (n < NN) v = x[((size_t)b*DD + d)*NN + n];
        t[d*65 + nl] = v;
    }
    __syncthreads();
#pragma unroll
    for (int i = 0; i < 8; ++i) {
        int idx = i*256 + tid;            // 64 nl x 32 d-pairs
        int nl = idx >> 5, dp = idx & 31;
        int n = n0 + nl;
        if (n < NN) {
            __half2 h = __floats2half2_rn(t[(dp*2)*65 + nl], t[(dp*2+1)*65 + nl]);
            *(__half2*)(feats + ((size_t)b*NN + n)*DD + dp*2) = h;
        }
    }
}

// ---------------- w fp32 -> fp16 (same [o][c] layout) ----------------
__global__ void k_convert_w(const float* __restrict__ w1, const float* __restrict__ w2,
                            __half* __restrict__ w1h, __half* __restrict__ w2h) {
    int i = blockIdx.x*256 + threadIdx.x;   // 64 blocks * 256 = 16384
    w1h[i] = __float2half(w1[i]);
    w2h[i] = __float2half(w2[i]);
}

// ---------------- KNN: radix-histogram rank selection ----------------
// Round-7 PMC: SQ_LDS_BANK_CONFLICT was BIT-IDENTICAL (2.318e7) before and
// after 4-way replication -- because replica stride 256 ints = 1024 B puts
// all 4 replicas of a bin in the SAME bank (LDS atomics serialize per-bank
// ALU; same-address queues became same-bank queues, same total cycles).
// Fix: HSTRIDE=264 (264%32==8) -> replicas of bin b sit in banks (b+8c)%32,
// four distinct banks, 4x parallel atomic throughput.
__global__ void __launch_bounds__(256) k_knn(const float* __restrict__ coords,
                                             int* __restrict__ idx_out,
                                             int* __restrict__ cnt) {
#pragma clang fp contract(off)
    __shared__ int hist[QPB][4*HSTRIDE];  // 4224 B per wave, 16.9 KB total
    __shared__ unsigned bcast[QPB][2];    // [0]=bucket, [1]=count below bucket
    int w = threadIdx.x >> 6, lane = threadIdx.x & 63;
    int p = blockIdx.x*QPB + w;
    int b = p / NN, n = p - b*NN;
    const float* cb = coords + (size_t)b*NN*3;
    float qx = cb[n*3+0], qy = cb[n*3+1], qz = cb[n*3+2];
    float sqn = (qx*qx + qy*qy) + qz*qz;

    unsigned key[NCHUNK];
#pragma unroll
    for (int i = 0; i < NCHUNK; ++i) {
        int m = lane + i*64;
        unsigned u = 0xFFFFFFFFu;
        if (m < NN) {
            float cx = cb[m*3+0], cy = cb[m*3+1], cz = cb[m*3+2];
            float sqm = (cx*cx + cy*cy) + cz*cz;
            float dot = (qx*cx + qy*cy) + qz*cz;
            float d = (sqn + sqm) - 2.0f*dot;
            unsigned t = __float_as_uint(d);
            u = (t & 0x80000000u) ? ~t : (t | 0x80000000u);
        }
        key[i] = u;
    }
    int* hrep = hist[w] + (lane & 3)*HSTRIDE;

    // ---- pass A: histogram on key[31:24] ----
    for (int i = lane; i < 4*HSTRIDE; i += 64) hist[w][i] = 0;
    __syncthreads();
#pragma unroll
    for (int i = 0; i < NCHUNK; ++i) {
        int m = lane + i*64;
        if (m < NN) atomicAdd(&hrep[key[i] >> 24], 1);
    }
    __syncthreads();
    {
        int v0 = 0, v1 = 0, v2 = 0, v3 = 0;
#pragma unroll
        for (int c = 0; c < 4; ++c) {
            const int* h = hist[w] + c*HSTRIDE;
            v0 += h[lane*4+0]; v1 += h[lane*4+1];
            v2 += h[lane*4+2]; v3 += h[lane*4+3];
        }
        int c1 = v0+v1, c2 = c1+v2, c3 = c2+v3;
        int inc = c3;
#pragma unroll
        for (int off = 1; off < 64; off <<= 1) {
            int t = __shfl_up(inc, off);
            if (lane >= off) inc += t;
        }
        int base = inc - c3;
        if (base < KK) {
            int u0 = base+v0, u1 = base+c1, u2 = base+c2, u3 = base+c3;
            if      (u0 >= KK) { bcast[w][0] = lane*4+0; bcast[w][1] = base; }
            else if (u1 >= KK) { bcast[w][0] = lane*4+1; bcast[w][1] = u0; }
            else if (u2 >= KK) { bcast[w][0] = lane*4+2; bcast[w][1] = u1; }
            else if (u3 >= KK) { bcast[w][0] = lane*4+3; bcast[w][1] = u2; }
        }
    }
    __syncthreads();
    unsigned BA = bcast[w][0];
    int rA = KK - (int)bcast[w][1];
    __syncthreads();

    // ---- pass B: histogram on key[23:16] within bucket BA ----
    for (int i = lane; i < 4*HSTRIDE; i += 64) hist[w][i] = 0;
    __syncthreads();
#pragma unroll
    for (int i = 0; i < NCHUNK; ++i) {
        int m = lane + i*64;
        if (m < NN && (key[i] >> 24) == BA) atomicAdd(&hrep[(key[i] >> 16) & 255], 1);
    }
    __syncthreads();
    {
        int v0 = 0, v1 = 0, v2 = 0, v3 = 0;
#pragma unroll
        for (int c = 0; c < 4; ++c) {
            const int* h = hist[w] + c*HSTRIDE;
            v0 += h[lane*4+0]; v1 += h[lane*4+1];
            v2 += h[lane*4+2]; v3 += h[lane*4+3];
        }
        int c1 = v0+v1, c2 = c1+v2, c3 = c2+v3;
        int inc = c3;
#pragma unroll
        for (int off = 1; off < 64; off <<= 1) {
            int t = __shfl_up(inc, off);
            if (lane >= off) inc += t;
        }
        int base = inc - c3;
        if (base < rA) {
            int u0 = base+v0, u1 = base+c1, u2 = base+c2, u3 = base+c3;
            if      (u0 >= rA) { bcast[w][0] = lane*4+0; bcast[w][1] = base; }
            else if (u1 >= rA) { bcast[w][0] = lane*4+1; bcast[w][1] = u0; }
            else if (u2 >= rA) { bcast[w][0] = lane*4+2; bcast[w][1] = u1; }
            else if (u3 >= rA) { bcast[w][0] = lane*4+3; bcast[w][1] = u2; }
        }
    }
    __syncthreads();
    unsigned prefix16 = (BA << 8) | bcast[w][0];
    int r = rA - (int)bcast[w][1];

    // ---- extract exact 32nd (key, m) pair (wave-local, no barriers) ----
    unsigned long long fl = 0;
    for (int round = 0; round < r; ++round) {
        unsigned long long best = ~0ull;
#pragma unroll
        for (int i = 0; i < NCHUNK; ++i) {
            if ((key[i] >> 16) == prefix16) {
                unsigned long long v = ((unsigned long long)key[i] << 32) | (unsigned)(lane + i*64);
                if (v > fl && v < best) best = v;
            }
        }
#pragma unroll
        for (int off = 32; off; off >>= 1) {
            unsigned long long o = __shfl_xor(best, off, 64);
            if (o < best) best = o;
        }
        fl = best;
    }
    unsigned kstar = (unsigned)(fl >> 32);
    unsigned mstar = (unsigned)fl;

    int cnt_ = 0;
    unsigned long long mylow = (1ull << lane) - 1ull;
#pragma unroll
    for (int i = 0; i < NCHUNK; ++i) {
        unsigned m = lane + i*64;
        bool sel = (key[i] < kstar) || (key[i] == kstar && m <= mstar);
        unsigned long long bal = __ballot(sel);
        if (sel) {
            int pos = cnt_ + __popcll(bal & mylow);
            idx_out[p*KK + pos] = (int)m;
            atomicAdd(&cnt[b*NN + (int)m], 1);
        }
        cnt_ += __popcll(bal);
    }
}

// ---------------- gather-sum: s_p = sum_k f_nb(p,k), fp32 ----------------
__global__ void __launch_bounds__(256) k_gather_sum(const __half* __restrict__ feats,
                                                    const int* __restrict__ knn_idx,
                                                    float* __restrict__ s_arr) {
    int w = threadIdx.x >> 6, lane = threadIdx.x & 63;
    int p = blockIdx.x*4 + w;
    int b = p / NN;
    int bbase = b*NN;
    int idx = 0;
    if (lane < KK) idx = knn_idx[p*KK + lane];
    float s = 0.f;
#pragma unroll
    for (int k = 0; k < KK; ++k) {
        int nb = __shfl(idx, k);
        s += __half2float(feats[((size_t)(bbase + nb))*DD + lane]);
    }
    s_arr[(size_t)p*DD + lane] = s;
}

// ---------------- gram: per-block partial M1/M2/M3 + vectors ----------------
// M1 = sum cnt_m f f^T, M2 = sum s_p f_p^T, M3 = sum f f^T, vcf = sum cnt f, vf = sum f
__global__ void __launch_bounds__(256) k_gram(const __half* __restrict__ feats,
                                              const float* __restrict__ s_arr,
                                              const int* __restrict__ cnt,
                                              float* __restrict__ Mpart) {
    __shared__ float fs[4][64];
    __shared__ float ss[4][64];
    __shared__ float cs[4];
    int tid = threadIdx.x;
    int rt = tid >> 4, ct = tid & 15;
    int r0 = rt*4, c0 = ct*4;
    float m1a[4][4] = {{0}}, m2a[4][4] = {{0}}, m3a[4][4] = {{0}};
    float vcf4[4] = {0,0,0,0}, vf4[4] = {0,0,0,0};

    int per = (PAIRS + GRAM_BLOCKS - 1)/GRAM_BLOCKS;   // 203
    int p0 = blockIdx.x * per;
    int p1 = p0 + per; if (p1 > PAIRS) p1 = PAIRS;

    for (int pc = p0; pc < p1; pc += 4) {
        __syncthreads();
        int sub = tid >> 6, l = tid & 63;
        int pp = pc + sub;
        if (pp < p1) {
            fs[sub][l] = __half2float(feats[(size_t)pp*DD + l]);
            ss[sub][l] = s_arr[(size_t)pp*DD + l];
            if (l == 0) cs[sub] = (float)cnt[pp];
        }
        __syncthreads();
        int e = p1 - pc; if (e > 4) e = 4;
        for (int j = 0; j < e; ++j) {
            float cn = cs[j];
            float fr[4], sr[4], fc[4];
#pragma unroll
            for (int a = 0; a < 4; ++a) { fr[a] = fs[j][r0+a]; sr[a] = ss[j][r0+a]; fc[a] = fs[j][c0+a]; }
#pragma unroll
            for (int a = 0; a < 4; ++a) {
                float cfr = cn * fr[a];
#pragma unroll
                for (int bc = 0; bc < 4; ++bc) {
                    m1a[a][bc] = fmaf(cfr,   fc[bc], m1a[a][bc]);
                    m2a[a][bc] = fmaf(sr[a], fc[bc], m2a[a][bc]);
                    m3a[a][bc] = fmaf(fr[a], fc[bc], m3a[a][bc]);
                }
                if (ct == 0) { vcf4[a] += cfr; vf4[a] += fr[a]; }
            }
        }
    }
    float* out = Mpart + (size_t)blockIdx.x * MSTRIDE;
#pragma unroll
    for (int a = 0; a < 4; ++a)
#pragma unroll
        for (int bc = 0; bc < 4; ++bc) {
            int idx = (r0+a)*64 + c0+bc;
            out[idx]        = m1a[a][bc];
            out[4096 + idx] = m2a[a][bc];
            out[8192 + idx] = m3a[a][bc];
        }
    if (ct == 0)
#pragma unroll
        for (int a = 0; a < 4; ++a) {
            out[12288 + r0+a] = vcf4[a];
            out[12352 + r0+a] = vf4[a];
        }
}

__global__ void __launch_bounds__(256) k_gram_reduce(const float* __restrict__ Mpart,
                                                     float* __restrict__ Mfin) {
    int e = blockIdx.x*256 + threadIdx.x;
    if (e < MSTRIDE) {
        float s = 0.f;
        for (int p = 0; p < GRAM_BLOCKS; ++p) s += Mpart[(size_t)p*MSTRIDE + e];
        Mfin[e] = s;
    }
}

// ---------------- stats1 from Gram: one block per output channel o ----------------
__global__ void __launch_bounds__(256) k_stats1(const float* __restrict__ M,
                                                const __half* __restrict__ w1h,
                                                const float* __restrict__ g1,
                                                const float* __restrict__ b1,
                                                float* __restrict__ ab1) {
    __shared__ float wl[64], wr[64];
    __shared__ float redA[256], redB[256];
    int o = blockIdx.x, tid = threadIdx.x;
    if (tid < 64)       wl[tid]    = __half2float(w1h[o*CC + tid]);
    else if (tid < 128) wr[tid-64] = __half2float(w1h[o*CC + tid]);
    __syncthreads();
    const float* M1 = M;
    const float* M2 = M + 4096;
    const float* M3 = M + 8192;
    const float* vcf = M + 12288;
    const float* vf  = M + 12352;
    float part = 0.f;
    for (int e = tid; e < 4096; e += 256) {
        int i = e >> 6, j = e & 63;
        float m1 = M1[e], m2 = M2[e], m2t = M2[j*64 + i], m3 = M3[e];
        float A  = m1 - m2 - m2t + 32.f*m3;   // sum u u^T
        float Bc = m2 - 32.f*m3;              // sum u v^T
        part += wl[i]*(A*wl[j] + 2.f*Bc*wr[j]) + 32.f*wr[i]*m3*wr[j];
    }
    float psum = 0.f;
    if (tid < 64) psum = wl[tid]*(vcf[tid] - 32.f*vf[tid]) + 32.f*wr[tid]*vf[tid];
    redA[tid] = part; redB[tid] = psum;
    __syncthreads();
    for (int s = 128; s > 0; s >>= 1) {
        if (tid < s) { redA[tid] += redA[tid+s]; redB[tid] += redB[tid+s]; }
        __syncthreads();
    }
    if (tid == 0) {
        float sumsq = redA[0], sum = redB[0];
        float mean = sum / (float)ROWS;
        float var  = sumsq / (float)ROWS - mean*mean;
        float a = g1[o] * rsqrtf(var + EPSV);
        ab1[o] = a;
        ab1[CC + o] = b1[o] - mean*a;
    }
}

// ============ staging helpers: coalesced gather + XOR-swizzled LDS ============
__device__ __forceinline__ void fill_bases(const int* __restrict__ knn_idx,
                                           int blk, int tid, int* rowb) {
#pragma unroll
    for (int e = tid; e < TPB_TILES*64; e += 256) {
        int tile = blk*TPB_TILES + (e >> 6);
        int rr = e & 63;
        int p = tile*2 + (rr >> 5);
        int nb = knn_idx[p*KK + (rr & 31)];
        int b = p / NN;
        rowb[e] = (b*NN + nb)*DD;
    }
}

__device__ __forceinline__ void stage_load(const __half* __restrict__ feats,
                                           const int* rowb, int blk,
                                           int tloc, int tid, uint4* A) {
    int kc = tid & 15;
#pragma unroll
    for (int it = 0; it < 4; ++it) {
        int row = it*16 + (tid >> 4);
        int e = tloc*64 + row;
        int p = (blk*TPB_TILES + tloc)*2 + (row >> 5);
        int ra = (kc < 8) ? (rowb[e] + kc*8) : (p*DD + (kc-8)*8);
        A[it] = *(const uint4*)(feats + ra);
    }
}

// stage_write: center row recovered from lane (kc^8)'s prefetch via shfl_xor.
__device__ __forceinline__ void stage_write(int tid, const uint4* A, __half* nf) {
    int kc = tid & 15;
#pragma unroll
    for (int it = 0; it < 4; ++it) {
        int row = it*16 + (tid >> 4);
        union { uint4 u; __half2 h[4]; } a, b, rr;
        a.u = A[it];
        b.u.x = (unsigned)__shfl_xor((int)a.u.x, 8);
        b.u.y = (unsigned)__shfl_xor((int)a.u.y, 8);
        b.u.z = (unsigned)__shfl_xor((int)a.u.z, 8);
        b.u.w = (unsigned)__shfl_xor((int)a.u.w, 8);
        if (kc < 8) {
#pragma unroll
            for (int j = 0; j < 4; ++j) rr.h[j] = __hsub2(a.h[j], b.h[j]);
        } else {
            rr.u = a.u;
        }
        int C = (row >> 4)*256 + kc*16 + ((row & 15) ^ kc);   // XOR swizzle
        *(uint4*)(nf + C*8) = rr.u;
    }
}

// ---------------- finalize bn params (layer 2) ----------------
__global__ void k_finalize(const float* __restrict__ gsum, const float* __restrict__ gsumsq,
                           const float* __restrict__ g, const float* __restrict__ bb,
                           float* __restrict__ ab) {
    int o = threadIdx.x;
    float cnt = (float)ROWS;
    float mean = gsum[o] / cnt;
    float var = gsumsq[o] / cnt - mean*mean;
    float a = g[o] * rsqrtf(var + EPSV);
    ab[o] = a;
    ab[CC + o] = bb[o] - mean*a;
}

// ---------------- fused: mm1 + bn1relu + mm2 + stats2 + per-pair max/min ----------------
// Round-6 proven operating point: launch_bounds(256,4) + LDS>40KB (pad)
// -> 3 blocks/CU -> 170-reg budget -> resident weights, zero spill.
// mm2 operand-swapped so per-pair max/min needs 2 shfls instead of a
// 4-step butterfly. DO NOT change LDS below 40 KB (rounds 1-5 ledger).
__global__ void __launch_bounds__(256, 4)
k_fused_mfma(const __half* __restrict__ feats,
             const int* __restrict__ knn_idx,
             const __half* __restrict__ w1h,
             const __half* __restrict__ w2h,
             const float* __restrict__ ab1,
             float* __restrict__ gsum2,
             float* __restrict__ gsumsq2,
             float* __restrict__ wsmax,
             float* __restrict__ wsmin) {
    __shared__ __align__(16) __half nf[8192];     // 16 KB, swizzled chunks
    __shared__ __align__(16) __half y1s[8192];    // 16 KB, same swizzled layout
    __shared__ __align__(16) float abs_lds[256];  // bn1 a (0..127), c (128..255)
    __shared__ int rowb[TPB_TILES*64];            // 2 KB
    __shared__ float lds_pad[1312];               // 5.25 KB occupancy shaping
    int tid = threadIdx.x;
    int lane = tid & 63, wid = tid >> 6;
    int m = lane & 15, q = lane >> 4;

    fill_bases(knn_idx, blockIdx.x, tid, rowb);
    abs_lds[tid] = ab1[tid];
    ((volatile float*)lds_pad)[tid] = 0.f;

    half8 w1f[2][4], w2f[2][4];
#pragma unroll
    for (int ob = 0; ob < 2; ++ob)
#pragma unroll
        for (int t = 0; t < 4; ++t) {
            int o = wid*32 + ob*16 + m;
            w1f[ob][t] = *(const half8*)(w1h + o*CC + t*32 + q*8);
            w2f[ob][t] = *(const half8*)(w2h + o*CC + t*32 + q*8);
        }

    f32x4 zero4 = {0.f, 0.f, 0.f, 0.f};
    f32x4 ssum[2] = {zero4, zero4}, ssq[2] = {zero4, zero4};

    __syncthreads();
    uint4 pf[4];
    stage_load(feats, rowb, blockIdx.x, 0, tid, pf);

    for (int it = 0; it < TPB_TILES; ++it) {
        int tile = blockIdx.x * TPB_TILES + it;

        stage_write(tid, pf, nf);
        __syncthreads();                               // B1
        if (it + 1 < TPB_TILES) stage_load(feats, rowb, blockIdx.x, it + 1, tid, pf);

        f32x4 acc[2][4];
#pragma unroll
        for (int ob = 0; ob < 2; ++ob)
#pragma unroll
            for (int rbk = 0; rbk < 4; ++rbk) acc[ob][rbk] = zero4;

        // mm1: z1^T = w1 . nf^T
#pragma unroll
        for (int t = 0; t < 4; ++t) {
            int kct = t*4 + q;
            int sw = m ^ kct;
#pragma unroll
            for (int rbk = 0; rbk < 4; ++rbk) {
                half8 bfr = *(const half8*)(nf + (rbk*256 + kct*16 + sw)*8);
                acc[0][rbk] = __builtin_amdgcn_mfma_f32_16x16x32_f16(w1f[0][t], bfr, acc[0][rbk], 0, 0, 0);
                acc[1][rbk] = __builtin_amdgcn_mfma_f32_16x16x32_f16(w1f[1][t], bfr, acc[1][rbk], 0, 0, 0);
            }
        }

        // bn1 + relu, write y1 in swizzled chunk layout (a/c broadcast from LDS)
#pragma unroll
        for (int ob = 0; ob < 2; ++ob) {
            f32x4 av = *(const f32x4*)(abs_lds + wid*32 + ob*16 + q*4);
            f32x4 cv = *(const f32x4*)(abs_lds + 128 + wid*32 + ob*16 + q*4);
#pragma unroll
            for (int rbk = 0; rbk < 4; ++rbk) {
                f32x4 z = acc[ob][rbk];
                float y0 = relu_(fmaf(av[0], z[0], cv[0]));
                float y1 = relu_(fmaf(av[1], z[1], cv[1]));
                float y2 = relu_(fmaf(av[2], z[2], cv[2]));
                float y3 = relu_(fmaf(av[3], z[3], cv[3]));
                H2U p0, p1;
                p0.h = __floats2half2_rn(y0, y1);
                p1.h = __floats2half2_rn(y2, y3);
                int kcy = wid*4 + ob*2 + (q >> 1);
                int C = rbk*256 + kcy*16 + (m ^ kcy);
                uint2 v; v.x = p0.u; v.y = p1.u;
                *(uint2*)(y1s + C*8 + (q & 1)*4) = v;
            }
        }
        __syncthreads();                               // B2

        // mm2 SWAPPED: channel = lane&15, row = rbk*16 + q*4 + c
#pragma unroll
        for (int ob = 0; ob < 2; ++ob)
#pragma unroll
            for (int rbk = 0; rbk < 4; ++rbk) acc[ob][rbk] = zero4;
#pragma unroll
        for (int t = 0; t < 4; ++t) {
            int kct = t*4 + q;
            int sw = m ^ kct;
#pragma unroll
            for (int rbk = 0; rbk < 4; ++rbk) {
                half8 bfr = *(const half8*)(y1s + (rbk*256 + kct*16 + sw)*8);
                acc[0][rbk] = __builtin_amdgcn_mfma_f32_16x16x32_f16(bfr, w2f[0][t], acc[0][rbk], 0, 0, 0);
                acc[1][rbk] = __builtin_amdgcn_mfma_f32_16x16x32_f16(bfr, w2f[1][t], acc[1][rbk], 0, 0, 0);
            }
        }
        // stats2
#pragma unroll
        for (int ob = 0; ob < 2; ++ob)
#pragma unroll
            for (int rbk = 0; rbk < 4; ++rbk) {
                ssum[ob] += acc[ob][rbk];
                ssq[ob]  += acc[ob][rbk]*acc[ob][rbk];
            }
        // per-pair max/min: 7 in-thread fmax + 2 shfls
#pragma unroll
        for (int ob = 0; ob < 2; ++ob)
#pragma unroll
            for (int pr = 0; pr < 2; ++pr) {
                f32x4 x0 = acc[ob][pr*2], x1 = acc[ob][pr*2 + 1];
                float mx = fmaxf(fmaxf(fmaxf(x0[0], x0[1]), fmaxf(x0[2], x0[3])),
                                 fmaxf(fmaxf(x1[0], x1[1]), fmaxf(x1[2], x1[3])));
                float mn = fminf(fminf(fminf(x0[0], x0[1]), fminf(x0[2], x0[3])),
                                 fminf(fminf(x1[0], x1[1]), fminf(x1[2], x1[3])));
                mx = fmaxf(mx, __shfl_xor(mx, 16));
                mx = fmaxf(mx, __shfl_xor(mx, 32));
                mn = fminf(mn, __shfl_xor(mn, 16));
                mn = fminf(mn, __shfl_xor(mn, 32));
                if (lane < 16) {
                    int p = tile*2 + pr;
                    int o = wid*32 + ob*16 + m;
                    wsmax[(size_t)p*CC + o] = mx;
                    wsmin[(size_t)p*CC + o] = mn;
                }
            }
    }
#pragma unroll
    for (int ob = 0; ob < 2; ++ob) {
        float v  = ssum[ob][0] + ssum[ob][1] + ssum[ob][2] + ssum[ob][3];
        float v2 = ssq[ob][0]  + ssq[ob][1]  + ssq[ob][2]  + ssq[ob][3];
        v  += __shfl_xor(v, 16);  v  += __shfl_xor(v, 32);
        v2 += __shfl_xor(v2, 16); v2 += __shfl_xor(v2, 32);
        if (lane < 16) {
            int o = wid*32 + ob*16 + m;
            atomicAdd(&gsum2[o], v);
            atomicAdd(&gsumsq2[o], v2);
        }
    }
}

// ---------------- epilogue: bn2+relu on max/min, transpose to (B,C,N) ----------------
__global__ void __launch_bounds__(256) k_epilogue(const float* __restrict__ wsmax,
                                                  const float* __restrict__ wsmin,
                                                  const float* __restrict__ ab2,
                                                  float* __restrict__ out) {
    __shared__ float t[128*65];
    int b = blockIdx.y;
    int n0 = blockIdx.x * 64;
    int tid = threadIdx.x;
#pragma unroll
    for (int i = 0; i < 32; ++i) {
        int idx = i*256 + tid;
        int nl = idx >> 7, o = idx & 127;
        int n = n0 + nl;
        float v = 0.f;
        if (n < NN) {
            float a = ab2[o], cc = ab2[CC + o];
            size_t p = (size_t)b*NN + n;
            float z = (a >= 0.f) ? wsmax[p*CC + o] : wsmin[p*CC + o];
            v = fmaf(a, z, cc);
            v = v > 0.f ? v : 0.f;
        }
        t[o*65 + nl] = v;
    }
    __syncthreads();
#pragma unroll
    for (int i = 0; i < 32; ++i) {
        int idx = i*256 + tid;
        int o = idx >> 6, nl = idx & 63;
        int n = n0 + nl;
        if (n < NN) out[((size_t)b*CC + o)*NN + n] = t[o*65 + nl];
    }
}

extern "C" void kernel_launch(void* const* d_in, const int* in_sizes, int n_in,
                              void* d_out, int out_size, void* d_ws, size_t ws_size,
                              hipStream_t stream) {
    const float* x      = (const float*)d_in[0];
    const float* coords = (const float*)d_in[1];
    const float* w1     = (const float*)d_in[2];
    const float* g1     = (const float*)d_in[3];
    const float* b1     = (const float*)d_in[4];
    const float* w2     = (const float*)d_in[5];
    const float* g2     = (const float*)d_in[6];
    const float* b2     = (const float*)d_in[7];
    float* out = (float*)d_out;

    char* ws = (char*)d_ws;
    size_t off = 0;
    int* knn_idx = (int*)(ws + off);   off += (size_t)ROWS * sizeof(int);        // 3.32 MB
    float* stats = (float*)(ws + off); off += 1024 * sizeof(float);
    float* gsum2 = stats + 256, *gsq2 = stats + 384;
    float* ab1   = stats + 512;
    float* ab2   = stats + 768;
    __half* feats = (__half*)(ws + off); off += (size_t)BB*NN*DD * sizeof(__half); // 3.32 MB
    __half* w1h   = (__half*)(ws + off); off += CC*CC * sizeof(__half);
    __half* w2h   = (__half*)(ws + off); off += CC*CC * sizeof(__half);
    float* wsmax = (float*)(ws + off);  off += (size_t)PAIRS*CC * sizeof(float);  // 13.3 MB
    float* wsmin = (float*)(ws + off);  off += (size_t)PAIRS*CC * sizeof(float);  // 13.3 MB
    int*   cnt   = (int*)(ws + off);    off += (size_t)PAIRS * sizeof(int);       // 104 KB
    float* Mfin  = (float*)(ws + off);  off += (size_t)MSTRIDE * sizeof(float);   // 50 KB
    // aliases (dead before k_fused writes wsmax/wsmin):
    float* s_arr = wsmax;                    // PAIRS*64 fp32 = 6.64 MB  (<13.3)
    float* Mpart = wsmin;                    // 128*12416 fp32 = 6.36 MB (<13.3)
    (void)ws_size; (void)in_sizes; (void)n_in; (void)out_size;

    hipMemsetAsync(stats, 0, 512 * sizeof(float), stream);
    hipMemsetAsync(cnt, 0, (size_t)PAIRS * sizeof(int), stream);

    dim3 gT((NN + 63)/64, BB);
    k_prep_feats<<<gT, 256, 0, stream>>>(x, feats);
    k_convert_w<<<64, 256, 0, stream>>>(w1, w2, w1h, w2h);
    k_knn<<<PAIRS/QPB, 256, 0, stream>>>(coords, knn_idx, cnt);
    k_gather_sum<<<PAIRS/4, 256, 0, stream>>>(feats, knn_idx, s_arr);
    k_gram<<<GRAM_BLOCKS, 256, 0, stream>>>(feats, s_arr, cnt, Mpart);
    k_gram_reduce<<<(MSTRIDE + 255)/256, 256, 0, stream>>>(Mpart, Mfin);
    k_stats1<<<CC, 256, 0, stream>>>(Mfin, w1h, g1, b1, ab1);
    k_fused_mfma<<<GRID_MM, 256, 0, stream>>>(feats, knn_idx, w1h, w2h, ab1,
                                              gsum2, gsq2, wsmax, wsmin);
    k_finalize<<<1, CC, 0, stream>>>(gsum2, gsq2, g2, b2, ab2);
    dim3 gE((NN + 63)/64, BB);
    k_epilogue<<<gE, 256, 0, stream>>>(wsmax, wsmin, ab2, out);
}

// Round 9
// 371.069 us; speedup vs baseline: 1.8624x; 1.0441x over previous
//
#include <hip/hip_runtime.h>
#include <hip/hip_fp16.h>
#include <stdint.h>

#define BB 16
#define NN 1620
#define DD 64
#define CC 128
#define KK 32
#define EPSV 1e-5f
#define PAIRS (BB*NN)            // 25920
#define ROWS  (PAIRS*KK)         // 829440
#define TILES (PAIRS/2)          // 12960 tiles of 64 rows
#define TPB_TILES 8
#define GRID_MM (TILES/TPB_TILES) // 1620
#define NCHUNK 26                // ceil(1620/64)
#define GRAM_BLOCKS 256          // was 128: only half the CUs had work
#define MSTRIDE 12416            // 3*4096 mats + 64 vcf + 64 vf
#define QPB 4                    // knn queries per 256-thread block
#define HSTRIDE 264              // replica stride (ints): 264 % 32 == 8 ->
                                 // replicas of a bin land in 4 DISTINCT banks

typedef _Float16 half8 __attribute__((ext_vector_type(8)));
typedef float f32x4 __attribute__((ext_vector_type(4)));

__device__ __forceinline__ float relu_(float v){ return v > 0.f ? v : 0.f; }

union H2U { __half2 h; unsigned u; };

// ---------------- x (B,D,N) fp32 -> feats (B,N,D) fp16 ----------------
__global__ void __launch_bounds__(256) k_prep_feats(const float* __restrict__ x,
                                                    __half* __restrict__ feats) {
    __shared__ float t[64*65];
    int b = blockIdx.y;
    int n0 = blockIdx.x * 64;
    int tid = threadIdx.x;
#pragma unroll
    for (int i = 0; i < 16; ++i) {
        int idx = i*256 + tid;
        int d = idx >> 6, nl = idx & 63;
        int n = n0 + nl;
        float v = 0.f;
        if (n < NN) v = x[((size_t)b*DD + d)*NN + n];
        t[d*65 + nl] = v;
    }
    __syncthreads();
#pragma unroll
    for (int i = 0; i < 8; ++i) {
        int idx = i*256 + tid;            // 64 nl x 32 d-pairs
        int nl = idx >> 5, dp = idx & 31;
        int n = n0 + nl;
        if (n < NN) {
            __half2 h = __floats2half2_rn(t[(dp*2)*65 + nl], t[(dp*2+1)*65 + nl]);
            *(__half2*)(feats + ((size_t)b*NN + n)*DD + dp*2) = h;
        }
    }
}

// ---------------- w fp32 -> fp16 (same [o][c] layout) ----------------
__global__ void k_convert_w(const float* __restrict__ w1, const float* __restrict__ w2,
                            __half* __restrict__ w1h, __half* __restrict__ w2h) {
    int i = blockIdx.x*256 + threadIdx.x;   // 64 blocks * 256 = 16384
    w1h[i] = __float2half(w1[i]);
    w2h[i] = __float2half(w2[i]);
}

// ---------------- KNN: radix-histogram rank selection ----------------
// Round-8: VALUBusy 44% -> 56% stalled on 78 scalar L2 loads/wave (26x3
// coords, 12B stride), re-read 4x per block (all 4 waves share b since
// NN%QPB==0). Stage coords ONCE per block into SoA LDS (stride-1 lane
// access = 2 lanes/bank = free); distance loop reads LDS. LDS 36.4 KB ->
// 4 blocks/CU = 16 waves, >= current 12.4 effective occupancy.
// HSTRIDE=264 keeps histogram replicas in 4 distinct banks (round-7 fix).
__global__ void __launch_bounds__(256) k_knn(const float* __restrict__ coords,
                                             int* __restrict__ idx_out,
                                             int* __restrict__ cnt) {
#pragma clang fp contract(off)
    __shared__ int hist[QPB][4*HSTRIDE];  // 16.9 KB
    __shared__ unsigned bcast[QPB][2];
    __shared__ float cxs[NN], cys[NN], czs[NN];   // 19.4 KB SoA coords
    int tid = threadIdx.x;
    int w = tid >> 6, lane = tid & 63;
    int p = blockIdx.x*QPB + w;
    int b = (blockIdx.x*QPB) / NN;        // block-uniform (NN % QPB == 0)
    int n = p - b*NN;
    const float* cb = coords + (size_t)b*NN*3;

    // stage coords (block-wide, 12B/thread contiguous) + zero histograms
    for (int i = tid; i < NN; i += 256) {
        float3 c = *(const float3*)(cb + i*3);
        cxs[i] = c.x; cys[i] = c.y; czs[i] = c.z;
    }
    for (int i = lane; i < 4*HSTRIDE; i += 64) hist[w][i] = 0;
    __syncthreads();

    float qx = cxs[n], qy = cys[n], qz = czs[n];
    float sqn = (qx*qx + qy*qy) + qz*qz;

    unsigned key[NCHUNK];
#pragma unroll
    for (int i = 0; i < NCHUNK; ++i) {
        int m = lane + i*64;
        unsigned u = 0xFFFFFFFFu;
        if (m < NN) {
            float cx = cxs[m], cy = cys[m], cz = czs[m];
            float sqm = (cx*cx + cy*cy) + cz*cz;
            float dot = (qx*cx + qy*cy) + qz*cz;
            float d = (sqn + sqm) - 2.0f*dot;
            unsigned t = __float_as_uint(d);
            u = (t & 0x80000000u) ? ~t : (t | 0x80000000u);
        }
        key[i] = u;
    }
    int* hrep = hist[w] + (lane & 3)*HSTRIDE;

    // ---- pass A: histogram on key[31:24] ----
#pragma unroll
    for (int i = 0; i < NCHUNK; ++i) {
        int m = lane + i*64;
        if (m < NN) atomicAdd(&hrep[key[i] >> 24], 1);
    }
    __syncthreads();
    {
        int v0 = 0, v1 = 0, v2 = 0, v3 = 0;
#pragma unroll
        for (int c = 0; c < 4; ++c) {
            const int* h = hist[w] + c*HSTRIDE;
            v0 += h[lane*4+0]; v1 += h[lane*4+1];
            v2 += h[lane*4+2]; v3 += h[lane*4+3];
        }
        int c1 = v0+v1, c2 = c1+v2, c3 = c2+v3;
        int inc = c3;
#pragma unroll
        for (int off = 1; off < 64; off <<= 1) {
            int t = __shfl_up(inc, off);
            if (lane >= off) inc += t;
        }
        int base = inc - c3;
        if (base < KK) {
            int u0 = base+v0, u1 = base+c1, u2 = base+c2, u3 = base+c3;
            if      (u0 >= KK) { bcast[w][0] = lane*4+0; bcast[w][1] = base; }
            else if (u1 >= KK) { bcast[w][0] = lane*4+1; bcast[w][1] = u0; }
            else if (u2 >= KK) { bcast[w][0] = lane*4+2; bcast[w][1] = u1; }
            else if (u3 >= KK) { bcast[w][0] = lane*4+3; bcast[w][1] = u2; }
        }
    }
    __syncthreads();
    unsigned BA = bcast[w][0];
    int rA = KK - (int)bcast[w][1];
    __syncthreads();

    // ---- pass B: histogram on key[23:16] within bucket BA ----
    for (int i = lane; i < 4*HSTRIDE; i += 64) hist[w][i] = 0;
    __syncthreads();
#pragma unroll
    for (int i = 0; i < NCHUNK; ++i) {
        int m = lane + i*64;
        if (m < NN && (key[i] >> 24) == BA) atomicAdd(&hrep[(key[i] >> 16) & 255], 1);
    }
    __syncthreads();
    {
        int v0 = 0, v1 = 0, v2 = 0, v3 = 0;
#pragma unroll
        for (int c = 0; c < 4; ++c) {
            const int* h = hist[w] + c*HSTRIDE;
            v0 += h[lane*4+0]; v1 += h[lane*4+1];
            v2 += h[lane*4+2]; v3 += h[lane*4+3];
        }
        int c1 = v0+v1, c2 = c1+v2, c3 = c2+v3;
        int inc = c3;
#pragma unroll
        for (int off = 1; off < 64; off <<= 1) {
            int t = __shfl_up(inc, off);
            if (lane >= off) inc += t;
        }
        int base = inc - c3;
        if (base < rA) {
            int u0 = base+v0, u1 = base+c1, u2 = base+c2, u3 = base+c3;
            if      (u0 >= rA) { bcast[w][0] = lane*4+0; bcast[w][1] = base; }
            else if (u1 >= rA) { bcast[w][0] = lane*4+1; bcast[w][1] = u0; }
            else if (u2 >= rA) { bcast[w][0] = lane*4+2; bcast[w][1] = u1; }
            else if (u3 >= rA) { bcast[w][0] = lane*4+3; bcast[w][1] = u2; }
        }
    }
    __syncthreads();
    unsigned prefix16 = (BA << 8) | bcast[w][0];
    int r = rA - (int)bcast[w][1];

    // ---- extract exact 32nd (key, m) pair (wave-local, no barriers) ----
    unsigned long long fl = 0;
    for (int round = 0; round < r; ++round) {
        unsigned long long best = ~0ull;
#pragma unroll
        for (int i = 0; i < NCHUNK; ++i) {
            if ((key[i] >> 16) == prefix16) {
                unsigned long long v = ((unsigned long long)key[i] << 32) | (unsigned)(lane + i*64);
                if (v > fl && v < best) best = v;
            }
        }
#pragma unroll
        for (int off = 32; off; off >>= 1) {
            unsigned long long o = __shfl_xor(best, off, 64);
            if (o < best) best = o;
        }
        fl = best;
    }
    unsigned kstar = (unsigned)(fl >> 32);
    unsigned mstar = (unsigned)fl;

    int cnt_ = 0;
    unsigned long long mylow = (1ull << lane) - 1ull;
#pragma unroll
    for (int i = 0; i < NCHUNK; ++i) {
        unsigned m = lane + i*64;
        bool sel = (key[i] < kstar) || (key[i] == kstar && m <= mstar);
        unsigned long long bal = __ballot(sel);
        if (sel) {
            int pos = cnt_ + __popcll(bal & mylow);
            idx_out[p*KK + pos] = (int)m;
            atomicAdd(&cnt[b*NN + (int)m], 1);
        }
        cnt_ += __popcll(bal);
    }
}

// ---------------- gather-sum: s_p = sum_k f_nb(p,k), fp32 ----------------
__global__ void __launch_bounds__(256) k_gather_sum(const __half* __restrict__ feats,
                                                    const int* __restrict__ knn_idx,
                                                    float* __restrict__ s_arr) {
    int w = threadIdx.x >> 6, lane = threadIdx.x & 63;
    int p = blockIdx.x*4 + w;
    int b = p / NN;
    int bbase = b*NN;
    int idx = 0;
    if (lane < KK) idx = knn_idx[p*KK + lane];
    float s = 0.f;
#pragma unroll
    for (int k = 0; k < KK; ++k) {
        int nb = __shfl(idx, k);
        s += __half2float(feats[((size_t)(bbase + nb))*DD + lane]);
    }
    s_arr[(size_t)p*DD + lane] = s;
}

// ---------------- gram: per-block partial M1/M2/M3 + vectors ----------------
// M1 = sum cnt_m f f^T, M2 = sum s_p f_p^T, M3 = sum f f^T, vcf = sum cnt f, vf = sum f
__global__ void __launch_bounds__(256) k_gram(const __half* __restrict__ feats,
                                              const float* __restrict__ s_arr,
                                              const int* __restrict__ cnt,
                                              float* __restrict__ Mpart) {
    __shared__ float fs[4][64];
    __shared__ float ss[4][64];
    __shared__ float cs[4];
    int tid = threadIdx.x;
    int rt = tid >> 4, ct = tid & 15;
    int r0 = rt*4, c0 = ct*4;
    float m1a[4][4] = {{0}}, m2a[4][4] = {{0}}, m3a[4][4] = {{0}};
    float vcf4[4] = {0,0,0,0}, vf4[4] = {0,0,0,0};

    int per = (PAIRS + GRAM_BLOCKS - 1)/GRAM_BLOCKS;   // 102
    int p0 = blockIdx.x * per;
    int p1 = p0 + per; if (p1 > PAIRS) p1 = PAIRS;

    for (int pc = p0; pc < p1; pc += 4) {
        __syncthreads();
        int sub = tid >> 6, l = tid & 63;
        int pp = pc + sub;
        if (pp < p1) {
            fs[sub][l] = __half2float(feats[(size_t)pp*DD + l]);
            ss[sub][l] = s_arr[(size_t)pp*DD + l];
            if (l == 0) cs[sub] = (float)cnt[pp];
        }
        __syncthreads();
        int e = p1 - pc; if (e > 4) e = 4;
        for (int j = 0; j < e; ++j) {
            float cn = cs[j];
            float fr[4], sr[4], fc[4];
#pragma unroll
            for (int a = 0; a < 4; ++a) { fr[a] = fs[j][r0+a]; sr[a] = ss[j][r0+a]; fc[a] = fs[j][c0+a]; }
#pragma unroll
            for (int a = 0; a < 4; ++a) {
                float cfr = cn * fr[a];
#pragma unroll
                for (int bc = 0; bc < 4; ++bc) {
                    m1a[a][bc] = fmaf(cfr,   fc[bc], m1a[a][bc]);
                    m2a[a][bc] = fmaf(sr[a], fc[bc], m2a[a][bc]);
                    m3a[a][bc] = fmaf(fr[a], fc[bc], m3a[a][bc]);
                }
                if (ct == 0) { vcf4[a] += cfr; vf4[a] += fr[a]; }
            }
        }
    }
    float* out = Mpart + (size_t)blockIdx.x * MSTRIDE;
#pragma unroll
    for (int a = 0; a < 4; ++a)
#pragma unroll
        for (int bc = 0; bc < 4; ++bc) {
            int idx = (r0+a)*64 + c0+bc;
            out[idx]        = m1a[a][bc];
            out[4096 + idx] = m2a[a][bc];
            out[8192 + idx] = m3a[a][bc];
        }
    if (ct == 0)
#pragma unroll
        for (int a = 0; a < 4; ++a) {
            out[12288 + r0+a] = vcf4[a];
            out[12352 + r0+a] = vf4[a];
        }
}

__global__ void __launch_bounds__(256) k_gram_reduce(const float* __restrict__ Mpart,
                                                     float* __restrict__ Mfin) {
    int e = blockIdx.x*256 + threadIdx.x;
    if (e < MSTRIDE) {
        float s = 0.f;
        for (int p = 0; p < GRAM_BLOCKS; ++p) s += Mpart[(size_t)p*MSTRIDE + e];
        Mfin[e] = s;
    }
}

// ---------------- stats1 from Gram: one block per output channel o ----------------
__global__ void __launch_bounds__(256) k_stats1(const float* __restrict__ M,
                                                const __half* __restrict__ w1h,
                                                const float* __restrict__ g1,
                                                const float* __restrict__ b1,
                                                float* __restrict__ ab1) {
    __shared__ float wl[64], wr[64];
    __shared__ float redA[256], redB[256];
    int o = blockIdx.x, tid = threadIdx.x;
    if (tid < 64)       wl[tid]    = __half2float(w1h[o*CC + tid]);
    else if (tid < 128) wr[tid-64] = __half2float(w1h[o*CC + tid]);
    __syncthreads();
    const float* M1 = M;
    const float* M2 = M + 4096;
    const float* M3 = M + 8192;
    const float* vcf = M + 12288;
    const float* vf  = M + 12352;
    float part = 0.f;
    for (int e = tid; e < 4096; e += 256) {
        int i = e >> 6, j = e & 63;
        float m1 = M1[e], m2 = M2[e], m2t = M2[j*64 + i], m3 = M3[e];
        float A  = m1 - m2 - m2t + 32.f*m3;   // sum u u^T
        float Bc = m2 - 32.f*m3;              // sum u v^T
        part += wl[i]*(A*wl[j] + 2.f*Bc*wr[j]) + 32.f*wr[i]*m3*wr[j];
    }
    float psum = 0.f;
    if (tid < 64) psum = wl[tid]*(vcf[tid] - 32.f*vf[tid]) + 32.f*wr[tid]*vf[tid];
    redA[tid] = part; redB[tid] = psum;
    __syncthreads();
    for (int s = 128; s > 0; s >>= 1) {
        if (tid < s) { redA[tid] += redA[tid+s]; redB[tid] += redB[tid+s]; }
        __syncthreads();
    }
    if (tid == 0) {
        float sumsq = redA[0], sum = redB[0];
        float mean = sum / (float)ROWS;
        float var  = sumsq / (float)ROWS - mean*mean;
        float a = g1[o] * rsqrtf(var + EPSV);
        ab1[o] = a;
        ab1[CC + o] = b1[o] - mean*a;
    }
}

// ============ staging helpers: coalesced gather + XOR-swizzled LDS ============
__device__ __forceinline__ void fill_bases(const int* __restrict__ knn_idx,
                                           int blk, int tid, int* rowb) {
#pragma unroll
    for (int e = tid; e < TPB_TILES*64; e += 256) {
        int tile = blk*TPB_TILES + (e >> 6);
        int rr = e & 63;
        int p = tile*2 + (rr >> 5);
        int nb = knn_idx[p*KK + (rr & 31)];
        int b = p / NN;
        rowb[e] = (b*NN + nb)*DD;
    }
}

__device__ __forceinline__ void stage_load(const __half* __restrict__ feats,
                                           const int* rowb, int blk,
                                           int tloc, int tid, uint4* A) {
    int kc = tid & 15;
#pragma unroll
    for (int it = 0; it < 4; ++it) {
        int row = it*16 + (tid >> 4);
        int e = tloc*64 + row;
        int p = (blk*TPB_TILES + tloc)*2 + (row >> 5);
        int ra = (kc < 8) ? (rowb[e] + kc*8) : (p*DD + (kc-8)*8);
        A[it] = *(const uint4*)(feats + ra);
    }
}

// stage_write: center row recovered from lane (kc^8)'s prefetch via shfl_xor.
__device__ __forceinline__ void stage_write(int tid, const uint4* A, __half* nf) {
    int kc = tid & 15;
#pragma unroll
    for (int it = 0; it < 4; ++it) {
        int row = it*16 + (tid >> 4);
        union { uint4 u; __half2 h[4]; } a, b, rr;
        a.u = A[it];
        b.u.x = (unsigned)__shfl_xor((int)a.u.x, 8);
        b.u.y = (unsigned)__shfl_xor((int)a.u.y, 8);
        b.u.z = (unsigned)__shfl_xor((int)a.u.z, 8);
        b.u.w = (unsigned)__shfl_xor((int)a.u.w, 8);
        if (kc < 8) {
#pragma unroll
            for (int j = 0; j < 4; ++j) rr.h[j] = __hsub2(a.h[j], b.h[j]);
        } else {
            rr.u = a.u;
        }
        int C = (row >> 4)*256 + kc*16 + ((row & 15) ^ kc);   // XOR swizzle
        *(uint4*)(nf + C*8) = rr.u;
    }
}

// ---------------- finalize bn params (layer 2) ----------------
__global__ void k_finalize(const float* __restrict__ gsum, const float* __restrict__ gsumsq,
                           const float* __restrict__ g, const float* __restrict__ bb,
                           float* __restrict__ ab) {
    int o = threadIdx.x;
    float cnt = (float)ROWS;
    float mean = gsum[o] / cnt;
    float var = gsumsq[o] / cnt - mean*mean;
    float a = g[o] * rsqrtf(var + EPSV);
    ab[o] = a;
    ab[CC + o] = bb[o] - mean*a;
}

// ---------------- fused: mm1 + bn1relu + mm2 + stats2 + per-pair max/min ----------------
// LOCKED operating point (rounds 0-8 ledger): launch_bounds(256,4) +
// LDS>40KB (pad) -> 3 blocks/CU -> 170-reg budget -> resident weights,
// ZERO spill (r8: VGPR 112, FETCH 14.5 MB = ideal). mm2 operand-swapped.
__global__ void __launch_bounds__(256, 4)
k_fused_mfma(const __half* __restrict__ feats,
             const int* __restrict__ knn_idx,
             const __half* __restrict__ w1h,
             const __half* __restrict__ w2h,
             const float* __restrict__ ab1,
             float* __restrict__ gsum2,
             float* __restrict__ gsumsq2,
             float* __restrict__ wsmax,
             float* __restrict__ wsmin) {
    __shared__ __align__(16) __half nf[8192];     // 16 KB, swizzled chunks
    __shared__ __align__(16) __half y1s[8192];    // 16 KB, same swizzled layout
    __shared__ __align__(16) float abs_lds[256];  // bn1 a (0..127), c (128..255)
    __shared__ int rowb[TPB_TILES*64];            // 2 KB
    __shared__ float lds_pad[1312];               // 5.25 KB occupancy shaping
    int tid = threadIdx.x;
    int lane = tid & 63, wid = tid >> 6;
    int m = lane & 15, q = lane >> 4;

    fill_bases(knn_idx, blockIdx.x, tid, rowb);
    abs_lds[tid] = ab1[tid];
    ((volatile float*)lds_pad)[tid] = 0.f;

    half8 w1f[2][4], w2f[2][4];
#pragma unroll
    for (int ob = 0; ob < 2; ++ob)
#pragma unroll
        for (int t = 0; t < 4; ++t) {
            int o = wid*32 + ob*16 + m;
            w1f[ob][t] = *(const half8*)(w1h + o*CC + t*32 + q*8);
            w2f[ob][t] = *(const half8*)(w2h + o*CC + t*32 + q*8);
        }

    f32x4 zero4 = {0.f, 0.f, 0.f, 0.f};
    f32x4 ssum[2] = {zero4, zero4}, ssq[2] = {zero4, zero4};

    __syncthreads();
    uint4 pf[4];
    stage_load(feats, rowb, blockIdx.x, 0, tid, pf);

    for (int it = 0; it < TPB_TILES; ++it) {
        int tile = blockIdx.x * TPB_TILES + it;

        stage_write(tid, pf, nf);
        __syncthreads();                               // B1
        if (it + 1 < TPB_TILES) stage_load(feats, rowb, blockIdx.x, it + 1, tid, pf);

        f32x4 acc[2][4];
#pragma unroll
        for (int ob = 0; ob < 2; ++ob)
#pragma unroll
            for (int rbk = 0; rbk < 4; ++rbk) acc[ob][rbk] = zero4;

        // mm1: z1^T = w1 . nf^T
#pragma unroll
        for (int t = 0; t < 4; ++t) {
            int kct = t*4 + q;
            int sw = m ^ kct;
#pragma unroll
            for (int rbk = 0; rbk < 4; ++rbk) {
                half8 bfr = *(const half8*)(nf + (rbk*256 + kct*16 + sw)*8);
                acc[0][rbk] = __builtin_amdgcn_mfma_f32_16x16x32_f16(w1f[0][t], bfr, acc[0][rbk], 0, 0, 0);
                acc[1][rbk] = __builtin_amdgcn_mfma_f32_16x16x32_f16(w1f[1][t], bfr, acc[1][rbk], 0, 0, 0);
            }
        }

        // bn1 + relu, write y1 in swizzled chunk layout (a/c broadcast from LDS)
#pragma unroll
        for (int ob = 0; ob < 2; ++ob) {
            f32x4 av = *(const f32x4*)(abs_lds + wid*32 + ob*16 + q*4);
            f32x4 cv = *(const f32x4*)(abs_lds + 128 + wid*32 + ob*16 + q*4);
#pragma unroll
            for (int rbk = 0; rbk < 4; ++rbk) {
                f32x4 z = acc[ob][rbk];
                float y0 = relu_(fmaf(av[0], z[0], cv[0]));
                float y1 = relu_(fmaf(av[1], z[1], cv[1]));
                float y2 = relu_(fmaf(av[2], z[2], cv[2]));
                float y3 = relu_(fmaf(av[3], z[3], cv[3]));
                H2U p0, p1;
                p0.h = __floats2half2_rn(y0, y1);
                p1.h = __floats2half2_rn(y2, y3);
                int kcy = wid*4 + ob*2 + (q >> 1);
                int C = rbk*256 + kcy*16 + (m ^ kcy);
                uint2 v; v.x = p0.u; v.y = p1.u;
                *(uint2*)(y1s + C*8 + (q & 1)*4) = v;
            }
        }
        __syncthreads();                               // B2

        // mm2 SWAPPED: channel = lane&15, row = rbk*16 + q*4 + c
#pragma unroll
        for (int ob = 0; ob < 2; ++ob)
#pragma unroll
            for (int rbk = 0; rbk < 4; ++rbk) acc[ob][rbk] = zero4;
#pragma unroll
        for (int t = 0; t < 4; ++t) {
            int kct = t*4 + q;
            int sw = m ^ kct;
#pragma unroll
            for (int rbk = 0; rbk < 4; ++rbk) {
                half8 bfr = *(const half8*)(y1s + (rbk*256 + kct*16 + sw)*8);
                acc[0][rbk] = __builtin_amdgcn_mfma_f32_16x16x32_f16(bfr, w2f[0][t], acc[0][rbk], 0, 0, 0);
                acc[1][rbk] = __builtin_amdgcn_mfma_f32_16x16x32_f16(bfr, w2f[1][t], acc[1][rbk], 0, 0, 0);
            }
        }
        // stats2
#pragma unroll
        for (int ob = 0; ob < 2; ++ob)
#pragma unroll
            for (int rbk = 0; rbk < 4; ++rbk) {
                ssum[ob] += acc[ob][rbk];
                ssq[ob]  += acc[ob][rbk]*acc[ob][rbk];
            }
        // per-pair max/min: 7 in-thread fmax + 2 shfls
#pragma unroll
        for (int ob = 0; ob < 2; ++ob)
#pragma unroll
            for (int pr = 0; pr < 2; ++pr) {
                f32x4 x0 = acc[ob][pr*2], x1 = acc[ob][pr*2 + 1];
                float mx = fmaxf(fmaxf(fmaxf(x0[0], x0[1]), fmaxf(x0[2], x0[3])),
                                 fmaxf(fmaxf(x1[0], x1[1]), fmaxf(x1[2], x1[3])));
                float mn = fminf(fminf(fminf(x0[0], x0[1]), fminf(x0[2], x0[3])),
                                 fminf(fminf(x1[0], x1[1]), fminf(x1[2], x1[3])));
                mx = fmaxf(mx, __shfl_xor(mx, 16));
                mx = fmaxf(mx, __shfl_xor(mx, 32));
                mn = fminf(mn, __shfl_xor(mn, 16));
                mn = fminf(mn, __shfl_xor(mn, 32));
                if (lane < 16) {
                    int p = tile*2 + pr;
                    int o = wid*32 + ob*16 + m;
                    wsmax[(size_t)p*CC + o] = mx;
                    wsmin[(size_t)p*CC + o] = mn;
                }
            }
    }
#pragma unroll
    for (int ob = 0; ob < 2; ++ob) {
        float v  = ssum[ob][0] + ssum[ob][1] + ssum[ob][2] + ssum[ob][3];
        float v2 = ssq[ob][0]  + ssq[ob][1]  + ssq[ob][2]  + ssq[ob][3];
        v  += __shfl_xor(v, 16);  v  += __shfl_xor(v, 32);
        v2 += __shfl_xor(v2, 16); v2 += __shfl_xor(v2, 32);
        if (lane < 16) {
            int o = wid*32 + ob*16 + m;
            atomicAdd(&gsum2[o], v);
            atomicAdd(&gsumsq2[o], v2);
        }
    }
}

// ---------------- epilogue: bn2+relu on max/min, transpose to (B,C,N) ----------------
__global__ void __launch_bounds__(256) k_epilogue(const float* __restrict__ wsmax,
                                                  const float* __restrict__ wsmin,
                                                  const float* __restrict__ ab2,
                                                  float* __restrict__ out) {
    __shared__ float t[128*65];
    int b = blockIdx.y;
    int n0 = blockIdx.x * 64;
    int tid = threadIdx.x;
#pragma unroll
    for (int i = 0; i < 32; ++i) {
        int idx = i*256 + tid;
        int nl = idx >> 7, o = idx & 127;
        int n = n0 + nl;
        float v = 0.f;
        if (n < NN) {
            float a = ab2[o], cc = ab2[CC + o];
            size_t p = (size_t)b*NN + n;
            float z = (a >= 0.f) ? wsmax[p*CC + o] : wsmin[p*CC + o];
            v = fmaf(a, z, cc);
            v = v > 0.f ? v : 0.f;
        }
        t[o*65 + nl] = v;
    }
    __syncthreads();
#pragma unroll
    for (int i = 0; i < 32; ++i) {
        int idx = i*256 + tid;
        int o = idx >> 6, nl = idx & 63;
        int n = n0 + nl;
        if (n < NN) out[((size_t)b*CC + o)*NN + n] = t[o*65 + nl];
    }
}

extern "C" void kernel_launch(void* const* d_in, const int* in_sizes, int n_in,
                              void* d_out, int out_size, void* d_ws, size_t ws_size,
                              hipStream_t stream) {
    const float* x      = (const float*)d_in[0];
    const float* coords = (const float*)d_in[1];
    const float* w1     = (const float*)d_in[2];
    const float* g1     = (const float*)d_in[3];
    const float* b1     = (const float*)d_in[4];
    const float* w2     = (const float*)d_in[5];
    const float* g2     = (const float*)d_in[6];
    const float* b2     = (const float*)d_in[7];
    float* out = (float*)d_out;

    char* ws = (char*)d_ws;
    size_t off = 0;
    int* knn_idx = (int*)(ws + off);   off += (size_t)ROWS * sizeof(int);        // 3.32 MB
    float* stats = (float*)(ws + off); off += 1024 * sizeof(float);
    float* gsum2 = stats + 256, *gsq2 = stats + 384;
    float* ab1   = stats + 512;
    float* ab2   = stats + 768;
    __half* feats = (__half*)(ws + off); off += (size_t)BB*NN*DD * sizeof(__half); // 3.32 MB
    __half* w1h   = (__half*)(ws + off); off += CC*CC * sizeof(__half);
    __half* w2h   = (__half*)(ws + off); off += CC*CC * sizeof(__half);
    float* wsmax = (float*)(ws + off);  off += (size_t)PAIRS*CC * sizeof(float);  // 13.3 MB
    float* wsmin = (float*)(ws + off);  off += (size_t)PAIRS*CC * sizeof(float);  // 13.3 MB
    int*   cnt   = (int*)(ws + off);    off += (size_t)PAIRS * sizeof(int);       // 104 KB
    float* Mfin  = (float*)(ws + off);  off += (size_t)MSTRIDE * sizeof(float);   // 50 KB
    // aliases (dead before k_fused writes wsmax/wsmin):
    float* s_arr = wsmax;                    // PAIRS*64 fp32 = 6.64 MB  (<13.3)
    float* Mpart = wsmin;                    // 256*12416 fp32 = 12.71 MB (<13.27)
    (void)ws_size; (void)in_sizes; (void)n_in; (void)out_size;

    hipMemsetAsync(stats, 0, 512 * sizeof(float), stream);
    hipMemsetAsync(cnt, 0, (size_t)PAIRS * sizeof(int), stream);

    dim3 gT((NN + 63)/64, BB);
    k_prep_feats<<<gT, 256, 0, stream>>>(x, feats);
    k_convert_w<<<64, 256, 0, stream>>>(w1, w2, w1h, w2h);
    k_knn<<<PAIRS/QPB, 256, 0, stream>>>(coords, knn_idx, cnt);
    k_gather_sum<<<PAIRS/4, 256, 0, stream>>>(feats, knn_idx, s_arr);
    k_gram<<<GRAM_BLOCKS, 256, 0, stream>>>(feats, s_arr, cnt, Mpart);
    k_gram_reduce<<<(MSTRIDE + 255)/256, 256, 0, stream>>>(Mpart, Mfin);
    k_stats1<<<CC, 256, 0, stream>>>(Mfin, w1h, g1, b1, ab1);
    k_fused_mfma<<<GRID_MM, 256, 0, stream>>>(feats, knn_idx, w1h, w2h, ab1,
                                              gsum2, gsq2, wsmax, wsmin);
    k_finalize<<<1, CC, 0, stream>>>(gsum2, gsq2, g2, b2, ab2);
    dim3 gE((NN + 63)/64, BB);
    k_epilogue<<<gE, 256, 0, stream>>>(wsmax, wsmin, ab2, out);
}